// Round 1
// baseline (2584.604 us; speedup 1.0000x reference)
//
#include <hip/hip_runtime.h>
#include <math.h>

#define NN 100000
#define EE 1600000
#define GG 64
#define HH 128
#define LL 4
#define CCLS 16
#define NC 100000

typedef __attribute__((ext_vector_type(8))) short bf16x8;
typedef __attribute__((ext_vector_type(4))) float f32x4;

__device__ __forceinline__ unsigned short f2bf(float x) {
  union { float f; unsigned int u; } v; v.f = x;
  unsigned int r = v.u + 0x7fffu + ((v.u >> 16) & 1u);
  return (unsigned short)(r >> 16);
}

// ---------------- CSR build ----------------
__global__ void hist_kernel(const int* __restrict__ dst, int* __restrict__ cnt, int E) {
  int e = blockIdx.x * 256 + threadIdx.x;
  if (e < E) atomicAdd(&cnt[dst[e]], 1);
}

__global__ __launch_bounds__(1024) void scan_kernel(const int* __restrict__ cnt,
                                                    int* __restrict__ rowptr,
                                                    int* __restrict__ cursor, int n) {
  __shared__ int buf[1024];
  __shared__ int carry;
  int tid = threadIdx.x;
  if (tid == 0) carry = 0;
  __syncthreads();
  for (int base = 0; base < n; base += 1024) {
    int i = base + tid;
    int v = (i < n) ? cnt[i] : 0;
    buf[tid] = v;
    __syncthreads();
    for (int off = 1; off < 1024; off <<= 1) {
      int t = (tid >= off) ? buf[tid - off] : 0;
      __syncthreads();
      buf[tid] += t;
      __syncthreads();
    }
    int excl = buf[tid] - v;
    if (i < n) { int e = carry + excl; rowptr[i] = e; cursor[i] = e; }
    __syncthreads();
    if (tid == 1023) carry += buf[1023];
    __syncthreads();
  }
  if (tid == 0) rowptr[n] = carry;
}

__global__ void fill_kernel(const int* __restrict__ src, const int* __restrict__ dst,
                            int* __restrict__ cursor, int* __restrict__ csr_src, int E) {
  int e = blockIdx.x * 256 + threadIdx.x;
  if (e < E) {
    int p = atomicAdd(&cursor[dst[e]], 1);
    csr_src[p] = src[e];
  }
}

// ---------------- f32 -> bf16 convert ----------------
__global__ void f2b_kernel(const float* __restrict__ in, unsigned short* __restrict__ out, int n) {
  int i = blockIdx.x * 256 + threadIdx.x;
  if (i < n) out[i] = f2bf(in[i]);
}

// ---------------- GIN aggregate: one wave per node ----------------
__global__ void aggregate_kernel(const float* __restrict__ h, int ld,
                                 const int* __restrict__ rowptr,
                                 const int* __restrict__ csr_src,
                                 const float* __restrict__ ceps_l,
                                 float* __restrict__ out, int n) {
  int node = blockIdx.x * 4 + (threadIdx.x >> 6);
  if (node >= n) return;
  int lane = threadIdx.x & 63;
  int c = lane * 2;
  float eps1 = 1.0f + *ceps_l;
  float2 acc = make_float2(0.f, 0.f);
  int b = rowptr[node], e = rowptr[node + 1];
  for (int j = b; j < e; ++j) {
    int s = csr_src[j];
    float2 v = *(const float2*)(h + (size_t)s * ld + c);
    acc.x += v.x; acc.y += v.y;
  }
  float2 hv = *(const float2*)(h + (size_t)node * ld + c);
  float2 r;
  r.x = eps1 * hv.x + acc.x;
  r.y = eps1 * hv.y + acc.y;
  *(float2*)(out + (size_t)node * 128 + c) = r;
}

// ---------------- fp32 GEMM: C[M,128] = relu(A[M,128] @ W[128,128] + b) -----
// in-place safe (block writes only its own rows, after all its reads)
__global__ __launch_bounds__(256) void gemm128_relu(
    const float* __restrict__ A, int lda,
    const float* __restrict__ W, const float* __restrict__ bias,
    float* C, int ldc, int M) {
  __shared__ float As[32][132];   // [k][m], padded
  __shared__ float Bs[32][128];   // [k][n]
  const int tid = threadIdx.x;
  const int bm = blockIdx.x * 128;
  const int tx = tid & 15, ty = tid >> 4;
  float acc[8][8] = {};
  for (int k0 = 0; k0 < 128; k0 += 32) {
#pragma unroll
    for (int p = 0; p < 4; ++p) {
      int slot = p * 256 + tid;
      int r = slot >> 3;
      int c4 = (slot & 7) << 2;
      int gr = bm + r;
      float4 v = make_float4(0.f, 0.f, 0.f, 0.f);
      if (gr < M) v = *(const float4*)(A + (size_t)gr * lda + k0 + c4);
      As[c4 + 0][r] = v.x; As[c4 + 1][r] = v.y; As[c4 + 2][r] = v.z; As[c4 + 3][r] = v.w;
    }
#pragma unroll
    for (int p = 0; p < 4; ++p) {
      int slot = p * 256 + tid;
      int kk = slot >> 5;
      int n4 = (slot & 31) << 2;
      *(float4*)&Bs[kk][n4] = *(const float4*)(W + (size_t)(k0 + kk) * 128 + n4);
    }
    __syncthreads();
#pragma unroll
    for (int k = 0; k < 32; ++k) {
      float4 a0 = *(const float4*)&As[k][ty * 8];
      float4 a1 = *(const float4*)&As[k][ty * 8 + 4];
      float4 b0 = *(const float4*)&Bs[k][tx * 8];
      float4 b1 = *(const float4*)&Bs[k][tx * 8 + 4];
      float av[8] = {a0.x, a0.y, a0.z, a0.w, a1.x, a1.y, a1.z, a1.w};
      float bv[8] = {b0.x, b0.y, b0.z, b0.w, b1.x, b1.y, b1.z, b1.w};
#pragma unroll
      for (int i = 0; i < 8; ++i)
#pragma unroll
        for (int j = 0; j < 8; ++j)
          acc[i][j] = fmaf(av[i], bv[j], acc[i][j]);
    }
    __syncthreads();
  }
  float bv[8];
#pragma unroll
  for (int j = 0; j < 8; ++j) bv[j] = bias[tx * 8 + j];
#pragma unroll
  for (int i = 0; i < 8; ++i) {
    int r = bm + ty * 8 + i;
    if (r >= M) continue;
    float4 o0, o1;
    o0.x = fmaxf(acc[i][0] + bv[0], 0.f);
    o0.y = fmaxf(acc[i][1] + bv[1], 0.f);
    o0.z = fmaxf(acc[i][2] + bv[2], 0.f);
    o0.w = fmaxf(acc[i][3] + bv[3], 0.f);
    o1.x = fmaxf(acc[i][4] + bv[4], 0.f);
    o1.y = fmaxf(acc[i][5] + bv[5], 0.f);
    o1.z = fmaxf(acc[i][6] + bv[6], 0.f);
    o1.w = fmaxf(acc[i][7] + bv[7], 0.f);
    *(float4*)(C + (size_t)r * ldc + tx * 8) = o0;
    *(float4*)(C + (size_t)r * ldc + tx * 8 + 4) = o1;
  }
}

// ---------------- BatchNorm ----------------
__global__ void bn_stats_kernel(const float* __restrict__ z, float* __restrict__ sum,
                                float* __restrict__ sumsq, int n) {
  int c = threadIdx.x;  // 0..127
  int r0 = blockIdx.x * 128;
  int rend = min(r0 + 128, n);
  float s = 0.f, q = 0.f;
  for (int r = r0; r < rend; ++r) {
    float v = z[(size_t)r * 128 + c];
    s += v; q += v * v;
  }
  atomicAdd(&sum[c], s);
  atomicAdd(&sumsq[c], q);
}

__global__ void bn_apply_kernel(const float* __restrict__ z, const float* __restrict__ sum,
                                const float* __restrict__ sumsq,
                                const float* __restrict__ gamma, const float* __restrict__ beta,
                                float* __restrict__ out /* emb + l*128, ld 512 */, int n) {
  int idx = blockIdx.x * 256 + threadIdx.x;
  if (idx >= n * 128) return;
  int r = idx >> 7, c = idx & 127;
  const float inv_n = 1.0f / (float)NN;
  float mu = sum[c] * inv_n;
  float var = sumsq[c] * inv_n - mu * mu;
  float sc = rsqrtf(var + 1e-5f) * gamma[c];
  out[(size_t)r * 512 + c] = (z[idx] - mu) * sc + beta[c];
}

// ---------------- pooling ----------------
__global__ void bounds_kernel(const int* __restrict__ batch, int* __restrict__ gstart, int n) {
  int g = threadIdx.x;
  if (g > GG) return;
  int lo = 0, hi = n;
  while (lo < hi) {
    int mid = (lo + hi) >> 1;
    if (batch[mid] < g) lo = mid + 1; else hi = mid;
  }
  gstart[g] = lo;
}

__global__ __launch_bounds__(512) void pool_kernel(const float* __restrict__ emb,
                                                   const int* __restrict__ gstart,
                                                   float* __restrict__ gsum) {
  int g = blockIdx.x;
  int chunk = blockIdx.y;
  int c = threadIdx.x;
  int s = gstart[g], e = gstart[g + 1];
  int len = e - s;
  int per = (len + 7) >> 3;
  int r0 = s + chunk * per;
  int r1 = min(r0 + per, e);
  float acc = 0.f;
  for (int r = r0; r < r1; ++r) acc += emb[(size_t)r * 512 + c];
  if (r1 > r0) atomicAdd(&gsum[g * 512 + c], acc);
}

__global__ void pool_div_kernel(const float* __restrict__ gsum, const int* __restrict__ gstart,
                                float* __restrict__ gemb) {
  int idx = blockIdx.x * 256 + threadIdx.x;
  if (idx >= GG * 512) return;
  int g = idx >> 9;
  float cntf = fmaxf((float)(gstart[g + 1] - gstart[g]), 1.0f);
  gemb[idx] = gsum[idx] / cntf;
}

// ---------------- small dense MLP (M=64) ----------------
__global__ void small_gemm(const float* __restrict__ A, const float* __restrict__ W,
                           const float* __restrict__ b, float* __restrict__ C,
                           int M, int K, int Nn, int relu) {
  int idx = blockIdx.x * 256 + threadIdx.x;
  if (idx >= M * Nn) return;
  int r = idx / Nn, n = idx % Nn;
  const float* a = A + (size_t)r * K;
  float acc = b[n];
  for (int k = 0; k < K; ++k) acc = fmaf(a[k], W[(size_t)k * Nn + n], acc);
  if (relu) acc = fmaxf(acc, 0.f);
  C[idx] = acc;
}

__global__ void cls_out_kernel(const float* __restrict__ t3, const float* __restrict__ W,
                               const float* __restrict__ b, float* __restrict__ out) {
  int g = blockIdx.x;
  int lane = threadIdx.x;  // 64 threads
  float v = 0.f;
  float logit = -1e30f;
  if (lane < CCLS) {
    v = b[lane];
    for (int k = 0; k < 128; ++k) v = fmaf(t3[g * 128 + k], W[k * CCLS + lane], v);
    logit = v;
  }
  float m = logit;
  for (int off = 8; off >= 1; off >>= 1) m = fmaxf(m, __shfl_down(m, off, 64));
  m = __shfl(m, 0, 64);
  float ex = (lane < CCLS) ? expf(v - m) : 0.f;
  float s = ex;
  for (int off = 8; off >= 1; off >>= 1) s += __shfl_down(s, off, 64);
  s = __shfl(s, 0, 64);
  if (lane < CCLS) out[g * CCLS + lane] = v - m - logf(s);
}

// ---------------- edge predictor: bf16 MFMA GEMMs ----------------
// GEMM1: C1[NC,256] = relu(ef @ epW1 + b1), ef gathered from emb via cand
#define LDK 40  // padded LDS row stride in bf16 elems (80 B, 16B-aligned)
__global__ __launch_bounds__(256) void ep_gemm1(
    const float* __restrict__ emb, const int* __restrict__ cand,
    const unsigned short* __restrict__ W16, const float* __restrict__ bias,
    unsigned short* __restrict__ Cout, int M) {
  __shared__ unsigned short As[128 * LDK];
  __shared__ unsigned short Bs[128 * LDK];
  const int tid = threadIdx.x;
  const int bm = blockIdx.x * 128;
  const int bn = blockIdx.y * 128;
  const int lane = tid & 63;
  const int wave = tid >> 6;
  const int wr = (wave >> 1) << 6;
  const int wc = (wave & 1) << 6;
  f32x4 acc[4][4] = {};
  const int ar = tid >> 1;
  const int ah = (tid & 1) << 4;
  int gra = bm + ar; if (gra >= M) gra = M - 1;
  const int bkk = tid >> 3;
  const int bn16 = (tid & 7) << 4;
  const int mrow = lane & 15;
  const int kq = (lane >> 4) << 3;

  for (int ks = 0; ks < 32; ++ks) {
    const int k0 = ks << 5;
    {  // A tile: gather rows from emb (fp32 -> bf16)
      const int* candp = (k0 < 512) ? cand : (cand + NC);
      int node = candp[gra];
      const float4* src = (const float4*)(emb + (size_t)node * 512 + (k0 & 511) + ah);
      unsigned short* d = As + ar * LDK + ah;
#pragma unroll
      for (int i = 0; i < 4; ++i) {
        float4 v = src[i];
        d[4 * i + 0] = f2bf(v.x); d[4 * i + 1] = f2bf(v.y);
        d[4 * i + 2] = f2bf(v.z); d[4 * i + 3] = f2bf(v.w);
      }
    }
    {  // B tile: transpose into Bs[n][k]
      const unsigned short* srcB = W16 + (size_t)(k0 + bkk) * 256 + bn + bn16;
#pragma unroll
      for (int i = 0; i < 16; ++i) Bs[(bn16 + i) * LDK + bkk] = srcB[i];
    }
    __syncthreads();
    bf16x8 af[4], bfv[4];
#pragma unroll
    for (int t = 0; t < 4; ++t)
      af[t] = *(const bf16x8*)(As + (wr + t * 16 + mrow) * LDK + kq);
#pragma unroll
    for (int t = 0; t < 4; ++t)
      bfv[t] = *(const bf16x8*)(Bs + (wc + t * 16 + mrow) * LDK + kq);
#pragma unroll
    for (int mt = 0; mt < 4; ++mt)
#pragma unroll
      for (int nt = 0; nt < 4; ++nt)
        acc[mt][nt] = __builtin_amdgcn_mfma_f32_16x16x32_bf16(af[mt], bfv[nt], acc[mt][nt], 0, 0, 0);
    __syncthreads();
  }
  const int crow = (lane >> 4) << 2;
  const int ccol = lane & 15;
#pragma unroll
  for (int nt = 0; nt < 4; ++nt) {
    int cbase = bn + wc + nt * 16 + ccol;
    float bz = bias[cbase];
#pragma unroll
    for (int mt = 0; mt < 4; ++mt) {
      int rbase = bm + wr + mt * 16 + crow;
#pragma unroll
      for (int i = 0; i < 4; ++i) {
        int r = rbase + i;
        if (r < M) Cout[(size_t)r * 256 + cbase] = f2bf(fmaxf(acc[mt][nt][i] + bz, 0.f));
      }
    }
  }
}

// GEMM2: C2[NC,128] f32 = relu(C1 @ epW2 + b2), K=256, in-place over C1 bytes
__global__ __launch_bounds__(256) void ep_gemm2(
    const unsigned short* Ain, const unsigned short* __restrict__ W16,
    const float* __restrict__ bias, float* Cout, int M) {
  __shared__ unsigned short As[128 * LDK];
  __shared__ unsigned short Bs[128 * LDK];
  const int tid = threadIdx.x;
  const int bm = blockIdx.x * 128;
  const int lane = tid & 63;
  const int wave = tid >> 6;
  const int wr = (wave >> 1) << 6;
  const int wc = (wave & 1) << 6;
  f32x4 acc[4][4] = {};
  const int ar = tid >> 1;
  const int ah = (tid & 1) << 4;
  int gra = bm + ar; if (gra >= M) gra = M - 1;
  const int bkk = tid >> 3;
  const int bn16 = (tid & 7) << 4;
  const int mrow = lane & 15;
  const int kq = (lane >> 4) << 3;

  for (int ks = 0; ks < 8; ++ks) {
    const int k0 = ks << 5;
    {  // A tile: direct bf16 rows
      const uint4* s = (const uint4*)(Ain + (size_t)gra * 256 + k0 + ah);
      uint4 v0 = s[0], v1 = s[1];
      *(uint4*)(As + ar * LDK + ah) = v0;
      *(uint4*)(As + ar * LDK + ah + 8) = v1;
    }
    {  // B tile transpose
      const unsigned short* srcB = W16 + (size_t)(k0 + bkk) * 128 + bn16;
#pragma unroll
      for (int i = 0; i < 16; ++i) Bs[(bn16 + i) * LDK + bkk] = srcB[i];
    }
    __syncthreads();
    bf16x8 af[4], bfv[4];
#pragma unroll
    for (int t = 0; t < 4; ++t)
      af[t] = *(const bf16x8*)(As + (wr + t * 16 + mrow) * LDK + kq);
#pragma unroll
    for (int t = 0; t < 4; ++t)
      bfv[t] = *(const bf16x8*)(Bs + (wc + t * 16 + mrow) * LDK + kq);
#pragma unroll
    for (int mt = 0; mt < 4; ++mt)
#pragma unroll
      for (int nt = 0; nt < 4; ++nt)
        acc[mt][nt] = __builtin_amdgcn_mfma_f32_16x16x32_bf16(af[mt], bfv[nt], acc[mt][nt], 0, 0, 0);
    __syncthreads();
  }
  const int crow = (lane >> 4) << 2;
  const int ccol = lane & 15;
#pragma unroll
  for (int nt = 0; nt < 4; ++nt) {
    int cbase = wc + nt * 16 + ccol;
    float bz = bias[cbase];
#pragma unroll
    for (int mt = 0; mt < 4; ++mt) {
      int rbase = bm + wr + mt * 16 + crow;
#pragma unroll
      for (int i = 0; i < 4; ++i) {
        int r = rbase + i;
        if (r < M) Cout[(size_t)r * 128 + cbase] = fmaxf(acc[mt][nt][i] + bz, 0.f);
      }
    }
  }
}

__global__ void ep_final_kernel(const float* __restrict__ C2, const float* __restrict__ w,
                                const float* __restrict__ b3, float* __restrict__ out, int M) {
  int row = blockIdx.x * 4 + (threadIdx.x >> 6);
  if (row >= M) return;
  int lane = threadIdx.x & 63;
  float2 v = *(const float2*)(C2 + (size_t)row * 128 + lane * 2);
  float2 wv = *(const float2*)(w + lane * 2);
  float s = v.x * wv.x + v.y * wv.y;
  for (int off = 32; off >= 1; off >>= 1) s += __shfl_down(s, off, 64);
  if (lane == 0) out[row] = 1.f / (1.f + expf(-(s + b3[0])));
}

// ---------------- launch ----------------
extern "C" void kernel_launch(void* const* d_in, const int* in_sizes, int n_in,
                              void* d_out, int out_size, void* d_ws, size_t ws_size,
                              hipStream_t stream) {
  const float* x = (const float*)d_in[0];
  const int* edge_index = (const int*)d_in[1];
  const int* batch = (const int*)d_in[2];
  const int* cand = (const int*)d_in[3];
  const float* cW1 = (const float*)d_in[4];
  const float* cb1 = (const float*)d_in[5];
  const float* cW2 = (const float*)d_in[6];
  const float* cb2 = (const float*)d_in[7];
  const float* cgamma = (const float*)d_in[8];
  const float* cbeta = (const float*)d_in[9];
  const float* ceps = (const float*)d_in[10];
  const float* ncW1 = (const float*)d_in[11];
  const float* ncb1 = (const float*)d_in[12];
  const float* ncW2 = (const float*)d_in[13];
  const float* ncb2 = (const float*)d_in[14];
  const float* ncW3 = (const float*)d_in[15];
  const float* ncb3 = (const float*)d_in[16];
  const float* ncW4 = (const float*)d_in[17];
  const float* ncb4 = (const float*)d_in[18];
  const float* epW1 = (const float*)d_in[19];
  const float* epb1 = (const float*)d_in[20];
  const float* epW2 = (const float*)d_in[21];
  const float* epb2 = (const float*)d_in[22];
  const float* epW3 = (const float*)d_in[23];
  const float* epb3 = (const float*)d_in[24];

  char* ws = (char*)d_ws;
  size_t off = 0;
  auto alloc = [&](size_t bytes) -> void* {
    off = (off + 255) & ~(size_t)255;
    void* p = ws + off;
    off += bytes;
    return p;
  };
  // contiguous zero zone: cnt | bnsum | bnsumsq | gsum
  size_t zz_bytes = (size_t)NN * 4 + 512 * 4 + 512 * 4 + (size_t)GG * 512 * 4;
  char* zz = (char*)alloc(zz_bytes);
  int* cnt = (int*)zz;
  float* bnsum = (float*)(zz + (size_t)NN * 4);
  float* bnsumsq = bnsum + 512;
  float* gsum = bnsumsq + 512;
  int* rowptr = (int*)alloc((size_t)(NN + 1) * 4);
  int* cursor = (int*)alloc((size_t)NN * 4);
  int* csr_src = (int*)alloc((size_t)EE * 4);
  float* work = (float*)alloc((size_t)NN * 256 * 2);   // 51.2 MB, reused: agg/z1/z2, then C1(bf16)/C2(f32)
  float* emb = (float*)alloc((size_t)NN * 512 * 4);    // 204.8 MB
  int* gstart = (int*)alloc(65 * 4);
  float* gemb = (float*)alloc((size_t)GG * 512 * 4);
  float* t1 = (float*)alloc((size_t)GG * 256 * 4);
  float* t2 = (float*)alloc((size_t)GG * 128 * 4);
  float* t3 = (float*)alloc((size_t)GG * 128 * 4);
  unsigned short* epW1_16 = (unsigned short*)alloc((size_t)1024 * 256 * 2);
  unsigned short* epW2_16 = (unsigned short*)alloc((size_t)256 * 128 * 2);

  const int* esrc = edge_index;
  const int* edst = edge_index + EE;

  hipMemsetAsync(zz, 0, zz_bytes, stream);
  hist_kernel<<<(EE + 255) / 256, 256, 0, stream>>>(edst, cnt, EE);
  scan_kernel<<<1, 1024, 0, stream>>>(cnt, rowptr, cursor, NN);
  fill_kernel<<<(EE + 255) / 256, 256, 0, stream>>>(esrc, edst, cursor, csr_src, EE);
  f2b_kernel<<<(1024 * 256 + 255) / 256, 256, 0, stream>>>(epW1, epW1_16, 1024 * 256);
  f2b_kernel<<<(256 * 128 + 255) / 256, 256, 0, stream>>>(epW2, epW2_16, 256 * 128);

  for (int l = 0; l < LL; ++l) {
    const float* h = (l == 0) ? x : (emb + (size_t)(l - 1) * 128);
    int ld = (l == 0) ? 128 : 512;
    aggregate_kernel<<<(NN + 3) / 4, 256, 0, stream>>>(h, ld, rowptr, csr_src, ceps + l, work, NN);
    gemm128_relu<<<(NN + 127) / 128, 256, 0, stream>>>(work, 128, cW1 + (size_t)l * 16384,
                                                       cb1 + l * 128, work, 128, NN);
    gemm128_relu<<<(NN + 127) / 128, 256, 0, stream>>>(work, 128, cW2 + (size_t)l * 16384,
                                                       cb2 + l * 128, work, 128, NN);
    bn_stats_kernel<<<(NN + 127) / 128, 128, 0, stream>>>(work, bnsum + l * 128, bnsumsq + l * 128, NN);
    bn_apply_kernel<<<(NN * 128 + 255) / 256, 256, 0, stream>>>(
        work, bnsum + l * 128, bnsumsq + l * 128, cgamma + l * 128, cbeta + l * 128,
        emb + (size_t)l * 128, NN);
  }

  bounds_kernel<<<1, 128, 0, stream>>>(batch, gstart, NN);
  pool_kernel<<<dim3(GG, 8), 512, 0, stream>>>(emb, gstart, gsum);
  pool_div_kernel<<<(GG * 512 + 255) / 256, 256, 0, stream>>>(gsum, gstart, gemb);
  small_gemm<<<(GG * 256 + 255) / 256, 256, 0, stream>>>(gemb, ncW1, ncb1, t1, GG, 512, 256, 1);
  small_gemm<<<(GG * 128 + 255) / 256, 256, 0, stream>>>(t1, ncW2, ncb2, t2, GG, 256, 128, 1);
  small_gemm<<<(GG * 128 + 255) / 256, 256, 0, stream>>>(t2, ncW3, ncb3, t3, GG, 128, 128, 1);
  cls_out_kernel<<<GG, 64, 0, stream>>>(t3, ncW4, ncb4, (float*)d_out);

  unsigned short* C1 = (unsigned short*)work;
  ep_gemm1<<<dim3((NC + 127) / 128, 2), 256, 0, stream>>>(emb, cand, epW1_16, epb1, C1, NC);
  ep_gemm2<<<dim3((NC + 127) / 128, 1), 256, 0, stream>>>(C1, epW2_16, epb2, (float*)work, NC);
  ep_final_kernel<<<(NC + 3) / 4, 256, 0, stream>>>((float*)work, epW3, epb3,
                                                    (float*)d_out + GG * CCLS, NC);
}

// Round 2
// 2249.082 us; speedup vs baseline: 1.1492x; 1.1492x over previous
//
#include <hip/hip_runtime.h>
#include <math.h>

#define NN 100000
#define EE 1600000
#define GG 64
#define HH 128
#define LL 4
#define CCLS 16
#define NC 100000
#define LDK 40  // padded LDS row stride in bf16 elems (80 B)

typedef __attribute__((ext_vector_type(8))) short bf16x8;
typedef __attribute__((ext_vector_type(4))) float f32x4;

__device__ __forceinline__ unsigned short f2bf(float x) {
  union { float f; unsigned int u; } v; v.f = x;
  unsigned int r = v.u + 0x7fffu + ((v.u >> 16) & 1u);
  return (unsigned short)(r >> 16);
}
__device__ __forceinline__ float bl(unsigned u) {
  union { unsigned u; float f; } v; v.u = u << 16; return v.f;
}
__device__ __forceinline__ float bh(unsigned u) {
  union { unsigned u; float f; } v; v.u = u & 0xffff0000u; return v.f;
}

// ---------------- CSR build ----------------
__global__ void hist_kernel(const int* __restrict__ dst, int* __restrict__ cnt, int E) {
  int e = blockIdx.x * 256 + threadIdx.x;
  if (e < E) atomicAdd(&cnt[dst[e]], 1);
}

__global__ __launch_bounds__(1024) void scan2_kernel(const int* __restrict__ cnt,
                                                     int* __restrict__ rowptr,
                                                     int* __restrict__ cursor, int n) {
  __shared__ int part[1024];
  int tid = threadIdx.x;
  const int CH = (n + 1023) >> 10;  // 98
  int base = tid * CH;
  int s = 0;
  for (int i = 0; i < CH; ++i) { int idx = base + i; if (idx < n) s += cnt[idx]; }
  part[tid] = s;
  __syncthreads();
  for (int off = 1; off < 1024; off <<= 1) {
    int t = (tid >= off) ? part[tid - off] : 0;
    __syncthreads();
    part[tid] += t;
    __syncthreads();
  }
  int run = part[tid] - s;  // exclusive prefix
  for (int i = 0; i < CH; ++i) {
    int idx = base + i;
    if (idx < n) { rowptr[idx] = run; cursor[idx] = run; run += cnt[idx]; }
  }
  if (tid == 1023) rowptr[n] = part[1023];
}

__global__ void fill_kernel(const int* __restrict__ src, const int* __restrict__ dst,
                            int* __restrict__ cursor, int* __restrict__ csr_src, int E) {
  int e = blockIdx.x * 256 + threadIdx.x;
  if (e < E) {
    int p = atomicAdd(&cursor[dst[e]], 1);
    csr_src[p] = src[e];
  }
}

// ---------------- converts ----------------
__global__ void f2b4_kernel(const float* __restrict__ in, unsigned short* __restrict__ out, int n4) {
  int i = blockIdx.x * 256 + threadIdx.x;
  if (i >= n4) return;
  float4 v = ((const float4*)in)[i];
  unsigned short r[4] = {f2bf(v.x), f2bf(v.y), f2bf(v.z), f2bf(v.w)};
  *(uint2*)(out + (size_t)i * 4) = *(uint2*)r;
}

// cW1/cW2 [L][K=128][N=128] fp32 -> WT [L][N][K] bf16 (both at once)
__global__ void convert_trunk(const float* __restrict__ cW1, const float* __restrict__ cW2,
                              unsigned short* __restrict__ WT1, unsigned short* __restrict__ WT2) {
  int idx = blockIdx.x * 256 + threadIdx.x;
  if (idx >= LL * 16384) return;
  int l = idx >> 14, r = idx & 16383, k = r >> 7, n = r & 127;
  WT1[l * 16384 + n * 128 + k] = f2bf(cW1[idx]);
  WT2[l * 16384 + n * 128 + k] = f2bf(cW2[idx]);
}

// in [K][Nn] fp32 -> out [Nn][K] bf16
__global__ void f2bT_kernel(const float* __restrict__ in, unsigned short* __restrict__ out,
                            int K, int Nn) {
  int idx = blockIdx.x * 256 + threadIdx.x;
  if (idx >= K * Nn) return;
  int k = idx / Nn, n = idx - k * Nn;
  out[(size_t)n * K + k] = f2bf(in[idx]);
}

// ---------------- GIN aggregate (bf16 gather, fp32 acc, bf16 out) ----------------
__global__ void aggregate_bf16(const unsigned short* __restrict__ h16, int ld,
                               const int* __restrict__ rowptr,
                               const int* __restrict__ csr_src,
                               const float* __restrict__ ceps_l,
                               unsigned short* __restrict__ out, int n) {
  int node = blockIdx.x * 4 + (threadIdx.x >> 6);
  if (node >= n) return;
  int lane = threadIdx.x & 63;
  int c2 = lane * 2;
  float eps1 = 1.0f + *ceps_l;
  float ax = 0.f, ay = 0.f;
  int b = rowptr[node], e = rowptr[node + 1];
  for (int j = b; j < e; ++j) {
    int s = csr_src[j];
    unsigned u = *(const unsigned*)(h16 + (size_t)s * ld + c2);
    ax += bl(u); ay += bh(u);
  }
  unsigned hu = *(const unsigned*)(h16 + (size_t)node * ld + c2);
  ax = fmaf(eps1, bl(hu), ax);
  ay = fmaf(eps1, bh(hu), ay);
  unsigned short o[2] = {f2bf(ax), f2bf(ay)};
  *(unsigned*)(out + (size_t)node * 128 + c2) = *(unsigned*)o;
}

// ---------------- bf16 MFMA GEMM: C[M,ldc]=relu(A[M,lda(K cols)] @ WT^T + bias) ----------------
// WT is pre-transposed [Nout][K] bf16. Block tile 128x128, 4 waves 2x2, wave 64x64.
__global__ __launch_bounds__(256) void mfma_gemm_bt(
    const unsigned short* __restrict__ A16, int lda,
    const unsigned short* __restrict__ WT, int K,
    const float* __restrict__ bias,
    unsigned short* __restrict__ C16, int ldc, int M) {
  __shared__ unsigned short As[128 * LDK];
  __shared__ unsigned short Bs[128 * LDK];
  const int tid = threadIdx.x;
  const int bm = blockIdx.x * 128;
  const int bn = blockIdx.y * 128;
  const int lane = tid & 63;
  const int wave = tid >> 6;
  const int wr = (wave >> 1) << 6;
  const int wc = (wave & 1) << 6;
  f32x4 acc[4][4] = {};
  const int ar = tid >> 1;
  const int ah = (tid & 1) << 4;
  int gra = bm + ar; if (gra >= M) gra = M - 1;
  const unsigned short* Arow = A16 + (size_t)gra * lda;
  const unsigned short* Brow = WT + (size_t)(bn + ar) * K;
  const int mrow = lane & 15;
  const int kq = (lane >> 4) << 3;
  const int nks = K >> 5;

  for (int ks = 0; ks < nks; ++ks) {
    const int k0 = ks << 5;
    {
      const uint4* s = (const uint4*)(Arow + k0 + ah);
      *(uint4*)(As + ar * LDK + ah) = s[0];
      *(uint4*)(As + ar * LDK + ah + 8) = s[1];
    }
    {
      const uint4* s = (const uint4*)(Brow + k0 + ah);
      *(uint4*)(Bs + ar * LDK + ah) = s[0];
      *(uint4*)(Bs + ar * LDK + ah + 8) = s[1];
    }
    __syncthreads();
    bf16x8 af[4], bfv[4];
#pragma unroll
    for (int t = 0; t < 4; ++t)
      af[t] = *(const bf16x8*)(As + (wr + t * 16 + mrow) * LDK + kq);
#pragma unroll
    for (int t = 0; t < 4; ++t)
      bfv[t] = *(const bf16x8*)(Bs + (wc + t * 16 + mrow) * LDK + kq);
#pragma unroll
    for (int mt = 0; mt < 4; ++mt)
#pragma unroll
      for (int nt = 0; nt < 4; ++nt)
        acc[mt][nt] = __builtin_amdgcn_mfma_f32_16x16x32_bf16(af[mt], bfv[nt], acc[mt][nt], 0, 0, 0);
    __syncthreads();
  }
  const int crow = (lane >> 4) << 2;
  const int ccol = lane & 15;
#pragma unroll
  for (int nt = 0; nt < 4; ++nt) {
    int cbase = bn + wc + nt * 16 + ccol;
    float bz = bias[cbase];
#pragma unroll
    for (int mt = 0; mt < 4; ++mt) {
      int rbase = bm + wr + mt * 16 + crow;
#pragma unroll
      for (int i = 0; i < 4; ++i) {
        int r = rbase + i;
        if (r < M) C16[(size_t)r * ldc + cbase] = f2bf(fmaxf(acc[mt][nt][i] + bz, 0.f));
      }
    }
  }
}

// ep GEMM1 with fused candidate gather: A row = [emb16[cand0] | emb16[cand1]], K=1024
__global__ __launch_bounds__(256) void mfma_gemm_gather(
    const unsigned short* __restrict__ emb16, const int* __restrict__ cand,
    const unsigned short* __restrict__ WT /*[256][1024]*/,
    const float* __restrict__ bias,
    unsigned short* __restrict__ C16 /*[M,256]*/, int M) {
  __shared__ unsigned short As[128 * LDK];
  __shared__ unsigned short Bs[128 * LDK];
  const int tid = threadIdx.x;
  const int bm = blockIdx.x * 128;
  const int bn = blockIdx.y * 128;
  const int lane = tid & 63;
  const int wave = tid >> 6;
  const int wr = (wave >> 1) << 6;
  const int wc = (wave & 1) << 6;
  f32x4 acc[4][4] = {};
  const int ar = tid >> 1;
  const int ah = (tid & 1) << 4;
  int gra = bm + ar; if (gra >= M) gra = M - 1;
  const int node0 = cand[gra];
  const int node1 = cand[NC + gra];
  const unsigned short* Brow = WT + (size_t)(bn + ar) * 1024;
  const int mrow = lane & 15;
  const int kq = (lane >> 4) << 3;

  for (int ks = 0; ks < 32; ++ks) {
    const int k0 = ks << 5;
    {
      int node = (k0 < 512) ? node0 : node1;
      const uint4* s = (const uint4*)(emb16 + (size_t)node * 512 + (k0 & 511) + ah);
      *(uint4*)(As + ar * LDK + ah) = s[0];
      *(uint4*)(As + ar * LDK + ah + 8) = s[1];
    }
    {
      const uint4* s = (const uint4*)(Brow + k0 + ah);
      *(uint4*)(Bs + ar * LDK + ah) = s[0];
      *(uint4*)(Bs + ar * LDK + ah + 8) = s[1];
    }
    __syncthreads();
    bf16x8 af[4], bfv[4];
#pragma unroll
    for (int t = 0; t < 4; ++t)
      af[t] = *(const bf16x8*)(As + (wr + t * 16 + mrow) * LDK + kq);
#pragma unroll
    for (int t = 0; t < 4; ++t)
      bfv[t] = *(const bf16x8*)(Bs + (wc + t * 16 + mrow) * LDK + kq);
#pragma unroll
    for (int mt = 0; mt < 4; ++mt)
#pragma unroll
      for (int nt = 0; nt < 4; ++nt)
        acc[mt][nt] = __builtin_amdgcn_mfma_f32_16x16x32_bf16(af[mt], bfv[nt], acc[mt][nt], 0, 0, 0);
    __syncthreads();
  }
  const int crow = (lane >> 4) << 2;
  const int ccol = lane & 15;
#pragma unroll
  for (int nt = 0; nt < 4; ++nt) {
    int cbase = bn + wc + nt * 16 + ccol;
    float bz = bias[cbase];
#pragma unroll
    for (int mt = 0; mt < 4; ++mt) {
      int rbase = bm + wr + mt * 16 + crow;
#pragma unroll
      for (int i = 0; i < 4; ++i) {
        int r = rbase + i;
        if (r < M) C16[(size_t)r * 256 + cbase] = f2bf(fmaxf(acc[mt][nt][i] + bz, 0.f));
      }
    }
  }
}

// ---------------- BatchNorm (bf16 in) ----------------
__global__ __launch_bounds__(256) void bn_stats_bf16(const unsigned short* __restrict__ z,
                                                     float* __restrict__ sum,
                                                     float* __restrict__ sumsq, int n) {
  __shared__ float red[16][128];
  int tid = threadIdx.x;
  int cg = tid & 15, rg = tid >> 4;
  int c8 = cg * 8;
  int base = blockIdx.x * 512;
  int rend = min(base + 512, n);
  float s[8] = {}, q[8] = {};
  for (int r = base + rg; r < rend; r += 16) {
    uint4 v = *(const uint4*)(z + (size_t)r * 128 + c8);
    float f[8] = {bl(v.x), bh(v.x), bl(v.y), bh(v.y), bl(v.z), bh(v.z), bl(v.w), bh(v.w)};
#pragma unroll
    for (int j = 0; j < 8; ++j) { s[j] += f[j]; q[j] += f[j] * f[j]; }
  }
#pragma unroll
  for (int j = 0; j < 8; ++j) red[rg][c8 + j] = s[j];
  __syncthreads();
  for (int step = 8; step >= 1; step >>= 1) {
    if (rg < step)
#pragma unroll
      for (int j = 0; j < 8; ++j) red[rg][c8 + j] += red[rg + step][c8 + j];
    __syncthreads();
  }
  if (rg == 0)
#pragma unroll
    for (int j = 0; j < 8; ++j) atomicAdd(&sum[c8 + j], red[0][c8 + j]);
  __syncthreads();
#pragma unroll
  for (int j = 0; j < 8; ++j) red[rg][c8 + j] = q[j];
  __syncthreads();
  for (int step = 8; step >= 1; step >>= 1) {
    if (rg < step)
#pragma unroll
      for (int j = 0; j < 8; ++j) red[rg][c8 + j] += red[rg + step][c8 + j];
    __syncthreads();
  }
  if (rg == 0)
#pragma unroll
    for (int j = 0; j < 8; ++j) atomicAdd(&sumsq[c8 + j], red[0][c8 + j]);
}

__global__ void bn_apply_bf16(const unsigned short* __restrict__ z,
                              const float* __restrict__ sum, const float* __restrict__ sumsq,
                              const float* __restrict__ gamma, const float* __restrict__ beta,
                              unsigned short* __restrict__ out /* emb16 + l*128, ld 512 */, int n) {
  int idx = blockIdx.x * 256 + threadIdx.x;
  if (idx >= n * 16) return;
  int r = idx >> 4, c8 = (idx & 15) << 3;
  uint4 v = *(const uint4*)(z + (size_t)r * 128 + c8);
  float f[8] = {bl(v.x), bh(v.x), bl(v.y), bh(v.y), bl(v.z), bh(v.z), bl(v.w), bh(v.w)};
  const float inv_n = 1.0f / (float)NN;
  unsigned short o[8];
#pragma unroll
  for (int j = 0; j < 8; ++j) {
    int c = c8 + j;
    float mu = sum[c] * inv_n;
    float var = sumsq[c] * inv_n - mu * mu;
    float sc = rsqrtf(var + 1e-5f) * gamma[c];
    o[j] = f2bf((f[j] - mu) * sc + beta[c]);
  }
  *(uint4*)(out + (size_t)r * 512 + c8) = *(uint4*)o;
}

// ---------------- pooling ----------------
__global__ void bounds_kernel(const int* __restrict__ batch, int* __restrict__ gstart, int n) {
  int g = threadIdx.x;
  if (g > GG) return;
  int lo = 0, hi = n;
  while (lo < hi) {
    int mid = (lo + hi) >> 1;
    if (batch[mid] < g) lo = mid + 1; else hi = mid;
  }
  gstart[g] = lo;
}

__global__ __launch_bounds__(256) void pool_bf16(const unsigned short* __restrict__ emb16,
                                                 const int* __restrict__ gstart,
                                                 float* __restrict__ gsum) {
  int g = blockIdx.x;
  int chunk = blockIdx.y;
  int c2 = threadIdx.x * 2;
  int s = gstart[g], e = gstart[g + 1];
  int len = e - s;
  int per = (len + 7) >> 3;
  int r0 = s + chunk * per;
  int r1 = min(r0 + per, e);
  float ax = 0.f, ay = 0.f;
  for (int r = r0; r < r1; ++r) {
    unsigned u = *(const unsigned*)(emb16 + (size_t)r * 512 + c2);
    ax += bl(u); ay += bh(u);
  }
  if (r1 > r0) {
    atomicAdd(&gsum[g * 512 + c2], ax);
    atomicAdd(&gsum[g * 512 + c2 + 1], ay);
  }
}

__global__ void pool_div_kernel(const float* __restrict__ gsum, const int* __restrict__ gstart,
                                float* __restrict__ gemb) {
  int idx = blockIdx.x * 256 + threadIdx.x;
  if (idx >= GG * 512) return;
  int g = idx >> 9;
  float cntf = fmaxf((float)(gstart[g + 1] - gstart[g]), 1.0f);
  gemb[idx] = gsum[idx] / cntf;
}

// ---------------- small dense MLP (M=64, fp32) ----------------
__global__ void small_gemm(const float* __restrict__ A, const float* __restrict__ W,
                           const float* __restrict__ b, float* __restrict__ C,
                           int M, int K, int Nn, int relu) {
  int idx = blockIdx.x * 256 + threadIdx.x;
  if (idx >= M * Nn) return;
  int r = idx / Nn, n = idx - r * Nn;
  const float* a = A + (size_t)r * K;
  float acc = b[n];
  for (int k = 0; k < K; ++k) acc = fmaf(a[k], W[(size_t)k * Nn + n], acc);
  if (relu) acc = fmaxf(acc, 0.f);
  C[idx] = acc;
}

__global__ void cls_out_kernel(const float* __restrict__ t3, const float* __restrict__ W,
                               const float* __restrict__ b, float* __restrict__ out) {
  int g = blockIdx.x;
  int lane = threadIdx.x;  // 64
  float v = 0.f;
  float logit = -1e30f;
  if (lane < CCLS) {
    v = b[lane];
    for (int k = 0; k < 128; ++k) v = fmaf(t3[g * 128 + k], W[k * CCLS + lane], v);
    logit = v;
  }
  float m = logit;
  for (int off = 8; off >= 1; off >>= 1) m = fmaxf(m, __shfl_down(m, off, 64));
  m = __shfl(m, 0, 64);
  float ex = (lane < CCLS) ? expf(v - m) : 0.f;
  float s = ex;
  for (int off = 8; off >= 1; off >>= 1) s += __shfl_down(s, off, 64);
  s = __shfl(s, 0, 64);
  if (lane < CCLS) out[g * CCLS + lane] = v - m - logf(s);
}

__global__ void ep_final_bf16(const unsigned short* __restrict__ C2, const float* __restrict__ w,
                              const float* __restrict__ b3, float* __restrict__ out, int M) {
  int row = blockIdx.x * 4 + (threadIdx.x >> 6);
  if (row >= M) return;
  int lane = threadIdx.x & 63;
  int c2 = lane * 2;
  unsigned u = *(const unsigned*)(C2 + (size_t)row * 128 + c2);
  float2 wv = *(const float2*)(w + c2);
  float s = bl(u) * wv.x + bh(u) * wv.y;
  for (int off = 32; off >= 1; off >>= 1) s += __shfl_down(s, off, 64);
  if (lane == 0) out[row] = 1.f / (1.f + expf(-(s + b3[0])));
}

// ---------------- launch ----------------
extern "C" void kernel_launch(void* const* d_in, const int* in_sizes, int n_in,
                              void* d_out, int out_size, void* d_ws, size_t ws_size,
                              hipStream_t stream) {
  const float* x = (const float*)d_in[0];
  const int* edge_index = (const int*)d_in[1];
  const int* batch = (const int*)d_in[2];
  const int* cand = (const int*)d_in[3];
  const float* cW1 = (const float*)d_in[4];
  const float* cb1 = (const float*)d_in[5];
  const float* cW2 = (const float*)d_in[6];
  const float* cb2 = (const float*)d_in[7];
  const float* cgamma = (const float*)d_in[8];
  const float* cbeta = (const float*)d_in[9];
  const float* ceps = (const float*)d_in[10];
  const float* ncW1 = (const float*)d_in[11];
  const float* ncb1 = (const float*)d_in[12];
  const float* ncW2 = (const float*)d_in[13];
  const float* ncb2 = (const float*)d_in[14];
  const float* ncW3 = (const float*)d_in[15];
  const float* ncb3 = (const float*)d_in[16];
  const float* ncW4 = (const float*)d_in[17];
  const float* ncb4 = (const float*)d_in[18];
  const float* epW1 = (const float*)d_in[19];
  const float* epb1 = (const float*)d_in[20];
  const float* epW2 = (const float*)d_in[21];
  const float* epb2 = (const float*)d_in[22];
  const float* epW3 = (const float*)d_in[23];
  const float* epb3 = (const float*)d_in[24];

  char* ws = (char*)d_ws;
  size_t off = 0;
  auto alloc = [&](size_t bytes) -> void* {
    off = (off + 255) & ~(size_t)255;
    void* p = ws + off;
    off += bytes;
    return p;
  };
  // contiguous zero zone: cnt | bnsum | bnsumsq | gsum
  size_t zz_bytes = (size_t)NN * 4 + 512 * 4 + 512 * 4 + (size_t)GG * 512 * 4;
  char* zz = (char*)alloc(zz_bytes);
  int* cnt = (int*)zz;
  float* bnsum = (float*)(zz + (size_t)NN * 4);
  float* bnsumsq = bnsum + 512;
  float* gsum = bnsumsq + 512;
  int* rowptr = (int*)alloc((size_t)(NN + 1) * 4);
  int* cursor = (int*)alloc((size_t)NN * 4);
  int* csr_src = (int*)alloc((size_t)EE * 4);
  unsigned short* x16 = (unsigned short*)alloc((size_t)NN * 128 * 2);
  unsigned short* g16a = (unsigned short*)alloc((size_t)NN * 128 * 2);
  unsigned short* g16b = (unsigned short*)alloc((size_t)NN * 128 * 2);
  unsigned short* emb16 = (unsigned short*)alloc((size_t)NN * 512 * 2);
  unsigned short* C1 = (unsigned short*)alloc((size_t)NC * 256 * 2);
  unsigned short* C2 = (unsigned short*)alloc((size_t)NC * 128 * 2);
  unsigned short* WT1 = (unsigned short*)alloc((size_t)LL * 16384 * 2);
  unsigned short* WT2 = (unsigned short*)alloc((size_t)LL * 16384 * 2);
  unsigned short* W1T = (unsigned short*)alloc((size_t)1024 * 256 * 2);
  unsigned short* W2T = (unsigned short*)alloc((size_t)256 * 128 * 2);
  int* gstart = (int*)alloc(65 * 4);
  float* gemb = (float*)alloc((size_t)GG * 512 * 4);
  float* t1 = (float*)alloc((size_t)GG * 256 * 4);
  float* t2 = (float*)alloc((size_t)GG * 128 * 4);
  float* t3 = (float*)alloc((size_t)GG * 128 * 4);

  const int* esrc = edge_index;
  const int* edst = edge_index + EE;

  hipMemsetAsync(zz, 0, zz_bytes, stream);
  hist_kernel<<<(EE + 255) / 256, 256, 0, stream>>>(edst, cnt, EE);
  scan2_kernel<<<1, 1024, 0, stream>>>(cnt, rowptr, cursor, NN);
  fill_kernel<<<(EE + 255) / 256, 256, 0, stream>>>(esrc, edst, cursor, csr_src, EE);
  f2b4_kernel<<<(NN * 128 / 4 + 255) / 256, 256, 0, stream>>>(x, x16, NN * 128 / 4);
  convert_trunk<<<(LL * 16384 + 255) / 256, 256, 0, stream>>>(cW1, cW2, WT1, WT2);
  f2bT_kernel<<<(1024 * 256 + 255) / 256, 256, 0, stream>>>(epW1, W1T, 1024, 256);
  f2bT_kernel<<<(256 * 128 + 255) / 256, 256, 0, stream>>>(epW2, W2T, 256, 128);

  for (int l = 0; l < LL; ++l) {
    const unsigned short* h16 = (l == 0) ? x16 : (emb16 + (size_t)(l - 1) * 128);
    int ld = (l == 0) ? 128 : 512;
    aggregate_bf16<<<(NN + 3) / 4, 256, 0, stream>>>(h16, ld, rowptr, csr_src, ceps + l, g16a, NN);
    mfma_gemm_bt<<<dim3((NN + 127) / 128, 1), 256, 0, stream>>>(
        g16a, 128, WT1 + (size_t)l * 16384, 128, cb1 + l * 128, g16b, 128, NN);
    mfma_gemm_bt<<<dim3((NN + 127) / 128, 1), 256, 0, stream>>>(
        g16b, 128, WT2 + (size_t)l * 16384, 128, cb2 + l * 128, g16a, 128, NN);
    bn_stats_bf16<<<(NN + 511) / 512, 256, 0, stream>>>(g16a, bnsum + l * 128, bnsumsq + l * 128, NN);
    bn_apply_bf16<<<(NN * 16 + 255) / 256, 256, 0, stream>>>(
        g16a, bnsum + l * 128, bnsumsq + l * 128, cgamma + l * 128, cbeta + l * 128,
        emb16 + (size_t)l * 128, NN);
  }

  bounds_kernel<<<1, 128, 0, stream>>>(batch, gstart, NN);
  pool_bf16<<<dim3(GG, 8), 256, 0, stream>>>(emb16, gstart, gsum);
  pool_div_kernel<<<(GG * 512 + 255) / 256, 256, 0, stream>>>(gsum, gstart, gemb);
  small_gemm<<<(GG * 256 + 255) / 256, 256, 0, stream>>>(gemb, ncW1, ncb1, t1, GG, 512, 256, 1);
  small_gemm<<<(GG * 128 + 255) / 256, 256, 0, stream>>>(t1, ncW2, ncb2, t2, GG, 256, 128, 1);
  small_gemm<<<(GG * 128 + 255) / 256, 256, 0, stream>>>(t2, ncW3, ncb3, t3, GG, 128, 128, 1);
  cls_out_kernel<<<GG, 64, 0, stream>>>(t3, ncW4, ncb4, (float*)d_out);

  mfma_gemm_gather<<<dim3((NC + 127) / 128, 2), 256, 0, stream>>>(emb16, cand, W1T, epb1, C1, NC);
  mfma_gemm_bt<<<dim3((NC + 127) / 128, 1), 256, 0, stream>>>(C1, 256, W2T, 256, epb2, C2, 128, NC);
  ep_final_bf16<<<(NC + 3) / 4, 256, 0, stream>>>(C2, epW3, epb3, (float*)d_out + GG * CCLS, NC);
}

// Round 3
// 2101.102 us; speedup vs baseline: 1.2301x; 1.0704x over previous
//
#include <hip/hip_runtime.h>
#include <math.h>

#define NN 100000
#define EE 1600000
#define GG 64
#define HH 128
#define LL 4
#define CCLS 16
#define NC 100000
#define LDK 40  // padded LDS row stride in bf16 elems (80 B)

typedef __attribute__((ext_vector_type(8))) short bf16x8;
typedef __attribute__((ext_vector_type(4))) float f32x4;

__device__ __forceinline__ unsigned short f2bf(float x) {
  union { float f; unsigned int u; } v; v.f = x;
  unsigned int r = v.u + 0x7fffu + ((v.u >> 16) & 1u);
  return (unsigned short)(r >> 16);
}
__device__ __forceinline__ float bl(unsigned u) {
  union { unsigned u; float f; } v; v.u = u << 16; return v.f;
}
__device__ __forceinline__ float bh(unsigned u) {
  union { unsigned u; float f; } v; v.u = u & 0xffff0000u; return v.f;
}

// ---------------- CSR build ----------------
__global__ void hist_kernel(const int* __restrict__ dst, int* __restrict__ cnt, int E) {
  int e = blockIdx.x * 256 + threadIdx.x;
  if (e < E) atomicAdd(&cnt[dst[e]], 1);
}

// 3-phase scan: p1 block sums, p2 scan of block sums, p3 write prefixes
__global__ __launch_bounds__(256) void scan_p1(const int* __restrict__ cnt,
                                               int* __restrict__ bsum, int n) {
  __shared__ int red[256];
  int tid = threadIdx.x;
  int base = blockIdx.x * 1024 + tid * 4;
  int s = 0;
  if (base + 3 < n) {
    int4 v = *(const int4*)(cnt + base);
    s = v.x + v.y + v.z + v.w;
  } else {
    for (int i = 0; i < 4; ++i) if (base + i < n) s += cnt[base + i];
  }
  red[tid] = s;
  __syncthreads();
  for (int st = 128; st >= 1; st >>= 1) {
    if (tid < st) red[tid] += red[tid + st];
    __syncthreads();
  }
  if (tid == 0) bsum[blockIdx.x] = red[0];
}

__global__ void scan_p2(int* __restrict__ bsum, int* __restrict__ rowptr, int nb, int n) {
  __shared__ int buf[128];
  int tid = threadIdx.x;
  int v = (tid < nb) ? bsum[tid] : 0;
  buf[tid] = v;
  __syncthreads();
  for (int off = 1; off < 128; off <<= 1) {
    int t = (tid >= off) ? buf[tid - off] : 0;
    __syncthreads();
    buf[tid] += t;
    __syncthreads();
  }
  if (tid < nb) bsum[tid] = buf[tid] - v;  // exclusive
  if (tid == 127) rowptr[n] = buf[127];    // total
}

__global__ __launch_bounds__(256) void scan_p3(const int* __restrict__ cnt,
                                               const int* __restrict__ bsum,
                                               int* __restrict__ rowptr,
                                               int* __restrict__ cursor, int n) {
  __shared__ int red[256];
  int tid = threadIdx.x;
  int base = blockIdx.x * 1024 + tid * 4;
  int v[4] = {0, 0, 0, 0};
  if (base + 3 < n) {
    int4 t = *(const int4*)(cnt + base);
    v[0] = t.x; v[1] = t.y; v[2] = t.z; v[3] = t.w;
  } else {
    for (int i = 0; i < 4; ++i) if (base + i < n) v[i] = cnt[base + i];
  }
  int s = v[0] + v[1] + v[2] + v[3];
  red[tid] = s;
  __syncthreads();
  for (int off = 1; off < 256; off <<= 1) {
    int t = (tid >= off) ? red[tid - off] : 0;
    __syncthreads();
    red[tid] += t;
    __syncthreads();
  }
  int run = bsum[blockIdx.x] + red[tid] - s;
  int4 o;
  o.x = run; o.y = run + v[0]; o.z = o.y + v[1]; o.w = o.z + v[2];
  if (base + 3 < n) {
    *(int4*)(rowptr + base) = o;
    *(int4*)(cursor + base) = o;
  } else {
    int oo[4] = {o.x, o.y, o.z, o.w};
    for (int i = 0; i < 4; ++i)
      if (base + i < n) { rowptr[base + i] = oo[i]; cursor[base + i] = oo[i]; }
  }
}

__global__ void fill_kernel(const int* __restrict__ src, const int* __restrict__ dst,
                            int* __restrict__ cursor, int* __restrict__ csr_src, int E) {
  int e = blockIdx.x * 256 + threadIdx.x;
  if (e < E) {
    int p = atomicAdd(&cursor[dst[e]], 1);
    csr_src[p] = src[e];
  }
}

// ---------------- converts ----------------
__global__ void f2b4_kernel(const float* __restrict__ in, unsigned short* __restrict__ out, int n4) {
  int i = blockIdx.x * 256 + threadIdx.x;
  if (i >= n4) return;
  float4 v = ((const float4*)in)[i];
  unsigned short r[4] = {f2bf(v.x), f2bf(v.y), f2bf(v.z), f2bf(v.w)};
  *(uint2*)(out + (size_t)i * 4) = *(uint2*)r;
}

// cW1/cW2 [L][K=128][N=128] fp32 -> WT [L][N][K] bf16 (both at once)
__global__ void convert_trunk(const float* __restrict__ cW1, const float* __restrict__ cW2,
                              unsigned short* __restrict__ WT1, unsigned short* __restrict__ WT2) {
  int idx = blockIdx.x * 256 + threadIdx.x;
  if (idx >= LL * 16384) return;
  int l = idx >> 14, r = idx & 16383, k = r >> 7, n = r & 127;
  WT1[l * 16384 + n * 128 + k] = f2bf(cW1[idx]);
  WT2[l * 16384 + n * 128 + k] = f2bf(cW2[idx]);
}

// in [K][Nn] fp32 -> out [Nn][K] bf16
__global__ void f2bT_kernel(const float* __restrict__ in, unsigned short* __restrict__ out,
                            int K, int Nn) {
  int idx = blockIdx.x * 256 + threadIdx.x;
  if (idx >= K * Nn) return;
  int k = idx / Nn, n = idx - k * Nn;
  out[(size_t)n * K + k] = f2bf(in[idx]);
}

// ---------------- GIN aggregate (bf16 gather, fp32 acc, bf16 out) ----------------
__global__ void aggregate_bf16(const unsigned short* __restrict__ h16, int ld,
                               const int* __restrict__ rowptr,
                               const int* __restrict__ csr_src,
                               const float* __restrict__ ceps_l,
                               unsigned short* __restrict__ out, int n) {
  int node = blockIdx.x * 4 + (threadIdx.x >> 6);
  if (node >= n) return;
  int lane = threadIdx.x & 63;
  int c2 = lane * 2;
  float eps1 = 1.0f + *ceps_l;
  float ax = 0.f, ay = 0.f;
  int b = rowptr[node], e = rowptr[node + 1];
  for (int j = b; j < e; ++j) {
    int s = csr_src[j];
    unsigned u = *(const unsigned*)(h16 + (size_t)s * ld + c2);
    ax += bl(u); ay += bh(u);
  }
  unsigned hu = *(const unsigned*)(h16 + (size_t)node * ld + c2);
  ax = fmaf(eps1, bl(hu), ax);
  ay = fmaf(eps1, bh(hu), ay);
  unsigned short o[2] = {f2bf(ax), f2bf(ay)};
  *(unsigned*)(out + (size_t)node * 128 + c2) = *(unsigned*)o;
}

// ---------------- bf16 MFMA GEMM: C[M,ldc]=relu(A[M,lda(K cols)] @ WT^T + bias) ----------------
// WT is pre-transposed [Nout][K] bf16. Block tile 128x128, 4 waves 2x2, wave 64x64.
__global__ __launch_bounds__(256) void mfma_gemm_bt(
    const unsigned short* __restrict__ A16, int lda,
    const unsigned short* __restrict__ WT, int K,
    const float* __restrict__ bias,
    unsigned short* __restrict__ C16, int ldc, int M) {
  __shared__ unsigned short As[128 * LDK];
  __shared__ unsigned short Bs[128 * LDK];
  const int tid = threadIdx.x;
  const int bm = blockIdx.x * 128;
  const int bn = blockIdx.y * 128;
  const int lane = tid & 63;
  const int wave = tid >> 6;
  const int wr = (wave >> 1) << 6;
  const int wc = (wave & 1) << 6;
  f32x4 acc[4][4] = {};
  const int ar = tid >> 1;
  const int ah = (tid & 1) << 4;
  int gra = bm + ar; if (gra >= M) gra = M - 1;
  const unsigned short* Arow = A16 + (size_t)gra * lda;
  const unsigned short* Brow = WT + (size_t)(bn + ar) * K;
  const int mrow = lane & 15;
  const int kq = (lane >> 4) << 3;
  const int nks = K >> 5;

  for (int ks = 0; ks < nks; ++ks) {
    const int k0 = ks << 5;
    {
      const uint4* s = (const uint4*)(Arow + k0 + ah);
      *(uint4*)(As + ar * LDK + ah) = s[0];
      *(uint4*)(As + ar * LDK + ah + 8) = s[1];
    }
    {
      const uint4* s = (const uint4*)(Brow + k0 + ah);
      *(uint4*)(Bs + ar * LDK + ah) = s[0];
      *(uint4*)(Bs + ar * LDK + ah + 8) = s[1];
    }
    __syncthreads();
    bf16x8 af[4], bfv[4];
#pragma unroll
    for (int t = 0; t < 4; ++t)
      af[t] = *(const bf16x8*)(As + (wr + t * 16 + mrow) * LDK + kq);
#pragma unroll
    for (int t = 0; t < 4; ++t)
      bfv[t] = *(const bf16x8*)(Bs + (wc + t * 16 + mrow) * LDK + kq);
#pragma unroll
    for (int mt = 0; mt < 4; ++mt)
#pragma unroll
      for (int nt = 0; nt < 4; ++nt)
        acc[mt][nt] = __builtin_amdgcn_mfma_f32_16x16x32_bf16(af[mt], bfv[nt], acc[mt][nt], 0, 0, 0);
    __syncthreads();
  }
  const int crow = (lane >> 4) << 2;
  const int ccol = lane & 15;
#pragma unroll
  for (int nt = 0; nt < 4; ++nt) {
    int cbase = bn + wc + nt * 16 + ccol;
    float bz = bias[cbase];
#pragma unroll
    for (int mt = 0; mt < 4; ++mt) {
      int rbase = bm + wr + mt * 16 + crow;
#pragma unroll
      for (int i = 0; i < 4; ++i) {
        int r = rbase + i;
        if (r < M) C16[(size_t)r * ldc + cbase] = f2bf(fmaxf(acc[mt][nt][i] + bz, 0.f));
      }
    }
  }
}

// ep GEMM1 with fused candidate gather: A row = [emb16[cand0] | emb16[cand1]], K=1024
// Full N=256 per block so A is gathered ONCE. Waves 2x2; wave tile 64(m) x 128(n).
__global__ __launch_bounds__(256) void mfma_gemm_gather(
    const unsigned short* __restrict__ emb16, const int* __restrict__ cand,
    const unsigned short* __restrict__ WT /*[256][1024]*/,
    const float* __restrict__ bias,
    unsigned short* __restrict__ C16 /*[M,256]*/, int M) {
  __shared__ unsigned short As[128 * LDK];
  __shared__ unsigned short Bs[256 * LDK];
  const int tid = threadIdx.x;
  const int bm = blockIdx.x * 128;
  const int lane = tid & 63;
  const int wave = tid >> 6;
  const int wr = (wave >> 1) << 6;
  const int wc = (wave & 1) << 7;  // 0 or 128
  f32x4 acc[4][8] = {};
  const int ar = tid >> 1;
  const int ah = (tid & 1) << 4;
  int gra = bm + ar; if (gra >= M) gra = M - 1;
  const int node0 = cand[gra];
  const int node1 = cand[NC + gra];
  const unsigned short* Brow = WT + (size_t)tid * 1024;  // one full output-col row per thread
  const int mrow = lane & 15;
  const int kq = (lane >> 4) << 3;

  for (int ks = 0; ks < 32; ++ks) {
    const int k0 = ks << 5;
    {
      int node = (k0 < 512) ? node0 : node1;
      const uint4* s = (const uint4*)(emb16 + (size_t)node * 512 + (k0 & 511) + ah);
      *(uint4*)(As + ar * LDK + ah) = s[0];
      *(uint4*)(As + ar * LDK + ah + 8) = s[1];
    }
    {
      const uint4* s = (const uint4*)(Brow + k0);
      *(uint4*)(Bs + tid * LDK) = s[0];
      *(uint4*)(Bs + tid * LDK + 8) = s[1];
      *(uint4*)(Bs + tid * LDK + 16) = s[2];
      *(uint4*)(Bs + tid * LDK + 24) = s[3];
    }
    __syncthreads();
    bf16x8 af[4], bfv[8];
#pragma unroll
    for (int t = 0; t < 4; ++t)
      af[t] = *(const bf16x8*)(As + (wr + t * 16 + mrow) * LDK + kq);
#pragma unroll
    for (int t = 0; t < 8; ++t)
      bfv[t] = *(const bf16x8*)(Bs + (wc + t * 16 + mrow) * LDK + kq);
#pragma unroll
    for (int mt = 0; mt < 4; ++mt)
#pragma unroll
      for (int nt = 0; nt < 8; ++nt)
        acc[mt][nt] = __builtin_amdgcn_mfma_f32_16x16x32_bf16(af[mt], bfv[nt], acc[mt][nt], 0, 0, 0);
    __syncthreads();
  }
  const int crow = (lane >> 4) << 2;
  const int ccol = lane & 15;
#pragma unroll
  for (int nt = 0; nt < 8; ++nt) {
    int cbase = wc + nt * 16 + ccol;
    float bz = bias[cbase];
#pragma unroll
    for (int mt = 0; mt < 4; ++mt) {
      int rbase = bm + wr + mt * 16 + crow;
#pragma unroll
      for (int i = 0; i < 4; ++i) {
        int r = rbase + i;
        if (r < M) C16[(size_t)r * 256 + cbase] = f2bf(fmaxf(acc[mt][nt][i] + bz, 0.f));
      }
    }
  }
}

// ---------------- BatchNorm (bf16 in) ----------------
__global__ __launch_bounds__(256) void bn_stats_bf16(const unsigned short* __restrict__ z,
                                                     float* __restrict__ sum,
                                                     float* __restrict__ sumsq, int n) {
  __shared__ float red[16][128];
  int tid = threadIdx.x;
  int cg = tid & 15, rg = tid >> 4;
  int c8 = cg * 8;
  int base = blockIdx.x * 512;
  int rend = min(base + 512, n);
  float s[8] = {}, q[8] = {};
  for (int r = base + rg; r < rend; r += 16) {
    uint4 v = *(const uint4*)(z + (size_t)r * 128 + c8);
    float f[8] = {bl(v.x), bh(v.x), bl(v.y), bh(v.y), bl(v.z), bh(v.z), bl(v.w), bh(v.w)};
#pragma unroll
    for (int j = 0; j < 8; ++j) { s[j] += f[j]; q[j] += f[j] * f[j]; }
  }
#pragma unroll
  for (int j = 0; j < 8; ++j) red[rg][c8 + j] = s[j];
  __syncthreads();
  for (int step = 8; step >= 1; step >>= 1) {
    if (rg < step)
#pragma unroll
      for (int j = 0; j < 8; ++j) red[rg][c8 + j] += red[rg + step][c8 + j];
    __syncthreads();
  }
  if (rg == 0)
#pragma unroll
    for (int j = 0; j < 8; ++j) atomicAdd(&sum[c8 + j], red[0][c8 + j]);
  __syncthreads();
#pragma unroll
  for (int j = 0; j < 8; ++j) red[rg][c8 + j] = q[j];
  __syncthreads();
  for (int step = 8; step >= 1; step >>= 1) {
    if (rg < step)
#pragma unroll
      for (int j = 0; j < 8; ++j) red[rg][c8 + j] += red[rg + step][c8 + j];
    __syncthreads();
  }
  if (rg == 0)
#pragma unroll
    for (int j = 0; j < 8; ++j) atomicAdd(&sumsq[c8 + j], red[0][c8 + j]);
}

__global__ void bn_apply_bf16(const unsigned short* __restrict__ z,
                              const float* __restrict__ sum, const float* __restrict__ sumsq,
                              const float* __restrict__ gamma, const float* __restrict__ beta,
                              unsigned short* __restrict__ out /* emb16 + l*128, ld 512 */, int n) {
  int idx = blockIdx.x * 256 + threadIdx.x;
  if (idx >= n * 16) return;
  int r = idx >> 4, c8 = (idx & 15) << 3;
  uint4 v = *(const uint4*)(z + (size_t)r * 128 + c8);
  float f[8] = {bl(v.x), bh(v.x), bl(v.y), bh(v.y), bl(v.z), bh(v.z), bl(v.w), bh(v.w)};
  const float inv_n = 1.0f / (float)NN;
  unsigned short o[8];
#pragma unroll
  for (int j = 0; j < 8; ++j) {
    int c = c8 + j;
    float mu = sum[c] * inv_n;
    float var = sumsq[c] * inv_n - mu * mu;
    float sc = rsqrtf(var + 1e-5f) * gamma[c];
    o[j] = f2bf((f[j] - mu) * sc + beta[c]);
  }
  *(uint4*)(out + (size_t)r * 512 + c8) = *(uint4*)o;
}

// ---------------- pooling ----------------
__global__ void bounds_kernel(const int* __restrict__ batch, int* __restrict__ gstart, int n) {
  int g = threadIdx.x;
  if (g > GG) return;
  int lo = 0, hi = n;
  while (lo < hi) {
    int mid = (lo + hi) >> 1;
    if (batch[mid] < g) lo = mid + 1; else hi = mid;
  }
  gstart[g] = lo;
}

__global__ __launch_bounds__(256) void pool_bf16(const unsigned short* __restrict__ emb16,
                                                 const int* __restrict__ gstart,
                                                 float* __restrict__ gsum) {
  int g = blockIdx.x;
  int chunk = blockIdx.y;
  int c2 = threadIdx.x * 2;
  int s = gstart[g], e = gstart[g + 1];
  int len = e - s;
  int per = (len + 7) >> 3;
  int r0 = s + chunk * per;
  int r1 = min(r0 + per, e);
  float ax = 0.f, ay = 0.f;
  for (int r = r0; r < r1; ++r) {
    unsigned u = *(const unsigned*)(emb16 + (size_t)r * 512 + c2);
    ax += bl(u); ay += bh(u);
  }
  if (r1 > r0) {
    atomicAdd(&gsum[g * 512 + c2], ax);
    atomicAdd(&gsum[g * 512 + c2 + 1], ay);
  }
}

__global__ void pool_div_kernel(const float* __restrict__ gsum, const int* __restrict__ gstart,
                                float* __restrict__ gemb) {
  int idx = blockIdx.x * 256 + threadIdx.x;
  if (idx >= GG * 512) return;
  int g = idx >> 9;
  float cntf = fmaxf((float)(gstart[g + 1] - gstart[g]), 1.0f);
  gemb[idx] = gsum[idx] / cntf;
}

// ---------------- small dense MLP (M=64, fp32) ----------------
__global__ void small_gemm(const float* __restrict__ A, const float* __restrict__ W,
                           const float* __restrict__ b, float* __restrict__ C,
                           int M, int K, int Nn, int relu) {
  int idx = blockIdx.x * 256 + threadIdx.x;
  if (idx >= M * Nn) return;
  int r = idx / Nn, n = idx - r * Nn;
  const float* a = A + (size_t)r * K;
  float acc = b[n];
  for (int k = 0; k < K; ++k) acc = fmaf(a[k], W[(size_t)k * Nn + n], acc);
  if (relu) acc = fmaxf(acc, 0.f);
  C[idx] = acc;
}

__global__ void cls_out_kernel(const float* __restrict__ t3, const float* __restrict__ W,
                               const float* __restrict__ b, float* __restrict__ out) {
  int g = blockIdx.x;
  int lane = threadIdx.x;  // 64
  float v = 0.f;
  float logit = -1e30f;
  if (lane < CCLS) {
    v = b[lane];
    for (int k = 0; k < 128; ++k) v = fmaf(t3[g * 128 + k], W[k * CCLS + lane], v);
    logit = v;
  }
  float m = logit;
  for (int off = 8; off >= 1; off >>= 1) m = fmaxf(m, __shfl_down(m, off, 64));
  m = __shfl(m, 0, 64);
  float ex = (lane < CCLS) ? expf(v - m) : 0.f;
  float s = ex;
  for (int off = 8; off >= 1; off >>= 1) s += __shfl_down(s, off, 64);
  s = __shfl(s, 0, 64);
  if (lane < CCLS) out[g * CCLS + lane] = v - m - logf(s);
}

__global__ void ep_final_bf16(const unsigned short* __restrict__ C2, const float* __restrict__ w,
                              const float* __restrict__ b3, float* __restrict__ out, int M) {
  int row = blockIdx.x * 4 + (threadIdx.x >> 6);
  if (row >= M) return;
  int lane = threadIdx.x & 63;
  int c2 = lane * 2;
  unsigned u = *(const unsigned*)(C2 + (size_t)row * 128 + c2);
  float2 wv = *(const float2*)(w + c2);
  float s = bl(u) * wv.x + bh(u) * wv.y;
  for (int off = 32; off >= 1; off >>= 1) s += __shfl_down(s, off, 64);
  if (lane == 0) out[row] = 1.f / (1.f + expf(-(s + b3[0])));
}

// ---------------- launch ----------------
extern "C" void kernel_launch(void* const* d_in, const int* in_sizes, int n_in,
                              void* d_out, int out_size, void* d_ws, size_t ws_size,
                              hipStream_t stream) {
  const float* x = (const float*)d_in[0];
  const int* edge_index = (const int*)d_in[1];
  const int* batch = (const int*)d_in[2];
  const int* cand = (const int*)d_in[3];
  const float* cW1 = (const float*)d_in[4];
  const float* cb1 = (const float*)d_in[5];
  const float* cW2 = (const float*)d_in[6];
  const float* cb2 = (const float*)d_in[7];
  const float* cgamma = (const float*)d_in[8];
  const float* cbeta = (const float*)d_in[9];
  const float* ceps = (const float*)d_in[10];
  const float* ncW1 = (const float*)d_in[11];
  const float* ncb1 = (const float*)d_in[12];
  const float* ncW2 = (const float*)d_in[13];
  const float* ncb2 = (const float*)d_in[14];
  const float* ncW3 = (const float*)d_in[15];
  const float* ncb3 = (const float*)d_in[16];
  const float* ncW4 = (const float*)d_in[17];
  const float* ncb4 = (const float*)d_in[18];
  const float* epW1 = (const float*)d_in[19];
  const float* epb1 = (const float*)d_in[20];
  const float* epW2 = (const float*)d_in[21];
  const float* epb2 = (const float*)d_in[22];
  const float* epW3 = (const float*)d_in[23];
  const float* epb3 = (const float*)d_in[24];

  char* ws = (char*)d_ws;
  size_t off = 0;
  auto alloc = [&](size_t bytes) -> void* {
    off = (off + 255) & ~(size_t)255;
    void* p = ws + off;
    off += bytes;
    return p;
  };
  // contiguous zero zone: cnt | bnsum | bnsumsq | gsum
  size_t zz_bytes = (size_t)NN * 4 + 512 * 4 + 512 * 4 + (size_t)GG * 512 * 4;
  char* zz = (char*)alloc(zz_bytes);
  int* cnt = (int*)zz;
  float* bnsum = (float*)(zz + (size_t)NN * 4);
  float* bnsumsq = bnsum + 512;
  float* gsum = bnsumsq + 512;
  int* rowptr = (int*)alloc((size_t)(NN + 1) * 4);
  int* cursor = (int*)alloc((size_t)NN * 4);
  int* csr_src = (int*)alloc((size_t)EE * 4);
  int* bsum = (int*)alloc(128 * 4);
  unsigned short* x16 = (unsigned short*)alloc((size_t)NN * 128 * 2);
  unsigned short* g16a = (unsigned short*)alloc((size_t)NN * 128 * 2);
  unsigned short* g16b = (unsigned short*)alloc((size_t)NN * 128 * 2);
  unsigned short* emb16 = (unsigned short*)alloc((size_t)NN * 512 * 2);
  unsigned short* C1 = (unsigned short*)alloc((size_t)NC * 256 * 2);
  unsigned short* C2 = (unsigned short*)alloc((size_t)NC * 128 * 2);
  unsigned short* WT1 = (unsigned short*)alloc((size_t)LL * 16384 * 2);
  unsigned short* WT2 = (unsigned short*)alloc((size_t)LL * 16384 * 2);
  unsigned short* W1T = (unsigned short*)alloc((size_t)1024 * 256 * 2);
  unsigned short* W2T = (unsigned short*)alloc((size_t)256 * 128 * 2);
  int* gstart = (int*)alloc(65 * 4);
  float* gemb = (float*)alloc((size_t)GG * 512 * 4);
  float* t1 = (float*)alloc((size_t)GG * 256 * 4);
  float* t2 = (float*)alloc((size_t)GG * 128 * 4);
  float* t3 = (float*)alloc((size_t)GG * 128 * 4);

  const int* esrc = edge_index;
  const int* edst = edge_index + EE;
  const int nblk = (NN + 1023) / 1024;  // 98

  hipMemsetAsync(zz, 0, zz_bytes, stream);
  hist_kernel<<<(EE + 255) / 256, 256, 0, stream>>>(edst, cnt, EE);
  scan_p1<<<nblk, 256, 0, stream>>>(cnt, bsum, NN);
  scan_p2<<<1, 128, 0, stream>>>(bsum, rowptr, nblk, NN);
  scan_p3<<<nblk, 256, 0, stream>>>(cnt, bsum, rowptr, cursor, NN);
  fill_kernel<<<(EE + 255) / 256, 256, 0, stream>>>(esrc, edst, cursor, csr_src, EE);
  f2b4_kernel<<<(NN * 128 / 4 + 255) / 256, 256, 0, stream>>>(x, x16, NN * 128 / 4);
  convert_trunk<<<(LL * 16384 + 255) / 256, 256, 0, stream>>>(cW1, cW2, WT1, WT2);
  f2bT_kernel<<<(1024 * 256 + 255) / 256, 256, 0, stream>>>(epW1, W1T, 1024, 256);
  f2bT_kernel<<<(256 * 128 + 255) / 256, 256, 0, stream>>>(epW2, W2T, 256, 128);

  for (int l = 0; l < LL; ++l) {
    const unsigned short* h16 = (l == 0) ? x16 : (emb16 + (size_t)(l - 1) * 128);
    int ld = (l == 0) ? 128 : 512;
    aggregate_bf16<<<(NN + 3) / 4, 256, 0, stream>>>(h16, ld, rowptr, csr_src, ceps + l, g16a, NN);
    mfma_gemm_bt<<<dim3((NN + 127) / 128, 1), 256, 0, stream>>>(
        g16a, 128, WT1 + (size_t)l * 16384, 128, cb1 + l * 128, g16b, 128, NN);
    mfma_gemm_bt<<<dim3((NN + 127) / 128, 1), 256, 0, stream>>>(
        g16b, 128, WT2 + (size_t)l * 16384, 128, cb2 + l * 128, g16a, 128, NN);
    bn_stats_bf16<<<(NN + 511) / 512, 256, 0, stream>>>(g16a, bnsum + l * 128, bnsumsq + l * 128, NN);
    bn_apply_bf16<<<(NN * 16 + 255) / 256, 256, 0, stream>>>(
        g16a, bnsum + l * 128, bnsumsq + l * 128, cgamma + l * 128, cbeta + l * 128,
        emb16 + (size_t)l * 128, NN);
  }

  bounds_kernel<<<1, 128, 0, stream>>>(batch, gstart, NN);
  pool_bf16<<<dim3(GG, 8), 256, 0, stream>>>(emb16, gstart, gsum);
  pool_div_kernel<<<(GG * 512 + 255) / 256, 256, 0, stream>>>(gsum, gstart, gemb);
  small_gemm<<<(GG * 256 + 255) / 256, 256, 0, stream>>>(gemb, ncW1, ncb1, t1, GG, 512, 256, 1);
  small_gemm<<<(GG * 128 + 255) / 256, 256, 0, stream>>>(t1, ncW2, ncb2, t2, GG, 256, 128, 1);
  small_gemm<<<(GG * 128 + 255) / 256, 256, 0, stream>>>(t2, ncW3, ncb3, t3, GG, 128, 128, 1);
  cls_out_kernel<<<GG, 64, 0, stream>>>(t3, ncW4, ncb4, (float*)d_out);

  mfma_gemm_gather<<<(NC + 127) / 128, 256, 0, stream>>>(emb16, cand, W1T, epb1, C1, NC);
  mfma_gemm_bt<<<dim3((NC + 127) / 128, 1), 256, 0, stream>>>(C1, 256, W2T, 256, epb2, C2, 128, NC);
  ep_final_bf16<<<(NC + 3) / 4, 256, 0, stream>>>(C2, epW3, epb3, (float*)d_out + GG * CCLS, NC);
}

// Round 4
// 1665.192 us; speedup vs baseline: 1.5521x; 1.2618x over previous
//
#include <hip/hip_runtime.h>
#include <math.h>

#define NN 100000
#define EE 1600000
#define GG 64
#define HH 128
#define LL 4
#define CCLS 16
#define NC 100000
#define LDK 40  // padded LDS row stride in bf16 elems (80 B, 16B-aligned)

typedef __attribute__((ext_vector_type(8))) short bf16x8;
typedef __attribute__((ext_vector_type(4))) float f32x4;

__device__ __forceinline__ unsigned short f2bf(float x) {
  union { float f; unsigned int u; } v; v.f = x;
  unsigned int r = v.u + 0x7fffu + ((v.u >> 16) & 1u);
  return (unsigned short)(r >> 16);
}
__device__ __forceinline__ float bl(unsigned u) {
  union { unsigned u; float f; } v; v.u = u << 16; return v.f;
}
__device__ __forceinline__ float bh(unsigned u) {
  union { unsigned u; float f; } v; v.u = u & 0xffff0000u; return v.f;
}

// ---------------- CSR build ----------------
__global__ void hist_kernel(const int* __restrict__ dst, int* __restrict__ cnt, int E) {
  int e = blockIdx.x * 256 + threadIdx.x;
  if (e < E) atomicAdd(&cnt[dst[e]], 1);
}

// 3-phase scan
__global__ __launch_bounds__(256) void scan_p1(const int* __restrict__ cnt,
                                               int* __restrict__ bsum, int n) {
  __shared__ int red[256];
  int tid = threadIdx.x;
  int base = blockIdx.x * 1024 + tid * 4;
  int s = 0;
  if (base + 3 < n) {
    int4 v = *(const int4*)(cnt + base);
    s = v.x + v.y + v.z + v.w;
  } else {
    for (int i = 0; i < 4; ++i) if (base + i < n) s += cnt[base + i];
  }
  red[tid] = s;
  __syncthreads();
  for (int st = 128; st >= 1; st >>= 1) {
    if (tid < st) red[tid] += red[tid + st];
    __syncthreads();
  }
  if (tid == 0) bsum[blockIdx.x] = red[0];
}

__global__ void scan_p2(int* __restrict__ bsum, int* __restrict__ rowptr, int nb, int n) {
  __shared__ int buf[128];
  int tid = threadIdx.x;
  int v = (tid < nb) ? bsum[tid] : 0;
  buf[tid] = v;
  __syncthreads();
  for (int off = 1; off < 128; off <<= 1) {
    int t = (tid >= off) ? buf[tid - off] : 0;
    __syncthreads();
    buf[tid] += t;
    __syncthreads();
  }
  if (tid < nb) bsum[tid] = buf[tid] - v;  // exclusive
  if (tid == 127) rowptr[n] = buf[127];    // total
}

__global__ __launch_bounds__(256) void scan_p3(const int* __restrict__ cnt,
                                               const int* __restrict__ bsum,
                                               int* __restrict__ rowptr,
                                               int* __restrict__ cursor, int n) {
  __shared__ int red[256];
  int tid = threadIdx.x;
  int base = blockIdx.x * 1024 + tid * 4;
  int v[4] = {0, 0, 0, 0};
  if (base + 3 < n) {
    int4 t = *(const int4*)(cnt + base);
    v[0] = t.x; v[1] = t.y; v[2] = t.z; v[3] = t.w;
  } else {
    for (int i = 0; i < 4; ++i) if (base + i < n) v[i] = cnt[base + i];
  }
  int s = v[0] + v[1] + v[2] + v[3];
  red[tid] = s;
  __syncthreads();
  for (int off = 1; off < 256; off <<= 1) {
    int t = (tid >= off) ? red[tid - off] : 0;
    __syncthreads();
    red[tid] += t;
    __syncthreads();
  }
  int run = bsum[blockIdx.x] + red[tid] - s;
  int4 o;
  o.x = run; o.y = run + v[0]; o.z = o.y + v[1]; o.w = o.z + v[2];
  if (base + 3 < n) {
    *(int4*)(rowptr + base) = o;
    *(int4*)(cursor + base) = o;
  } else {
    int oo[4] = {o.x, o.y, o.z, o.w};
    for (int i = 0; i < 4; ++i)
      if (base + i < n) { rowptr[base + i] = oo[i]; cursor[base + i] = oo[i]; }
  }
}

__global__ void fill_kernel(const int* __restrict__ src, const int* __restrict__ dst,
                            int* __restrict__ cursor, int* __restrict__ csr_src, int E) {
  int e = blockIdx.x * 256 + threadIdx.x;
  if (e < E) {
    int p = atomicAdd(&cursor[dst[e]], 1);
    csr_src[p] = src[e];
  }
}

// ---------------- converts ----------------
__global__ void f2b4_kernel(const float* __restrict__ in, unsigned short* __restrict__ out, int n4) {
  int i = blockIdx.x * 256 + threadIdx.x;
  if (i >= n4) return;
  float4 v = ((const float4*)in)[i];
  unsigned short r[4] = {f2bf(v.x), f2bf(v.y), f2bf(v.z), f2bf(v.w)};
  *(uint2*)(out + (size_t)i * 4) = *(uint2*)r;
}

__global__ void convert_trunk(const float* __restrict__ cW1, const float* __restrict__ cW2,
                              unsigned short* __restrict__ WT1, unsigned short* __restrict__ WT2) {
  int idx = blockIdx.x * 256 + threadIdx.x;
  if (idx >= LL * 16384) return;
  int l = idx >> 14, r = idx & 16383, k = r >> 7, n = r & 127;
  WT1[l * 16384 + n * 128 + k] = f2bf(cW1[idx]);
  WT2[l * 16384 + n * 128 + k] = f2bf(cW2[idx]);
}

__global__ void f2bT_kernel(const float* __restrict__ in, unsigned short* __restrict__ out,
                            int K, int Nn) {
  int idx = blockIdx.x * 256 + threadIdx.x;
  if (idx >= K * Nn) return;
  int k = idx / Nn, n = idx - k * Nn;
  out[(size_t)n * K + k] = f2bf(in[idx]);
}

// ---------------- GIN aggregate (bf16 gather, fp32 acc, bf16 out) ----------------
// one wave per node; neighbor loop unrolled x4 for memory-level parallelism
__global__ void aggregate_bf16(const unsigned short* __restrict__ h16, int ld,
                               const int* __restrict__ rowptr,
                               const int* __restrict__ csr_src,
                               const float* __restrict__ ceps_l,
                               unsigned short* __restrict__ out, int n) {
  int node = blockIdx.x * 4 + (threadIdx.x >> 6);
  if (node >= n) return;
  int lane = threadIdx.x & 63;
  int c2 = lane * 2;
  float eps1 = 1.0f + *ceps_l;
  float ax = 0.f, ay = 0.f;
  int b = rowptr[node], e = rowptr[node + 1];
  int j = b;
  for (; j + 4 <= e; j += 4) {
    int s0 = csr_src[j + 0];
    int s1 = csr_src[j + 1];
    int s2 = csr_src[j + 2];
    int s3 = csr_src[j + 3];
    unsigned u0 = *(const unsigned*)(h16 + (size_t)s0 * ld + c2);
    unsigned u1 = *(const unsigned*)(h16 + (size_t)s1 * ld + c2);
    unsigned u2 = *(const unsigned*)(h16 + (size_t)s2 * ld + c2);
    unsigned u3 = *(const unsigned*)(h16 + (size_t)s3 * ld + c2);
    ax += bl(u0); ay += bh(u0);
    ax += bl(u1); ay += bh(u1);
    ax += bl(u2); ay += bh(u2);
    ax += bl(u3); ay += bh(u3);
  }
  for (; j < e; ++j) {
    int s = csr_src[j];
    unsigned u = *(const unsigned*)(h16 + (size_t)s * ld + c2);
    ax += bl(u); ay += bh(u);
  }
  unsigned hu = *(const unsigned*)(h16 + (size_t)node * ld + c2);
  ax = fmaf(eps1, bl(hu), ax);
  ay = fmaf(eps1, bh(hu), ay);
  unsigned short o[2] = {f2bf(ax), f2bf(ay)};
  *(unsigned*)(out + (size_t)node * 128 + c2) = *(unsigned*)o;
}

// ---------------- bf16 MFMA GEMM: C[M,ldc]=relu(A[M,lda(K cols)] @ WT^T + bias) ----------------
// WT pre-transposed [Nout][K]. Block 128x128, 4 waves 2x2, wave 64x64.
__global__ __launch_bounds__(256) void mfma_gemm_bt(
    const unsigned short* __restrict__ A16, int lda,
    const unsigned short* __restrict__ WT, int K,
    const float* __restrict__ bias,
    unsigned short* __restrict__ C16, int ldc, int M) {
  __shared__ unsigned short As[128 * LDK];
  __shared__ unsigned short Bs[128 * LDK];
  const int tid = threadIdx.x;
  const int bm = blockIdx.x * 128;
  const int bn = blockIdx.y * 128;
  const int lane = tid & 63;
  const int wave = tid >> 6;
  const int wr = (wave >> 1) << 6;
  const int wc = (wave & 1) << 6;
  f32x4 acc[4][4] = {};
  const int ar = tid >> 1;
  const int ah = (tid & 1) << 4;
  int gra = bm + ar; if (gra >= M) gra = M - 1;
  const unsigned short* Arow = A16 + (size_t)gra * lda;
  const unsigned short* Brow = WT + (size_t)(bn + ar) * K;
  const int mrow = lane & 15;
  const int kq = (lane >> 4) << 3;
  const int nks = K >> 5;

  for (int ks = 0; ks < nks; ++ks) {
    const int k0 = ks << 5;
    {
      const uint4* s = (const uint4*)(Arow + k0 + ah);
      *(uint4*)(As + ar * LDK + ah) = s[0];
      *(uint4*)(As + ar * LDK + ah + 8) = s[1];
    }
    {
      const uint4* s = (const uint4*)(Brow + k0 + ah);
      *(uint4*)(Bs + ar * LDK + ah) = s[0];
      *(uint4*)(Bs + ar * LDK + ah + 8) = s[1];
    }
    __syncthreads();
    bf16x8 af[4], bfv[4];
#pragma unroll
    for (int t = 0; t < 4; ++t)
      af[t] = *(const bf16x8*)(As + (wr + t * 16 + mrow) * LDK + kq);
#pragma unroll
    for (int t = 0; t < 4; ++t)
      bfv[t] = *(const bf16x8*)(Bs + (wc + t * 16 + mrow) * LDK + kq);
#pragma unroll
    for (int mt = 0; mt < 4; ++mt)
#pragma unroll
      for (int nt = 0; nt < 4; ++nt)
        acc[mt][nt] = __builtin_amdgcn_mfma_f32_16x16x32_bf16(af[mt], bfv[nt], acc[mt][nt], 0, 0, 0);
    __syncthreads();
  }
  const int crow = (lane >> 4) << 2;
  const int ccol = lane & 15;
#pragma unroll
  for (int nt = 0; nt < 4; ++nt) {
    int cbase = bn + wc + nt * 16 + ccol;
    float bz = bias[cbase];
#pragma unroll
    for (int mt = 0; mt < 4; ++mt) {
      int rbase = bm + wr + mt * 16 + crow;
#pragma unroll
      for (int i = 0; i < 4; ++i) {
        int r = rbase + i;
        if (r < M) C16[(size_t)r * ldc + cbase] = f2bf(fmaxf(acc[mt][nt][i] + bz, 0.f));
      }
    }
  }
}

// ep GEMM1 with fused candidate gather: A row = [emb16[cand0] | emb16[cand1]], K=1024.
// Block 128(m) x 256(n) with 8 waves (2x4), wave tile 64x64 => acc[4][4] (no occupancy cliff).
// A gathered exactly once.
__global__ __launch_bounds__(512) void mfma_gemm_gather(
    const unsigned short* __restrict__ emb16, const int* __restrict__ cand,
    const unsigned short* __restrict__ WT /*[256][1024]*/,
    const float* __restrict__ bias,
    unsigned short* __restrict__ C16 /*[M,256]*/, int M) {
  __shared__ unsigned short As[128 * LDK];
  __shared__ unsigned short Bs[256 * LDK];
  const int tid = threadIdx.x;
  const int bm = blockIdx.x * 128;
  const int lane = tid & 63;
  const int wave = tid >> 6;
  const int wr = (wave >> 2) << 6;   // 0 / 64
  const int wc = (wave & 3) << 6;    // 0 / 64 / 128 / 192
  f32x4 acc[4][4] = {};
  // A staging: 128 rows x 32 k-elems = 512 uint4 -> 1 per thread
  const int ar = tid >> 2;
  const int ah = (tid & 3) << 3;
  int gra = bm + ar; if (gra >= M) gra = M - 1;
  const int node0 = cand[gra];
  const int node1 = cand[NC + gra];
  // B staging: 256 rows x 32 k-elems = 1024 uint4 -> 2 per thread
  const int br = tid >> 1;
  const int bh8 = (tid & 1) << 4;
  const unsigned short* Brow = WT + (size_t)br * 1024 + bh8;
  const int mrow = lane & 15;
  const int kq = (lane >> 4) << 3;

  for (int ks = 0; ks < 32; ++ks) {
    const int k0 = ks << 5;
    {
      int node = (k0 < 512) ? node0 : node1;
      const uint4* s = (const uint4*)(emb16 + (size_t)node * 512 + (k0 & 511) + ah);
      *(uint4*)(As + ar * LDK + ah) = s[0];
    }
    {
      const uint4* s = (const uint4*)(Brow + k0);
      *(uint4*)(Bs + br * LDK + bh8) = s[0];
      *(uint4*)(Bs + br * LDK + bh8 + 8) = s[1];
    }
    __syncthreads();
    bf16x8 af[4], bfv[4];
#pragma unroll
    for (int t = 0; t < 4; ++t)
      af[t] = *(const bf16x8*)(As + (wr + t * 16 + mrow) * LDK + kq);
#pragma unroll
    for (int t = 0; t < 4; ++t)
      bfv[t] = *(const bf16x8*)(Bs + (wc + t * 16 + mrow) * LDK + kq);
#pragma unroll
    for (int mt = 0; mt < 4; ++mt)
#pragma unroll
      for (int nt = 0; nt < 4; ++nt)
        acc[mt][nt] = __builtin_amdgcn_mfma_f32_16x16x32_bf16(af[mt], bfv[nt], acc[mt][nt], 0, 0, 0);
    __syncthreads();
  }
  const int crow = (lane >> 4) << 2;
  const int ccol = lane & 15;
#pragma unroll
  for (int nt = 0; nt < 4; ++nt) {
    int cbase = wc + nt * 16 + ccol;
    float bz = bias[cbase];
#pragma unroll
    for (int mt = 0; mt < 4; ++mt) {
      int rbase = bm + wr + mt * 16 + crow;
#pragma unroll
      for (int i = 0; i < 4; ++i) {
        int r = rbase + i;
        if (r < M) C16[(size_t)r * 256 + cbase] = f2bf(fmaxf(acc[mt][nt][i] + bz, 0.f));
      }
    }
  }
}

// ---------------- BatchNorm (bf16 in) ----------------
__global__ __launch_bounds__(256) void bn_stats_bf16(const unsigned short* __restrict__ z,
                                                     float* __restrict__ sum,
                                                     float* __restrict__ sumsq, int n) {
  __shared__ float red[16][128];
  int tid = threadIdx.x;
  int cg = tid & 15, rg = tid >> 4;
  int c8 = cg * 8;
  int base = blockIdx.x * 512;
  int rend = min(base + 512, n);
  float s[8] = {}, q[8] = {};
  for (int r = base + rg; r < rend; r += 16) {
    uint4 v = *(const uint4*)(z + (size_t)r * 128 + c8);
    float f[8] = {bl(v.x), bh(v.x), bl(v.y), bh(v.y), bl(v.z), bh(v.z), bl(v.w), bh(v.w)};
#pragma unroll
    for (int j = 0; j < 8; ++j) { s[j] += f[j]; q[j] += f[j] * f[j]; }
  }
#pragma unroll
  for (int j = 0; j < 8; ++j) red[rg][c8 + j] = s[j];
  __syncthreads();
  for (int step = 8; step >= 1; step >>= 1) {
    if (rg < step)
#pragma unroll
      for (int j = 0; j < 8; ++j) red[rg][c8 + j] += red[rg + step][c8 + j];
    __syncthreads();
  }
  if (rg == 0)
#pragma unroll
    for (int j = 0; j < 8; ++j) atomicAdd(&sum[c8 + j], red[0][c8 + j]);
  __syncthreads();
#pragma unroll
  for (int j = 0; j < 8; ++j) red[rg][c8 + j] = q[j];
  __syncthreads();
  for (int step = 8; step >= 1; step >>= 1) {
    if (rg < step)
#pragma unroll
      for (int j = 0; j < 8; ++j) red[rg][c8 + j] += red[rg + step][c8 + j];
    __syncthreads();
  }
  if (rg == 0)
#pragma unroll
    for (int j = 0; j < 8; ++j) atomicAdd(&sumsq[c8 + j], red[0][c8 + j]);
}

__global__ void bn_apply_bf16(const unsigned short* __restrict__ z,
                              const float* __restrict__ sum, const float* __restrict__ sumsq,
                              const float* __restrict__ gamma, const float* __restrict__ beta,
                              unsigned short* __restrict__ out, int n) {
  int idx = blockIdx.x * 256 + threadIdx.x;
  if (idx >= n * 16) return;
  int r = idx >> 4, c8 = (idx & 15) << 3;
  uint4 v = *(const uint4*)(z + (size_t)r * 128 + c8);
  float f[8] = {bl(v.x), bh(v.x), bl(v.y), bh(v.y), bl(v.z), bh(v.z), bl(v.w), bh(v.w)};
  const float inv_n = 1.0f / (float)NN;
  unsigned short o[8];
#pragma unroll
  for (int j = 0; j < 8; ++j) {
    int c = c8 + j;
    float mu = sum[c] * inv_n;
    float var = sumsq[c] * inv_n - mu * mu;
    float sc = rsqrtf(var + 1e-5f) * gamma[c];
    o[j] = f2bf((f[j] - mu) * sc + beta[c]);
  }
  *(uint4*)(out + (size_t)r * 512 + c8) = *(uint4*)o;
}

// ---------------- pooling ----------------
__global__ void bounds_kernel(const int* __restrict__ batch, int* __restrict__ gstart, int n) {
  int g = threadIdx.x;
  if (g > GG) return;
  int lo = 0, hi = n;
  while (lo < hi) {
    int mid = (lo + hi) >> 1;
    if (batch[mid] < g) lo = mid + 1; else hi = mid;
  }
  gstart[g] = lo;
}

__global__ __launch_bounds__(256) void pool_bf16(const unsigned short* __restrict__ emb16,
                                                 const int* __restrict__ gstart,
                                                 float* __restrict__ gsum) {
  int g = blockIdx.x;
  int chunk = blockIdx.y;
  int c2 = threadIdx.x * 2;
  int s = gstart[g], e = gstart[g + 1];
  int len = e - s;
  int per = (len + 7) >> 3;
  int r0 = s + chunk * per;
  int r1 = min(r0 + per, e);
  float ax = 0.f, ay = 0.f;
  for (int r = r0; r < r1; ++r) {
    unsigned u = *(const unsigned*)(emb16 + (size_t)r * 512 + c2);
    ax += bl(u); ay += bh(u);
  }
  if (r1 > r0) {
    atomicAdd(&gsum[g * 512 + c2], ax);
    atomicAdd(&gsum[g * 512 + c2 + 1], ay);
  }
}

__global__ void pool_div_kernel(const float* __restrict__ gsum, const int* __restrict__ gstart,
                                float* __restrict__ gemb) {
  int idx = blockIdx.x * 256 + threadIdx.x;
  if (idx >= GG * 512) return;
  int g = idx >> 9;
  float cntf = fmaxf((float)(gstart[g + 1] - gstart[g]), 1.0f);
  gemb[idx] = gsum[idx] / cntf;
}

// ---------------- small dense MLP (M=64, fp32) ----------------
__global__ void small_gemm(const float* __restrict__ A, const float* __restrict__ W,
                           const float* __restrict__ b, float* __restrict__ C,
                           int M, int K, int Nn, int relu) {
  int idx = blockIdx.x * 256 + threadIdx.x;
  if (idx >= M * Nn) return;
  int r = idx / Nn, n = idx - r * Nn;
  const float* a = A + (size_t)r * K;
  float acc = b[n];
  for (int k = 0; k < K; ++k) acc = fmaf(a[k], W[(size_t)k * Nn + n], acc);
  if (relu) acc = fmaxf(acc, 0.f);
  C[idx] = acc;
}

__global__ void cls_out_kernel(const float* __restrict__ t3, const float* __restrict__ W,
                               const float* __restrict__ b, float* __restrict__ out) {
  int g = blockIdx.x;
  int lane = threadIdx.x;  // 64
  float v = 0.f;
  float logit = -1e30f;
  if (lane < CCLS) {
    v = b[lane];
    for (int k = 0; k < 128; ++k) v = fmaf(t3[g * 128 + k], W[k * CCLS + lane], v);
    logit = v;
  }
  float m = logit;
  for (int off = 8; off >= 1; off >>= 1) m = fmaxf(m, __shfl_down(m, off, 64));
  m = __shfl(m, 0, 64);
  float ex = (lane < CCLS) ? expf(v - m) : 0.f;
  float s = ex;
  for (int off = 8; off >= 1; off >>= 1) s += __shfl_down(s, off, 64);
  s = __shfl(s, 0, 64);
  if (lane < CCLS) out[g * CCLS + lane] = v - m - logf(s);
}

__global__ void ep_final_bf16(const unsigned short* __restrict__ C2, const float* __restrict__ w,
                              const float* __restrict__ b3, float* __restrict__ out, int M) {
  int row = blockIdx.x * 4 + (threadIdx.x >> 6);
  if (row >= M) return;
  int lane = threadIdx.x & 63;
  int c2 = lane * 2;
  unsigned u = *(const unsigned*)(C2 + (size_t)row * 128 + c2);
  float2 wv = *(const float2*)(w + c2);
  float s = bl(u) * wv.x + bh(u) * wv.y;
  for (int off = 32; off >= 1; off >>= 1) s += __shfl_down(s, off, 64);
  if (lane == 0) out[row] = 1.f / (1.f + expf(-(s + b3[0])));
}

// ---------------- launch ----------------
extern "C" void kernel_launch(void* const* d_in, const int* in_sizes, int n_in,
                              void* d_out, int out_size, void* d_ws, size_t ws_size,
                              hipStream_t stream) {
  const float* x = (const float*)d_in[0];
  const int* edge_index = (const int*)d_in[1];
  const int* batch = (const int*)d_in[2];
  const int* cand = (const int*)d_in[3];
  const float* cW1 = (const float*)d_in[4];
  const float* cb1 = (const float*)d_in[5];
  const float* cW2 = (const float*)d_in[6];
  const float* cb2 = (const float*)d_in[7];
  const float* cgamma = (const float*)d_in[8];
  const float* cbeta = (const float*)d_in[9];
  const float* ceps = (const float*)d_in[10];
  const float* ncW1 = (const float*)d_in[11];
  const float* ncb1 = (const float*)d_in[12];
  const float* ncW2 = (const float*)d_in[13];
  const float* ncb2 = (const float*)d_in[14];
  const float* ncW3 = (const float*)d_in[15];
  const float* ncb3 = (const float*)d_in[16];
  const float* ncW4 = (const float*)d_in[17];
  const float* ncb4 = (const float*)d_in[18];
  const float* epW1 = (const float*)d_in[19];
  const float* epb1 = (const float*)d_in[20];
  const float* epW2 = (const float*)d_in[21];
  const float* epb2 = (const float*)d_in[22];
  const float* epW3 = (const float*)d_in[23];
  const float* epb3 = (const float*)d_in[24];

  char* ws = (char*)d_ws;
  size_t off = 0;
  auto alloc = [&](size_t bytes) -> void* {
    off = (off + 255) & ~(size_t)255;
    void* p = ws + off;
    off += bytes;
    return p;
  };
  size_t zz_bytes = (size_t)NN * 4 + 512 * 4 + 512 * 4 + (size_t)GG * 512 * 4;
  char* zz = (char*)alloc(zz_bytes);
  int* cnt = (int*)zz;
  float* bnsum = (float*)(zz + (size_t)NN * 4);
  float* bnsumsq = bnsum + 512;
  float* gsum = bnsumsq + 512;
  int* rowptr = (int*)alloc((size_t)(NN + 1) * 4);
  int* cursor = (int*)alloc((size_t)NN * 4);
  int* csr_src = (int*)alloc((size_t)EE * 4);
  int* bsum = (int*)alloc(128 * 4);
  unsigned short* x16 = (unsigned short*)alloc((size_t)NN * 128 * 2);
  unsigned short* g16a = (unsigned short*)alloc((size_t)NN * 128 * 2);
  unsigned short* g16b = (unsigned short*)alloc((size_t)NN * 128 * 2);
  unsigned short* emb16 = (unsigned short*)alloc((size_t)NN * 512 * 2);
  unsigned short* C1 = (unsigned short*)alloc((size_t)NC * 256 * 2);
  unsigned short* C2 = (unsigned short*)alloc((size_t)NC * 128 * 2);
  unsigned short* WT1 = (unsigned short*)alloc((size_t)LL * 16384 * 2);
  unsigned short* WT2 = (unsigned short*)alloc((size_t)LL * 16384 * 2);
  unsigned short* W1T = (unsigned short*)alloc((size_t)1024 * 256 * 2);
  unsigned short* W2T = (unsigned short*)alloc((size_t)256 * 128 * 2);
  int* gstart = (int*)alloc(65 * 4);
  float* gemb = (float*)alloc((size_t)GG * 512 * 4);
  float* t1 = (float*)alloc((size_t)GG * 256 * 4);
  float* t2 = (float*)alloc((size_t)GG * 128 * 4);
  float* t3 = (float*)alloc((size_t)GG * 128 * 4);

  const int* esrc = edge_index;
  const int* edst = edge_index + EE;
  const int nblk = (NN + 1023) / 1024;  // 98

  hipMemsetAsync(zz, 0, zz_bytes, stream);
  hist_kernel<<<(EE + 255) / 256, 256, 0, stream>>>(edst, cnt, EE);
  scan_p1<<<nblk, 256, 0, stream>>>(cnt, bsum, NN);
  scan_p2<<<1, 128, 0, stream>>>(bsum, rowptr, nblk, NN);
  scan_p3<<<nblk, 256, 0, stream>>>(cnt, bsum, rowptr, cursor, NN);
  fill_kernel<<<(EE + 255) / 256, 256, 0, stream>>>(esrc, edst, cursor, csr_src, EE);
  f2b4_kernel<<<(NN * 128 / 4 + 255) / 256, 256, 0, stream>>>(x, x16, NN * 128 / 4);
  convert_trunk<<<(LL * 16384 + 255) / 256, 256, 0, stream>>>(cW1, cW2, WT1, WT2);
  f2bT_kernel<<<(1024 * 256 + 255) / 256, 256, 0, stream>>>(epW1, W1T, 1024, 256);
  f2bT_kernel<<<(256 * 128 + 255) / 256, 256, 0, stream>>>(epW2, W2T, 256, 128);

  for (int l = 0; l < LL; ++l) {
    const unsigned short* h16 = (l == 0) ? x16 : (emb16 + (size_t)(l - 1) * 128);
    int ld = (l == 0) ? 128 : 512;
    aggregate_bf16<<<(NN + 3) / 4, 256, 0, stream>>>(h16, ld, rowptr, csr_src, ceps + l, g16a, NN);
    mfma_gemm_bt<<<dim3((NN + 127) / 128, 1), 256, 0, stream>>>(
        g16a, 128, WT1 + (size_t)l * 16384, 128, cb1 + l * 128, g16b, 128, NN);
    mfma_gemm_bt<<<dim3((NN + 127) / 128, 1), 256, 0, stream>>>(
        g16b, 128, WT2 + (size_t)l * 16384, 128, cb2 + l * 128, g16a, 128, NN);
    bn_stats_bf16<<<(NN + 511) / 512, 256, 0, stream>>>(g16a, bnsum + l * 128, bnsumsq + l * 128, NN);
    bn_apply_bf16<<<(NN * 16 + 255) / 256, 256, 0, stream>>>(
        g16a, bnsum + l * 128, bnsumsq + l * 128, cgamma + l * 128, cbeta + l * 128,
        emb16 + (size_t)l * 128, NN);
  }

  bounds_kernel<<<1, 128, 0, stream>>>(batch, gstart, NN);
  pool_bf16<<<dim3(GG, 8), 256, 0, stream>>>(emb16, gstart, gsum);
  pool_div_kernel<<<(GG * 512 + 255) / 256, 256, 0, stream>>>(gsum, gstart, gemb);
  small_gemm<<<(GG * 256 + 255) / 256, 256, 0, stream>>>(gemb, ncW1, ncb1, t1, GG, 512, 256, 1);
  small_gemm<<<(GG * 128 + 255) / 256, 256, 0, stream>>>(t1, ncW2, ncb2, t2, GG, 256, 128, 1);
  small_gemm<<<(GG * 128 + 255) / 256, 256, 0, stream>>>(t2, ncW3, ncb3, t3, GG, 128, 128, 1);
  cls_out_kernel<<<GG, 64, 0, stream>>>(t3, ncW4, ncb4, (float*)d_out);

  mfma_gemm_gather<<<(NC + 127) / 128, 512, 0, stream>>>(emb16, cand, W1T, epb1, C1, NC);
  mfma_gemm_bt<<<dim3((NC + 127) / 128, 1), 256, 0, stream>>>(C1, 256, W2T, 256, epb2, C2, 128, NC);
  ep_final_bf16<<<(NC + 3) / 4, 256, 0, stream>>>(C2, epW3, epb3, (float*)d_out + GG * CCLS, NC);
}

// Round 5
// 1410.464 us; speedup vs baseline: 1.8324x; 1.1806x over previous
//
#include <hip/hip_runtime.h>
#include <math.h>

#define NN 100000
#define EE 1600000
#define GG 64
#define HH 128
#define LL 4
#define CCLS 16
#define NC 100000
#define LDK 40  // padded LDS row stride in bf16 elems (80 B, 16B-aligned)

typedef __attribute__((ext_vector_type(8))) short bf16x8;
typedef __attribute__((ext_vector_type(4))) float f32x4;

__device__ __forceinline__ unsigned short f2bf(float x) {
  union { float f; unsigned int u; } v; v.f = x;
  unsigned int r = v.u + 0x7fffu + ((v.u >> 16) & 1u);
  return (unsigned short)(r >> 16);
}
__device__ __forceinline__ float bl(unsigned u) {
  union { unsigned u; float f; } v; v.u = u << 16; return v.f;
}
__device__ __forceinline__ float bh(unsigned u) {
  union { unsigned u; float f; } v; v.u = u & 0xffff0000u; return v.f;
}

// ---------------- CSR build ----------------
__global__ void hist_kernel(const int* __restrict__ dst, int* __restrict__ cnt, int E) {
  int e = blockIdx.x * 256 + threadIdx.x;
  if (e < E) atomicAdd(&cnt[dst[e]], 1);
}

// 3-phase scan
__global__ __launch_bounds__(256) void scan_p1(const int* __restrict__ cnt,
                                               int* __restrict__ bsum, int n) {
  __shared__ int red[256];
  int tid = threadIdx.x;
  int base = blockIdx.x * 1024 + tid * 4;
  int s = 0;
  if (base + 3 < n) {
    int4 v = *(const int4*)(cnt + base);
    s = v.x + v.y + v.z + v.w;
  } else {
    for (int i = 0; i < 4; ++i) if (base + i < n) s += cnt[base + i];
  }
  red[tid] = s;
  __syncthreads();
  for (int st = 128; st >= 1; st >>= 1) {
    if (tid < st) red[tid] += red[tid + st];
    __syncthreads();
  }
  if (tid == 0) bsum[blockIdx.x] = red[0];
}

__global__ void scan_p2(int* __restrict__ bsum, int* __restrict__ rowptr, int nb, int n) {
  __shared__ int buf[128];
  int tid = threadIdx.x;
  int v = (tid < nb) ? bsum[tid] : 0;
  buf[tid] = v;
  __syncthreads();
  for (int off = 1; off < 128; off <<= 1) {
    int t = (tid >= off) ? buf[tid - off] : 0;
    __syncthreads();
    buf[tid] += t;
    __syncthreads();
  }
  if (tid < nb) bsum[tid] = buf[tid] - v;  // exclusive
  if (tid == 127) rowptr[n] = buf[127];    // total
}

__global__ __launch_bounds__(256) void scan_p3(const int* __restrict__ cnt,
                                               const int* __restrict__ bsum,
                                               int* __restrict__ rowptr,
                                               int* __restrict__ cursor, int n) {
  __shared__ int red[256];
  int tid = threadIdx.x;
  int base = blockIdx.x * 1024 + tid * 4;
  int v[4] = {0, 0, 0, 0};
  if (base + 3 < n) {
    int4 t = *(const int4*)(cnt + base);
    v[0] = t.x; v[1] = t.y; v[2] = t.z; v[3] = t.w;
  } else {
    for (int i = 0; i < 4; ++i) if (base + i < n) v[i] = cnt[base + i];
  }
  int s = v[0] + v[1] + v[2] + v[3];
  red[tid] = s;
  __syncthreads();
  for (int off = 1; off < 256; off <<= 1) {
    int t = (tid >= off) ? red[tid - off] : 0;
    __syncthreads();
    red[tid] += t;
    __syncthreads();
  }
  int run = bsum[blockIdx.x] + red[tid] - s;
  int4 o;
  o.x = run; o.y = run + v[0]; o.z = o.y + v[1]; o.w = o.z + v[2];
  if (base + 3 < n) {
    *(int4*)(rowptr + base) = o;
    *(int4*)(cursor + base) = o;
  } else {
    int oo[4] = {o.x, o.y, o.z, o.w};
    for (int i = 0; i < 4; ++i)
      if (base + i < n) { rowptr[base + i] = oo[i]; cursor[base + i] = oo[i]; }
  }
}

__global__ void fill_kernel(const int* __restrict__ src, const int* __restrict__ dst,
                            int* __restrict__ cursor, int* __restrict__ csr_src, int E) {
  int e = blockIdx.x * 256 + threadIdx.x;
  if (e < E) {
    int p = atomicAdd(&cursor[dst[e]], 1);
    csr_src[p] = src[e];
  }
}

// ---------------- converts ----------------
__global__ void f2b4_kernel(const float* __restrict__ in, unsigned short* __restrict__ out, int n4) {
  int i = blockIdx.x * 256 + threadIdx.x;
  if (i >= n4) return;
  float4 v = ((const float4*)in)[i];
  unsigned short r[4] = {f2bf(v.x), f2bf(v.y), f2bf(v.z), f2bf(v.w)};
  *(uint2*)(out + (size_t)i * 4) = *(uint2*)r;
}

__global__ void convert_trunk(const float* __restrict__ cW1, const float* __restrict__ cW2,
                              unsigned short* __restrict__ WT1, unsigned short* __restrict__ WT2) {
  int idx = blockIdx.x * 256 + threadIdx.x;
  if (idx >= LL * 16384) return;
  int l = idx >> 14, r = idx & 16383, k = r >> 7, n = r & 127;
  WT1[l * 16384 + n * 128 + k] = f2bf(cW1[idx]);
  WT2[l * 16384 + n * 128 + k] = f2bf(cW2[idx]);
}

__global__ void f2bT_kernel(const float* __restrict__ in, unsigned short* __restrict__ out,
                            int K, int Nn) {
  int idx = blockIdx.x * 256 + threadIdx.x;
  if (idx >= K * Nn) return;
  int k = idx / Nn, n = idx - k * Nn;
  out[(size_t)n * K + k] = f2bf(in[idx]);
}

// ---------------- GIN aggregate (bf16 gather, fp32 acc, bf16 out) ----------------
__global__ void aggregate_bf16(const unsigned short* __restrict__ h16, int ld,
                               const int* __restrict__ rowptr,
                               const int* __restrict__ csr_src,
                               const float* __restrict__ ceps_l,
                               unsigned short* __restrict__ out, int n) {
  int node = blockIdx.x * 4 + (threadIdx.x >> 6);
  if (node >= n) return;
  int lane = threadIdx.x & 63;
  int c2 = lane * 2;
  float eps1 = 1.0f + *ceps_l;
  float ax = 0.f, ay = 0.f;
  int b = rowptr[node], e = rowptr[node + 1];
  int j = b;
  for (; j + 4 <= e; j += 4) {
    int s0 = csr_src[j + 0];
    int s1 = csr_src[j + 1];
    int s2 = csr_src[j + 2];
    int s3 = csr_src[j + 3];
    unsigned u0 = *(const unsigned*)(h16 + (size_t)s0 * ld + c2);
    unsigned u1 = *(const unsigned*)(h16 + (size_t)s1 * ld + c2);
    unsigned u2 = *(const unsigned*)(h16 + (size_t)s2 * ld + c2);
    unsigned u3 = *(const unsigned*)(h16 + (size_t)s3 * ld + c2);
    ax += bl(u0); ay += bh(u0);
    ax += bl(u1); ay += bh(u1);
    ax += bl(u2); ay += bh(u2);
    ax += bl(u3); ay += bh(u3);
  }
  for (; j < e; ++j) {
    int s = csr_src[j];
    unsigned u = *(const unsigned*)(h16 + (size_t)s * ld + c2);
    ax += bl(u); ay += bh(u);
  }
  unsigned hu = *(const unsigned*)(h16 + (size_t)node * ld + c2);
  ax = fmaf(eps1, bl(hu), ax);
  ay = fmaf(eps1, bh(hu), ay);
  unsigned short o[2] = {f2bf(ax), f2bf(ay)};
  *(unsigned*)(out + (size_t)node * 128 + c2) = *(unsigned*)o;
}

// ---------------- bf16 MFMA GEMM ----------------
__global__ __launch_bounds__(256) void mfma_gemm_bt(
    const unsigned short* __restrict__ A16, int lda,
    const unsigned short* __restrict__ WT, int K,
    const float* __restrict__ bias,
    unsigned short* __restrict__ C16, int ldc, int M) {
  __shared__ unsigned short As[128 * LDK];
  __shared__ unsigned short Bs[128 * LDK];
  const int tid = threadIdx.x;
  const int bm = blockIdx.x * 128;
  const int bn = blockIdx.y * 128;
  const int lane = tid & 63;
  const int wave = tid >> 6;
  const int wr = (wave >> 1) << 6;
  const int wc = (wave & 1) << 6;
  f32x4 acc[4][4] = {};
  const int ar = tid >> 1;
  const int ah = (tid & 1) << 4;
  int gra = bm + ar; if (gra >= M) gra = M - 1;
  const unsigned short* Arow = A16 + (size_t)gra * lda;
  const unsigned short* Brow = WT + (size_t)(bn + ar) * K;
  const int mrow = lane & 15;
  const int kq = (lane >> 4) << 3;
  const int nks = K >> 5;

  for (int ks = 0; ks < nks; ++ks) {
    const int k0 = ks << 5;
    {
      const uint4* s = (const uint4*)(Arow + k0 + ah);
      *(uint4*)(As + ar * LDK + ah) = s[0];
      *(uint4*)(As + ar * LDK + ah + 8) = s[1];
    }
    {
      const uint4* s = (const uint4*)(Brow + k0 + ah);
      *(uint4*)(Bs + ar * LDK + ah) = s[0];
      *(uint4*)(Bs + ar * LDK + ah + 8) = s[1];
    }
    __syncthreads();
    bf16x8 af[4], bfv[4];
#pragma unroll
    for (int t = 0; t < 4; ++t)
      af[t] = *(const bf16x8*)(As + (wr + t * 16 + mrow) * LDK + kq);
#pragma unroll
    for (int t = 0; t < 4; ++t)
      bfv[t] = *(const bf16x8*)(Bs + (wc + t * 16 + mrow) * LDK + kq);
#pragma unroll
    for (int mt = 0; mt < 4; ++mt)
#pragma unroll
      for (int nt = 0; nt < 4; ++nt)
        acc[mt][nt] = __builtin_amdgcn_mfma_f32_16x16x32_bf16(af[mt], bfv[nt], acc[mt][nt], 0, 0, 0);
    __syncthreads();
  }
  const int crow = (lane >> 4) << 2;
  const int ccol = lane & 15;
#pragma unroll
  for (int nt = 0; nt < 4; ++nt) {
    int cbase = bn + wc + nt * 16 + ccol;
    float bz = bias[cbase];
#pragma unroll
    for (int mt = 0; mt < 4; ++mt) {
      int rbase = bm + wr + mt * 16 + crow;
#pragma unroll
      for (int i = 0; i < 4; ++i) {
        int r = rbase + i;
        if (r < M) C16[(size_t)r * ldc + cbase] = f2bf(fmaxf(acc[mt][nt][i] + bz, 0.f));
      }
    }
  }
}

// ep GEMM1 with fused candidate gather, block 128x256, 8 waves 2x4, wave 64x64
__global__ __launch_bounds__(512) void mfma_gemm_gather(
    const unsigned short* __restrict__ emb16, const int* __restrict__ cand,
    const unsigned short* __restrict__ WT /*[256][1024]*/,
    const float* __restrict__ bias,
    unsigned short* __restrict__ C16 /*[M,256]*/, int M) {
  __shared__ unsigned short As[128 * LDK];
  __shared__ unsigned short Bs[256 * LDK];
  const int tid = threadIdx.x;
  const int bm = blockIdx.x * 128;
  const int lane = tid & 63;
  const int wave = tid >> 6;
  const int wr = (wave >> 2) << 6;
  const int wc = (wave & 3) << 6;
  f32x4 acc[4][4] = {};
  const int ar = tid >> 2;
  const int ah = (tid & 3) << 3;
  int gra = bm + ar; if (gra >= M) gra = M - 1;
  const int node0 = cand[gra];
  const int node1 = cand[NC + gra];
  const int br = tid >> 1;
  const int bh8 = (tid & 1) << 4;
  const unsigned short* Brow = WT + (size_t)br * 1024 + bh8;
  const int mrow = lane & 15;
  const int kq = (lane >> 4) << 3;

  for (int ks = 0; ks < 32; ++ks) {
    const int k0 = ks << 5;
    {
      int node = (k0 < 512) ? node0 : node1;
      const uint4* s = (const uint4*)(emb16 + (size_t)node * 512 + (k0 & 511) + ah);
      *(uint4*)(As + ar * LDK + ah) = s[0];
    }
    {
      const uint4* s = (const uint4*)(Brow + k0);
      *(uint4*)(Bs + br * LDK + bh8) = s[0];
      *(uint4*)(Bs + br * LDK + bh8 + 8) = s[1];
    }
    __syncthreads();
    bf16x8 af[4], bfv[4];
#pragma unroll
    for (int t = 0; t < 4; ++t)
      af[t] = *(const bf16x8*)(As + (wr + t * 16 + mrow) * LDK + kq);
#pragma unroll
    for (int t = 0; t < 4; ++t)
      bfv[t] = *(const bf16x8*)(Bs + (wc + t * 16 + mrow) * LDK + kq);
#pragma unroll
    for (int mt = 0; mt < 4; ++mt)
#pragma unroll
      for (int nt = 0; nt < 4; ++nt)
        acc[mt][nt] = __builtin_amdgcn_mfma_f32_16x16x32_bf16(af[mt], bfv[nt], acc[mt][nt], 0, 0, 0);
    __syncthreads();
  }
  const int crow = (lane >> 4) << 2;
  const int ccol = lane & 15;
#pragma unroll
  for (int nt = 0; nt < 4; ++nt) {
    int cbase = wc + nt * 16 + ccol;
    float bz = bias[cbase];
#pragma unroll
    for (int mt = 0; mt < 4; ++mt) {
      int rbase = bm + wr + mt * 16 + crow;
#pragma unroll
      for (int i = 0; i < 4; ++i) {
        int r = rbase + i;
        if (r < M) C16[(size_t)r * 256 + cbase] = f2bf(fmaxf(acc[mt][nt][i] + bz, 0.f));
      }
    }
  }
}

// ---------------- BatchNorm (bf16 in) ----------------
__global__ __launch_bounds__(256) void bn_stats_bf16(const unsigned short* __restrict__ z,
                                                     float* __restrict__ sum,
                                                     float* __restrict__ sumsq, int n) {
  __shared__ float red[16][128];
  int tid = threadIdx.x;
  int cg = tid & 15, rg = tid >> 4;
  int c8 = cg * 8;
  int base = blockIdx.x * 512;
  int rend = min(base + 512, n);
  float s[8] = {}, q[8] = {};
  for (int r = base + rg; r < rend; r += 16) {
    uint4 v = *(const uint4*)(z + (size_t)r * 128 + c8);
    float f[8] = {bl(v.x), bh(v.x), bl(v.y), bh(v.y), bl(v.z), bh(v.z), bl(v.w), bh(v.w)};
#pragma unroll
    for (int j = 0; j < 8; ++j) { s[j] += f[j]; q[j] += f[j] * f[j]; }
  }
#pragma unroll
  for (int j = 0; j < 8; ++j) red[rg][c8 + j] = s[j];
  __syncthreads();
  for (int step = 8; step >= 1; step >>= 1) {
    if (rg < step)
#pragma unroll
      for (int j = 0; j < 8; ++j) red[rg][c8 + j] += red[rg + step][c8 + j];
    __syncthreads();
  }
  if (rg == 0)
#pragma unroll
    for (int j = 0; j < 8; ++j) atomicAdd(&sum[c8 + j], red[0][c8 + j]);
  __syncthreads();
#pragma unroll
  for (int j = 0; j < 8; ++j) red[rg][c8 + j] = q[j];
  __syncthreads();
  for (int step = 8; step >= 1; step >>= 1) {
    if (rg < step)
#pragma unroll
      for (int j = 0; j < 8; ++j) red[rg][c8 + j] += red[rg + step][c8 + j];
    __syncthreads();
  }
  if (rg == 0)
#pragma unroll
    for (int j = 0; j < 8; ++j) atomicAdd(&sumsq[c8 + j], red[0][c8 + j]);
}

__global__ void bn_apply_bf16(const unsigned short* __restrict__ z,
                              const float* __restrict__ sum, const float* __restrict__ sumsq,
                              const float* __restrict__ gamma, const float* __restrict__ beta,
                              unsigned short* __restrict__ out, int n) {
  int idx = blockIdx.x * 256 + threadIdx.x;
  if (idx >= n * 16) return;
  int r = idx >> 4, c8 = (idx & 15) << 3;
  uint4 v = *(const uint4*)(z + (size_t)r * 128 + c8);
  float f[8] = {bl(v.x), bh(v.x), bl(v.y), bh(v.y), bl(v.z), bh(v.z), bl(v.w), bh(v.w)};
  const float inv_n = 1.0f / (float)NN;
  unsigned short o[8];
#pragma unroll
  for (int j = 0; j < 8; ++j) {
    int c = c8 + j;
    float mu = sum[c] * inv_n;
    float var = sumsq[c] * inv_n - mu * mu;
    float sc = rsqrtf(var + 1e-5f) * gamma[c];
    o[j] = f2bf((f[j] - mu) * sc + beta[c]);
  }
  *(uint4*)(out + (size_t)r * 512 + c8) = *(uint4*)o;
}

// ---------------- pooling ----------------
__global__ void bounds_kernel(const int* __restrict__ batch, int* __restrict__ gstart, int n) {
  int g = threadIdx.x;
  if (g > GG) return;
  int lo = 0, hi = n;
  while (lo < hi) {
    int mid = (lo + hi) >> 1;
    if (batch[mid] < g) lo = mid + 1; else hi = mid;
  }
  gstart[g] = lo;
}

__global__ __launch_bounds__(256) void pool_bf16(const unsigned short* __restrict__ emb16,
                                                 const int* __restrict__ gstart,
                                                 float* __restrict__ gsum) {
  int g = blockIdx.x;
  int chunk = blockIdx.y;
  int c2 = threadIdx.x * 2;
  int s = gstart[g], e = gstart[g + 1];
  int len = e - s;
  int per = (len + 7) >> 3;
  int r0 = s + chunk * per;
  int r1 = min(r0 + per, e);
  float ax = 0.f, ay = 0.f;
  for (int r = r0; r < r1; ++r) {
    unsigned u = *(const unsigned*)(emb16 + (size_t)r * 512 + c2);
    ax += bl(u); ay += bh(u);
  }
  if (r1 > r0) {
    atomicAdd(&gsum[g * 512 + c2], ax);
    atomicAdd(&gsum[g * 512 + c2 + 1], ay);
  }
}

// ---------------- fused node classifier: one block per graph ----------------
// pool-div + 3 ReLU layers + logits + log_softmax, activations in LDS.
__global__ __launch_bounds__(256) void nc_fused(
    const float* __restrict__ gsum, const int* __restrict__ gstart,
    const float* __restrict__ W1, const float* __restrict__ b1,  // [512][256]
    const float* __restrict__ W2, const float* __restrict__ b2,  // [256][128]
    const float* __restrict__ W3, const float* __restrict__ b3,  // [128][128]
    const float* __restrict__ W4, const float* __restrict__ b4,  // [128][16]
    float* __restrict__ out) {
  __shared__ float row[512];
  __shared__ float t1[256];
  __shared__ float t2[128];
  __shared__ float t3s[128];
  __shared__ float lg[16];
  int g = blockIdx.x;
  int tid = threadIdx.x;
  float inv = 1.0f / fmaxf((float)(gstart[g + 1] - gstart[g]), 1.0f);
  row[tid] = gsum[g * 512 + tid] * inv;
  row[tid + 256] = gsum[g * 512 + tid + 256] * inv;
  __syncthreads();
  {
    float acc = b1[tid];
#pragma unroll 8
    for (int k = 0; k < 512; ++k) acc = fmaf(row[k], W1[k * 256 + tid], acc);
    t1[tid] = fmaxf(acc, 0.f);
  }
  __syncthreads();
  if (tid < 128) {
    float acc = b2[tid];
#pragma unroll 8
    for (int k = 0; k < 256; ++k) acc = fmaf(t1[k], W2[k * 128 + tid], acc);
    t2[tid] = fmaxf(acc, 0.f);
  }
  __syncthreads();
  if (tid < 128) {
    float acc = b3[tid];
#pragma unroll 8
    for (int k = 0; k < 128; ++k) acc = fmaf(t2[k], W3[k * 128 + tid], acc);
    t3s[tid] = fmaxf(acc, 0.f);
  }
  __syncthreads();
  if (tid < 16) {
    float acc = b4[tid];
#pragma unroll 8
    for (int k = 0; k < 128; ++k) acc = fmaf(t3s[k], W4[k * 16 + tid], acc);
    lg[tid] = acc;
  }
  __syncthreads();
  if (tid < 16) {
    float v = lg[tid];
    float m = v;
    for (int j = 0; j < 16; ++j) m = fmaxf(m, lg[j]);
    float s = 0.f;
    for (int j = 0; j < 16; ++j) s += expf(lg[j] - m);
    out[g * 16 + tid] = v - m - logf(s);
  }
}

__global__ void ep_final_bf16(const unsigned short* __restrict__ C2, const float* __restrict__ w,
                              const float* __restrict__ b3, float* __restrict__ out, int M) {
  int row = blockIdx.x * 4 + (threadIdx.x >> 6);
  if (row >= M) return;
  int lane = threadIdx.x & 63;
  int c2 = lane * 2;
  unsigned u = *(const unsigned*)(C2 + (size_t)row * 128 + c2);
  float2 wv = *(const float2*)(w + c2);
  float s = bl(u) * wv.x + bh(u) * wv.y;
  for (int off = 32; off >= 1; off >>= 1) s += __shfl_down(s, off, 64);
  if (lane == 0) out[row] = 1.f / (1.f + expf(-(s + b3[0])));
}

// ---------------- launch ----------------
extern "C" void kernel_launch(void* const* d_in, const int* in_sizes, int n_in,
                              void* d_out, int out_size, void* d_ws, size_t ws_size,
                              hipStream_t stream) {
  const float* x = (const float*)d_in[0];
  const int* edge_index = (const int*)d_in[1];
  const int* batch = (const int*)d_in[2];
  const int* cand = (const int*)d_in[3];
  const float* cW1 = (const float*)d_in[4];
  const float* cb1 = (const float*)d_in[5];
  const float* cW2 = (const float*)d_in[6];
  const float* cb2 = (const float*)d_in[7];
  const float* cgamma = (const float*)d_in[8];
  const float* cbeta = (const float*)d_in[9];
  const float* ceps = (const float*)d_in[10];
  const float* ncW1 = (const float*)d_in[11];
  const float* ncb1 = (const float*)d_in[12];
  const float* ncW2 = (const float*)d_in[13];
  const float* ncb2 = (const float*)d_in[14];
  const float* ncW3 = (const float*)d_in[15];
  const float* ncb3 = (const float*)d_in[16];
  const float* ncW4 = (const float*)d_in[17];
  const float* ncb4 = (const float*)d_in[18];
  const float* epW1 = (const float*)d_in[19];
  const float* epb1 = (const float*)d_in[20];
  const float* epW2 = (const float*)d_in[21];
  const float* epb2 = (const float*)d_in[22];
  const float* epW3 = (const float*)d_in[23];
  const float* epb3 = (const float*)d_in[24];

  char* ws = (char*)d_ws;
  size_t off = 0;
  auto alloc = [&](size_t bytes) -> void* {
    off = (off + 255) & ~(size_t)255;
    void* p = ws + off;
    off += bytes;
    return p;
  };
  size_t zz_bytes = (size_t)NN * 4 + 512 * 4 + 512 * 4 + (size_t)GG * 512 * 4;
  char* zz = (char*)alloc(zz_bytes);
  int* cnt = (int*)zz;
  float* bnsum = (float*)(zz + (size_t)NN * 4);
  float* bnsumsq = bnsum + 512;
  float* gsum = bnsumsq + 512;
  int* rowptr = (int*)alloc((size_t)(NN + 1) * 4);
  int* cursor = (int*)alloc((size_t)NN * 4);
  int* csr_src = (int*)alloc((size_t)EE * 4);
  int* bsum = (int*)alloc(128 * 4);
  unsigned short* x16 = (unsigned short*)alloc((size_t)NN * 128 * 2);
  unsigned short* g16a = (unsigned short*)alloc((size_t)NN * 128 * 2);
  unsigned short* g16b = (unsigned short*)alloc((size_t)NN * 128 * 2);
  unsigned short* emb16 = (unsigned short*)alloc((size_t)NN * 512 * 2);
  unsigned short* C1 = (unsigned short*)alloc((size_t)NC * 256 * 2);
  unsigned short* C2 = (unsigned short*)alloc((size_t)NC * 128 * 2);
  unsigned short* WT1 = (unsigned short*)alloc((size_t)LL * 16384 * 2);
  unsigned short* WT2 = (unsigned short*)alloc((size_t)LL * 16384 * 2);
  unsigned short* W1T = (unsigned short*)alloc((size_t)1024 * 256 * 2);
  unsigned short* W2T = (unsigned short*)alloc((size_t)256 * 128 * 2);
  int* gstart = (int*)alloc(65 * 4);

  const int* esrc = edge_index;
  const int* edst = edge_index + EE;
  const int nblk = (NN + 1023) / 1024;  // 98

  hipMemsetAsync(zz, 0, zz_bytes, stream);
  hist_kernel<<<(EE + 255) / 256, 256, 0, stream>>>(edst, cnt, EE);
  scan_p1<<<nblk, 256, 0, stream>>>(cnt, bsum, NN);
  scan_p2<<<1, 128, 0, stream>>>(bsum, rowptr, nblk, NN);
  scan_p3<<<nblk, 256, 0, stream>>>(cnt, bsum, rowptr, cursor, NN);
  fill_kernel<<<(EE + 255) / 256, 256, 0, stream>>>(esrc, edst, cursor, csr_src, EE);
  f2b4_kernel<<<(NN * 128 / 4 + 255) / 256, 256, 0, stream>>>(x, x16, NN * 128 / 4);
  convert_trunk<<<(LL * 16384 + 255) / 256, 256, 0, stream>>>(cW1, cW2, WT1, WT2);
  f2bT_kernel<<<(1024 * 256 + 255) / 256, 256, 0, stream>>>(epW1, W1T, 1024, 256);
  f2bT_kernel<<<(256 * 128 + 255) / 256, 256, 0, stream>>>(epW2, W2T, 256, 128);

  for (int l = 0; l < LL; ++l) {
    const unsigned short* h16 = (l == 0) ? x16 : (emb16 + (size_t)(l - 1) * 128);
    int ld = (l == 0) ? 128 : 512;
    aggregate_bf16<<<(NN + 3) / 4, 256, 0, stream>>>(h16, ld, rowptr, csr_src, ceps + l, g16a, NN);
    mfma_gemm_bt<<<dim3((NN + 127) / 128, 1), 256, 0, stream>>>(
        g16a, 128, WT1 + (size_t)l * 16384, 128, cb1 + l * 128, g16b, 128, NN);
    mfma_gemm_bt<<<dim3((NN + 127) / 128, 1), 256, 0, stream>>>(
        g16b, 128, WT2 + (size_t)l * 16384, 128, cb2 + l * 128, g16a, 128, NN);
    bn_stats_bf16<<<(NN + 511) / 512, 256, 0, stream>>>(g16a, bnsum + l * 128, bnsumsq + l * 128, NN);
    bn_apply_bf16<<<(NN * 16 + 255) / 256, 256, 0, stream>>>(
        g16a, bnsum + l * 128, bnsumsq + l * 128, cgamma + l * 128, cbeta + l * 128,
        emb16 + (size_t)l * 128, NN);
  }

  bounds_kernel<<<1, 128, 0, stream>>>(batch, gstart, NN);
  pool_bf16<<<dim3(GG, 8), 256, 0, stream>>>(emb16, gstart, gsum);
  nc_fused<<<GG, 256, 0, stream>>>(gsum, gstart, ncW1, ncb1, ncW2, ncb2, ncW3, ncb3,
                                   ncW4, ncb4, (float*)d_out);

  mfma_gemm_gather<<<(NC + 127) / 128, 512, 0, stream>>>(emb16, cand, W1T, epb1, C1, NC);
  mfma_gemm_bt<<<dim3((NC + 127) / 128, 1), 256, 0, stream>>>(C1, 256, W2T, 256, epb2, C2, 128, NC);
  ep_final_bf16<<<(NC + 3) / 4, 256, 0, stream>>>(C2, epW3, epb3, (float*)d_out + GG * CCLS, NC);
}

// Round 6
// 1289.288 us; speedup vs baseline: 2.0047x; 1.0940x over previous
//
#include <hip/hip_runtime.h>
#include <math.h>

#define NN 100000
#define EE 1600000
#define GG 64
#define HH 128
#define LL 4
#define CCLS 16
#define NC 100000
#define LDK 40   // padded LDS row stride (bf16 elems) for 32-wide K tiles
#define LDA2 136 // padded LDS row stride for full-K (128) A tiles

typedef __attribute__((ext_vector_type(8))) short bf16x8;
typedef __attribute__((ext_vector_type(4))) float f32x4;

__device__ __forceinline__ unsigned short f2bf(float x) {
  union { float f; unsigned int u; } v; v.f = x;
  unsigned int r = v.u + 0x7fffu + ((v.u >> 16) & 1u);
  return (unsigned short)(r >> 16);
}
__device__ __forceinline__ float bl(unsigned u) {
  union { unsigned u; float f; } v; v.u = u << 16; return v.f;
}
__device__ __forceinline__ float bh(unsigned u) {
  union { unsigned u; float f; } v; v.u = u & 0xffff0000u; return v.f;
}

// ---------------- CSR build ----------------
__global__ void hist_kernel(const int* __restrict__ dst, int* __restrict__ cnt, int E) {
  int e = blockIdx.x * 256 + threadIdx.x;
  if (e < E) atomicAdd(&cnt[dst[e]], 1);
}

__global__ __launch_bounds__(256) void scan_p1(const int* __restrict__ cnt,
                                               int* __restrict__ bsum, int n) {
  __shared__ int red[256];
  int tid = threadIdx.x;
  int base = blockIdx.x * 1024 + tid * 4;
  int s = 0;
  if (base + 3 < n) {
    int4 v = *(const int4*)(cnt + base);
    s = v.x + v.y + v.z + v.w;
  } else {
    for (int i = 0; i < 4; ++i) if (base + i < n) s += cnt[base + i];
  }
  red[tid] = s;
  __syncthreads();
  for (int st = 128; st >= 1; st >>= 1) {
    if (tid < st) red[tid] += red[tid + st];
    __syncthreads();
  }
  if (tid == 0) bsum[blockIdx.x] = red[0];
}

__global__ void scan_p2(int* __restrict__ bsum, int* __restrict__ rowptr, int nb, int n) {
  __shared__ int buf[128];
  int tid = threadIdx.x;
  int v = (tid < nb) ? bsum[tid] : 0;
  buf[tid] = v;
  __syncthreads();
  for (int off = 1; off < 128; off <<= 1) {
    int t = (tid >= off) ? buf[tid - off] : 0;
    __syncthreads();
    buf[tid] += t;
    __syncthreads();
  }
  if (tid < nb) bsum[tid] = buf[tid] - v;
  if (tid == 127) rowptr[n] = buf[127];
}

__global__ __launch_bounds__(256) void scan_p3(const int* __restrict__ cnt,
                                               const int* __restrict__ bsum,
                                               int* __restrict__ rowptr,
                                               int* __restrict__ cursor, int n) {
  __shared__ int red[256];
  int tid = threadIdx.x;
  int base = blockIdx.x * 1024 + tid * 4;
  int v[4] = {0, 0, 0, 0};
  if (base + 3 < n) {
    int4 t = *(const int4*)(cnt + base);
    v[0] = t.x; v[1] = t.y; v[2] = t.z; v[3] = t.w;
  } else {
    for (int i = 0; i < 4; ++i) if (base + i < n) v[i] = cnt[base + i];
  }
  int s = v[0] + v[1] + v[2] + v[3];
  red[tid] = s;
  __syncthreads();
  for (int off = 1; off < 256; off <<= 1) {
    int t = (tid >= off) ? red[tid - off] : 0;
    __syncthreads();
    red[tid] += t;
    __syncthreads();
  }
  int run = bsum[blockIdx.x] + red[tid] - s;
  int4 o;
  o.x = run; o.y = run + v[0]; o.z = o.y + v[1]; o.w = o.z + v[2];
  if (base + 3 < n) {
    *(int4*)(rowptr + base) = o;
    *(int4*)(cursor + base) = o;
  } else {
    int oo[4] = {o.x, o.y, o.z, o.w};
    for (int i = 0; i < 4; ++i)
      if (base + i < n) { rowptr[base + i] = oo[i]; cursor[base + i] = oo[i]; }
  }
}

// Bucketed fill: bucket = dst>>11 (49 buckets). In pass p, only blocks with
// (blockIdx&7)==bucket&7 and bucket>>3==p scatter. XCD-affinity heuristic:
// blockIdx%8 ~ XCD id, so each ~130KB csr region is written from one XCD's L2
// with dense temporal locality -> full-line evictions instead of 16x write amp.
__global__ __launch_bounds__(256) void fill_bucket(const int* __restrict__ src,
                                                   const int* __restrict__ dst,
                                                   int* __restrict__ cursor,
                                                   int* __restrict__ csr_src,
                                                   int E, int pass) {
  int cls = blockIdx.x & 7;
  int base = (blockIdx.x >> 3) * 4096;
  int want = (pass << 3) | cls;
  for (int i = threadIdx.x; i < 4096; i += 256) {
    int e = base + i;
    if (e >= E) break;
    int d = dst[e];
    if ((d >> 11) == want) {
      int p = atomicAdd(&cursor[d], 1);
      csr_src[p] = src[e];
    }
  }
}

// ---------------- converts ----------------
__global__ void f2b4_kernel(const float* __restrict__ in, unsigned short* __restrict__ out, int n4) {
  int i = blockIdx.x * 256 + threadIdx.x;
  if (i >= n4) return;
  float4 v = ((const float4*)in)[i];
  unsigned short r[4] = {f2bf(v.x), f2bf(v.y), f2bf(v.z), f2bf(v.w)};
  *(uint2*)(out + (size_t)i * 4) = *(uint2*)r;
}

__global__ void convert_trunk(const float* __restrict__ cW1, const float* __restrict__ cW2,
                              unsigned short* __restrict__ WT1, unsigned short* __restrict__ WT2) {
  int idx = blockIdx.x * 256 + threadIdx.x;
  if (idx >= LL * 16384) return;
  int l = idx >> 14, r = idx & 16383, k = r >> 7, n = r & 127;
  WT1[l * 16384 + n * 128 + k] = f2bf(cW1[idx]);
  WT2[l * 16384 + n * 128 + k] = f2bf(cW2[idx]);
}

__global__ void f2bT_kernel(const float* __restrict__ in, unsigned short* __restrict__ out,
                            int K, int Nn) {
  int idx = blockIdx.x * 256 + threadIdx.x;
  if (idx >= K * Nn) return;
  int k = idx / Nn, n = idx - k * Nn;
  out[(size_t)n * K + k] = f2bf(in[idx]);
}

// ---------------- GIN aggregate ----------------
__global__ void aggregate_bf16(const unsigned short* __restrict__ h16, int ld,
                               const int* __restrict__ rowptr,
                               const int* __restrict__ csr_src,
                               const float* __restrict__ ceps_l,
                               unsigned short* __restrict__ out, int n) {
  int node = blockIdx.x * 4 + (threadIdx.x >> 6);
  if (node >= n) return;
  int lane = threadIdx.x & 63;
  int c2 = lane * 2;
  float eps1 = 1.0f + *ceps_l;
  float ax = 0.f, ay = 0.f;
  int b = rowptr[node], e = rowptr[node + 1];
  int j = b;
  for (; j + 4 <= e; j += 4) {
    int s0 = csr_src[j + 0];
    int s1 = csr_src[j + 1];
    int s2 = csr_src[j + 2];
    int s3 = csr_src[j + 3];
    unsigned u0 = *(const unsigned*)(h16 + (size_t)s0 * ld + c2);
    unsigned u1 = *(const unsigned*)(h16 + (size_t)s1 * ld + c2);
    unsigned u2 = *(const unsigned*)(h16 + (size_t)s2 * ld + c2);
    unsigned u3 = *(const unsigned*)(h16 + (size_t)s3 * ld + c2);
    ax += bl(u0); ay += bh(u0);
    ax += bl(u1); ay += bh(u1);
    ax += bl(u2); ay += bh(u2);
    ax += bl(u3); ay += bh(u3);
  }
  for (; j < e; ++j) {
    int s = csr_src[j];
    unsigned u = *(const unsigned*)(h16 + (size_t)s * ld + c2);
    ax += bl(u); ay += bh(u);
  }
  unsigned hu = *(const unsigned*)(h16 + (size_t)node * ld + c2);
  ax = fmaf(eps1, bl(hu), ax);
  ay = fmaf(eps1, bh(hu), ay);
  unsigned short o[2] = {f2bf(ax), f2bf(ay)};
  *(unsigned*)(out + (size_t)node * 128 + c2) = *(unsigned*)o;
}

// ---------------- fused trunk layer: z2=relu(relu(A@W1+b1)@W2+b2), bn partial sums --------
// z1 lives only in LDS. In-place (C16 == A16): block reads its rows first, writes last.
__global__ __launch_bounds__(256) void trunk_fused(
    const unsigned short* __restrict__ A16,   // [M,128]
    const unsigned short* __restrict__ W1T,   // [128][128] pre-transposed
    const float* __restrict__ b1,
    const unsigned short* __restrict__ W2T,   // [128][128] pre-transposed
    const float* __restrict__ b2,
    float* __restrict__ bnsum, float* __restrict__ bnsumsq,
    unsigned short* __restrict__ C16,         // [M,128] (= A16)
    int M) {
  __shared__ unsigned short As[128 * LDA2];  // full 128x128 A tile / z1 tile
  __shared__ unsigned short Bs[128 * LDK];
  const int tid = threadIdx.x;
  const int bm = blockIdx.x * 128;
  const int lane = tid & 63;
  const int wave = tid >> 6;
  const int wr = (wave >> 1) << 6;
  const int wc = (wave & 1) << 6;
  const int ar = tid >> 1;
  const int ah = (tid & 1) << 4;
  int gra = bm + ar; if (gra >= M) gra = M - 1;
  const unsigned short* Arow = A16 + (size_t)gra * 128;
  const int mrow = lane & 15;
  const int kq = (lane >> 4) << 3;
  f32x4 acc[4][4] = {};

  // stage full A tile (128x128) up front
#pragma unroll
  for (int ks = 0; ks < 4; ++ks) {
    const int k0 = ks << 5;
    const uint4* s = (const uint4*)(Arow + k0 + ah);
    *(uint4*)(As + ar * LDA2 + k0 + ah) = s[0];
    *(uint4*)(As + ar * LDA2 + k0 + ah + 8) = s[1];
  }
  // phase 1: z1 = relu(A @ W1T^T + b1)
  for (int ks = 0; ks < 4; ++ks) {
    const int k0 = ks << 5;
    {
      const uint4* s = (const uint4*)(W1T + (size_t)ar * 128 + k0 + ah);
      *(uint4*)(Bs + ar * LDK + ah) = s[0];
      *(uint4*)(Bs + ar * LDK + ah + 8) = s[1];
    }
    __syncthreads();
    bf16x8 af[4], bfv[4];
#pragma unroll
    for (int t = 0; t < 4; ++t)
      af[t] = *(const bf16x8*)(As + (wr + t * 16 + mrow) * LDA2 + k0 + kq);
#pragma unroll
    for (int t = 0; t < 4; ++t)
      bfv[t] = *(const bf16x8*)(Bs + (wc + t * 16 + mrow) * LDK + kq);
#pragma unroll
    for (int mt = 0; mt < 4; ++mt)
#pragma unroll
      for (int nt = 0; nt < 4; ++nt)
        acc[mt][nt] = __builtin_amdgcn_mfma_f32_16x16x32_bf16(af[mt], bfv[nt], acc[mt][nt], 0, 0, 0);
    __syncthreads();
  }
  // write z1 back into As (C-layout -> A-row layout)
  const int crow = (lane >> 4) << 2;
  const int ccol = lane & 15;
#pragma unroll
  for (int nt = 0; nt < 4; ++nt) {
    int c = wc + nt * 16 + ccol;
    float bz = b1[c];
#pragma unroll
    for (int mt = 0; mt < 4; ++mt) {
      int rl = wr + mt * 16 + crow;
#pragma unroll
      for (int i = 0; i < 4; ++i)
        As[(rl + i) * LDA2 + c] = f2bf(fmaxf(acc[mt][nt][i] + bz, 0.f));
    }
  }
#pragma unroll
  for (int mt = 0; mt < 4; ++mt)
#pragma unroll
    for (int nt = 0; nt < 4; ++nt)
      acc[mt][nt] = (f32x4){0.f, 0.f, 0.f, 0.f};
  __syncthreads();
  // phase 2: z2 = relu(z1 @ W2T^T + b2)
  for (int ks = 0; ks < 4; ++ks) {
    const int k0 = ks << 5;
    {
      const uint4* s = (const uint4*)(W2T + (size_t)ar * 128 + k0 + ah);
      *(uint4*)(Bs + ar * LDK + ah) = s[0];
      *(uint4*)(Bs + ar * LDK + ah + 8) = s[1];
    }
    __syncthreads();
    bf16x8 af[4], bfv[4];
#pragma unroll
    for (int t = 0; t < 4; ++t)
      af[t] = *(const bf16x8*)(As + (wr + t * 16 + mrow) * LDA2 + k0 + kq);
#pragma unroll
    for (int t = 0; t < 4; ++t)
      bfv[t] = *(const bf16x8*)(Bs + (wc + t * 16 + mrow) * LDK + kq);
#pragma unroll
    for (int mt = 0; mt < 4; ++mt)
#pragma unroll
      for (int nt = 0; nt < 4; ++nt)
        acc[mt][nt] = __builtin_amdgcn_mfma_f32_16x16x32_bf16(af[mt], bfv[nt], acc[mt][nt], 0, 0, 0);
    __syncthreads();
  }
  // epilogue: bias+relu, write z2, per-column bn partial sums
#pragma unroll
  for (int nt = 0; nt < 4; ++nt) {
    int c = wc + nt * 16 + ccol;
    float bz = b2[c];
    float s = 0.f, q = 0.f;
#pragma unroll
    for (int mt = 0; mt < 4; ++mt) {
      int rbase = bm + wr + mt * 16 + crow;
#pragma unroll
      for (int i = 0; i < 4; ++i) {
        int r = rbase + i;
        if (r < M) {
          float v = fmaxf(acc[mt][nt][i] + bz, 0.f);
          C16[(size_t)r * 128 + c] = f2bf(v);
          s += v; q += v * v;
        }
      }
    }
    s += __shfl_xor(s, 16, 64);
    s += __shfl_xor(s, 32, 64);
    q += __shfl_xor(q, 16, 64);
    q += __shfl_xor(q, 32, 64);
    if (lane < 16) {
      atomicAdd(&bnsum[c], s);
      atomicAdd(&bnsumsq[c], q);
    }
  }
}

// ---------------- generic bf16 MFMA GEMM (used by edge predictor GEMM2) -----
__global__ __launch_bounds__(256) void mfma_gemm_bt(
    const unsigned short* __restrict__ A16, int lda,
    const unsigned short* __restrict__ WT, int K,
    const float* __restrict__ bias,
    unsigned short* __restrict__ C16, int ldc, int M) {
  __shared__ unsigned short As[128 * LDK];
  __shared__ unsigned short Bs[128 * LDK];
  const int tid = threadIdx.x;
  const int bm = blockIdx.x * 128;
  const int bn = blockIdx.y * 128;
  const int lane = tid & 63;
  const int wave = tid >> 6;
  const int wr = (wave >> 1) << 6;
  const int wc = (wave & 1) << 6;
  f32x4 acc[4][4] = {};
  const int ar = tid >> 1;
  const int ah = (tid & 1) << 4;
  int gra = bm + ar; if (gra >= M) gra = M - 1;
  const unsigned short* Arow = A16 + (size_t)gra * lda;
  const unsigned short* Brow = WT + (size_t)(bn + ar) * K;
  const int mrow = lane & 15;
  const int kq = (lane >> 4) << 3;
  const int nks = K >> 5;

  for (int ks = 0; ks < nks; ++ks) {
    const int k0 = ks << 5;
    {
      const uint4* s = (const uint4*)(Arow + k0 + ah);
      *(uint4*)(As + ar * LDK + ah) = s[0];
      *(uint4*)(As + ar * LDK + ah + 8) = s[1];
    }
    {
      const uint4* s = (const uint4*)(Brow + k0 + ah);
      *(uint4*)(Bs + ar * LDK + ah) = s[0];
      *(uint4*)(Bs + ar * LDK + ah + 8) = s[1];
    }
    __syncthreads();
    bf16x8 af[4], bfv[4];
#pragma unroll
    for (int t = 0; t < 4; ++t)
      af[t] = *(const bf16x8*)(As + (wr + t * 16 + mrow) * LDK + kq);
#pragma unroll
    for (int t = 0; t < 4; ++t)
      bfv[t] = *(const bf16x8*)(Bs + (wc + t * 16 + mrow) * LDK + kq);
#pragma unroll
    for (int mt = 0; mt < 4; ++mt)
#pragma unroll
      for (int nt = 0; nt < 4; ++nt)
        acc[mt][nt] = __builtin_amdgcn_mfma_f32_16x16x32_bf16(af[mt], bfv[nt], acc[mt][nt], 0, 0, 0);
    __syncthreads();
  }
  const int crow = (lane >> 4) << 2;
  const int ccol = lane & 15;
#pragma unroll
  for (int nt = 0; nt < 4; ++nt) {
    int cbase = bn + wc + nt * 16 + ccol;
    float bz = bias[cbase];
#pragma unroll
    for (int mt = 0; mt < 4; ++mt) {
      int rbase = bm + wr + mt * 16 + crow;
#pragma unroll
      for (int i = 0; i < 4; ++i) {
        int r = rbase + i;
        if (r < M) C16[(size_t)r * ldc + cbase] = f2bf(fmaxf(acc[mt][nt][i] + bz, 0.f));
      }
    }
  }
}

// ep GEMM1 with fused candidate gather, block 128x256, 8 waves 2x4, wave 64x64
__global__ __launch_bounds__(512) void mfma_gemm_gather(
    const unsigned short* __restrict__ emb16, const int* __restrict__ cand,
    const unsigned short* __restrict__ WT /*[256][1024]*/,
    const float* __restrict__ bias,
    unsigned short* __restrict__ C16 /*[M,256]*/, int M) {
  __shared__ unsigned short As[128 * LDK];
  __shared__ unsigned short Bs[256 * LDK];
  const int tid = threadIdx.x;
  const int bm = blockIdx.x * 128;
  const int lane = tid & 63;
  const int wave = tid >> 6;
  const int wr = (wave >> 2) << 6;
  const int wc = (wave & 3) << 6;
  f32x4 acc[4][4] = {};
  const int ar = tid >> 2;
  const int ah = (tid & 3) << 3;
  int gra = bm + ar; if (gra >= M) gra = M - 1;
  const int node0 = cand[gra];
  const int node1 = cand[NC + gra];
  const int br = tid >> 1;
  const int bh8 = (tid & 1) << 4;
  const unsigned short* Brow = WT + (size_t)br * 1024 + bh8;
  const int mrow = lane & 15;
  const int kq = (lane >> 4) << 3;

  for (int ks = 0; ks < 32; ++ks) {
    const int k0 = ks << 5;
    {
      int node = (k0 < 512) ? node0 : node1;
      const uint4* s = (const uint4*)(emb16 + (size_t)node * 512 + (k0 & 511) + ah);
      *(uint4*)(As + ar * LDK + ah) = s[0];
    }
    {
      const uint4* s = (const uint4*)(Brow + k0);
      *(uint4*)(Bs + br * LDK + bh8) = s[0];
      *(uint4*)(Bs + br * LDK + bh8 + 8) = s[1];
    }
    __syncthreads();
    bf16x8 af[4], bfv[4];
#pragma unroll
    for (int t = 0; t < 4; ++t)
      af[t] = *(const bf16x8*)(As + (wr + t * 16 + mrow) * LDK + kq);
#pragma unroll
    for (int t = 0; t < 4; ++t)
      bfv[t] = *(const bf16x8*)(Bs + (wc + t * 16 + mrow) * LDK + kq);
#pragma unroll
    for (int mt = 0; mt < 4; ++mt)
#pragma unroll
      for (int nt = 0; nt < 4; ++nt)
        acc[mt][nt] = __builtin_amdgcn_mfma_f32_16x16x32_bf16(af[mt], bfv[nt], acc[mt][nt], 0, 0, 0);
    __syncthreads();
  }
  const int crow = (lane >> 4) << 2;
  const int ccol = lane & 15;
#pragma unroll
  for (int nt = 0; nt < 4; ++nt) {
    int cbase = wc + nt * 16 + ccol;
    float bz = bias[cbase];
#pragma unroll
    for (int mt = 0; mt < 4; ++mt) {
      int rbase = bm + wr + mt * 16 + crow;
#pragma unroll
      for (int i = 0; i < 4; ++i) {
        int r = rbase + i;
        if (r < M) C16[(size_t)r * 256 + cbase] = f2bf(fmaxf(acc[mt][nt][i] + bz, 0.f));
      }
    }
  }
}

// ---------------- BatchNorm apply ----------------
__global__ void bn_apply_bf16(const unsigned short* __restrict__ z,
                              const float* __restrict__ sum, const float* __restrict__ sumsq,
                              const float* __restrict__ gamma, const float* __restrict__ beta,
                              unsigned short* __restrict__ out, int n) {
  int idx = blockIdx.x * 256 + threadIdx.x;
  if (idx >= n * 16) return;
  int r = idx >> 4, c8 = (idx & 15) << 3;
  uint4 v = *(const uint4*)(z + (size_t)r * 128 + c8);
  float f[8] = {bl(v.x), bh(v.x), bl(v.y), bh(v.y), bl(v.z), bh(v.z), bl(v.w), bh(v.w)};
  const float inv_n = 1.0f / (float)NN;
  unsigned short o[8];
#pragma unroll
  for (int j = 0; j < 8; ++j) {
    int c = c8 + j;
    float mu = sum[c] * inv_n;
    float var = sumsq[c] * inv_n - mu * mu;
    float sc = rsqrtf(var + 1e-5f) * gamma[c];
    o[j] = f2bf((f[j] - mu) * sc + beta[c]);
  }
  *(uint4*)(out + (size_t)r * 512 + c8) = *(uint4*)o;
}

// ---------------- pooling ----------------
__global__ void bounds_kernel(const int* __restrict__ batch, int* __restrict__ gstart, int n) {
  int g = threadIdx.x;
  if (g > GG) return;
  int lo = 0, hi = n;
  while (lo < hi) {
    int mid = (lo + hi) >> 1;
    if (batch[mid] < g) lo = mid + 1; else hi = mid;
  }
  gstart[g] = lo;
}

__global__ __launch_bounds__(256) void pool_bf16(const unsigned short* __restrict__ emb16,
                                                 const int* __restrict__ gstart,
                                                 float* __restrict__ gsum) {
  int g = blockIdx.x;
  int chunk = blockIdx.y;
  int c2 = threadIdx.x * 2;
  int s = gstart[g], e = gstart[g + 1];
  int len = e - s;
  int per = (len + 7) >> 3;
  int r0 = s + chunk * per;
  int r1 = min(r0 + per, e);
  float ax = 0.f, ay = 0.f;
  for (int r = r0; r < r1; ++r) {
    unsigned u = *(const unsigned*)(emb16 + (size_t)r * 512 + c2);
    ax += bl(u); ay += bh(u);
  }
  if (r1 > r0) {
    atomicAdd(&gsum[g * 512 + c2], ax);
    atomicAdd(&gsum[g * 512 + c2 + 1], ay);
  }
}

// ---------------- fused node classifier ----------------
__global__ __launch_bounds__(256) void nc_fused(
    const float* __restrict__ gsum, const int* __restrict__ gstart,
    const float* __restrict__ W1, const float* __restrict__ b1,
    const float* __restrict__ W2, const float* __restrict__ b2,
    const float* __restrict__ W3, const float* __restrict__ b3,
    const float* __restrict__ W4, const float* __restrict__ b4,
    float* __restrict__ out) {
  __shared__ float row[512];
  __shared__ float t1[256];
  __shared__ float t2[128];
  __shared__ float t3s[128];
  __shared__ float lg[16];
  int g = blockIdx.x;
  int tid = threadIdx.x;
  float inv = 1.0f / fmaxf((float)(gstart[g + 1] - gstart[g]), 1.0f);
  row[tid] = gsum[g * 512 + tid] * inv;
  row[tid + 256] = gsum[g * 512 + tid + 256] * inv;
  __syncthreads();
  {
    float acc = b1[tid];
#pragma unroll 8
    for (int k = 0; k < 512; ++k) acc = fmaf(row[k], W1[k * 256 + tid], acc);
    t1[tid] = fmaxf(acc, 0.f);
  }
  __syncthreads();
  if (tid < 128) {
    float acc = b2[tid];
#pragma unroll 8
    for (int k = 0; k < 256; ++k) acc = fmaf(t1[k], W2[k * 128 + tid], acc);
    t2[tid] = fmaxf(acc, 0.f);
  }
  __syncthreads();
  if (tid < 128) {
    float acc = b3[tid];
#pragma unroll 8
    for (int k = 0; k < 128; ++k) acc = fmaf(t2[k], W3[k * 128 + tid], acc);
    t3s[tid] = fmaxf(acc, 0.f);
  }
  __syncthreads();
  if (tid < 16) {
    float acc = b4[tid];
#pragma unroll 8
    for (int k = 0; k < 128; ++k) acc = fmaf(t3s[k], W4[k * 16 + tid], acc);
    lg[tid] = acc;
  }
  __syncthreads();
  if (tid < 16) {
    float v = lg[tid];
    float m = v;
    for (int j = 0; j < 16; ++j) m = fmaxf(m, lg[j]);
    float s = 0.f;
    for (int j = 0; j < 16; ++j) s += expf(lg[j] - m);
    out[g * 16 + tid] = v - m - logf(s);
  }
}

__global__ void ep_final_bf16(const unsigned short* __restrict__ C2, const float* __restrict__ w,
                              const float* __restrict__ b3, float* __restrict__ out, int M) {
  int row = blockIdx.x * 4 + (threadIdx.x >> 6);
  if (row >= M) return;
  int lane = threadIdx.x & 63;
  int c2 = lane * 2;
  unsigned u = *(const unsigned*)(C2 + (size_t)row * 128 + c2);
  float2 wv = *(const float2*)(w + c2);
  float s = bl(u) * wv.x + bh(u) * wv.y;
  for (int off = 32; off >= 1; off >>= 1) s += __shfl_down(s, off, 64);
  if (lane == 0) out[row] = 1.f / (1.f + expf(-(s + b3[0])));
}

// ---------------- launch ----------------
extern "C" void kernel_launch(void* const* d_in, const int* in_sizes, int n_in,
                              void* d_out, int out_size, void* d_ws, size_t ws_size,
                              hipStream_t stream) {
  const float* x = (const float*)d_in[0];
  const int* edge_index = (const int*)d_in[1];
  const int* batch = (const int*)d_in[2];
  const int* cand = (const int*)d_in[3];
  const float* cW1 = (const float*)d_in[4];
  const float* cb1 = (const float*)d_in[5];
  const float* cW2 = (const float*)d_in[6];
  const float* cb2 = (const float*)d_in[7];
  const float* cgamma = (const float*)d_in[8];
  const float* cbeta = (const float*)d_in[9];
  const float* ceps = (const float*)d_in[10];
  const float* ncW1 = (const float*)d_in[11];
  const float* ncb1 = (const float*)d_in[12];
  const float* ncW2 = (const float*)d_in[13];
  const float* ncb2 = (const float*)d_in[14];
  const float* ncW3 = (const float*)d_in[15];
  const float* ncb3 = (const float*)d_in[16];
  const float* ncW4 = (const float*)d_in[17];
  const float* ncb4 = (const float*)d_in[18];
  const float* epW1 = (const float*)d_in[19];
  const float* epb1 = (const float*)d_in[20];
  const float* epW2 = (const float*)d_in[21];
  const float* epb2 = (const float*)d_in[22];
  const float* epW3 = (const float*)d_in[23];
  const float* epb3 = (const float*)d_in[24];

  char* ws = (char*)d_ws;
  size_t off = 0;
  auto alloc = [&](size_t bytes) -> void* {
    off = (off + 255) & ~(size_t)255;
    void* p = ws + off;
    off += bytes;
    return p;
  };
  size_t zz_bytes = (size_t)NN * 4 + 512 * 4 + 512 * 4 + (size_t)GG * 512 * 4;
  char* zz = (char*)alloc(zz_bytes);
  int* cnt = (int*)zz;
  float* bnsum = (float*)(zz + (size_t)NN * 4);
  float* bnsumsq = bnsum + 512;
  float* gsum = bnsumsq + 512;
  int* rowptr = (int*)alloc((size_t)(NN + 1) * 4);
  int* cursor = (int*)alloc((size_t)NN * 4);
  int* csr_src = (int*)alloc((size_t)EE * 4);
  int* bsum = (int*)alloc(128 * 4);
  unsigned short* x16 = (unsigned short*)alloc((size_t)NN * 128 * 2);
  unsigned short* g16a = (unsigned short*)alloc((size_t)NN * 128 * 2);
  unsigned short* emb16 = (unsigned short*)alloc((size_t)NN * 512 * 2);
  unsigned short* C1 = (unsigned short*)alloc((size_t)NC * 256 * 2);
  unsigned short* C2 = (unsigned short*)alloc((size_t)NC * 128 * 2);
  unsigned short* WT1 = (unsigned short*)alloc((size_t)LL * 16384 * 2);
  unsigned short* WT2 = (unsigned short*)alloc((size_t)LL * 16384 * 2);
  unsigned short* W1T = (unsigned short*)alloc((size_t)1024 * 256 * 2);
  unsigned short* W2T = (unsigned short*)alloc((size_t)256 * 128 * 2);
  int* gstart = (int*)alloc(65 * 4);

  const int* esrc = edge_index;
  const int* edst = edge_index + EE;
  const int nblk = (NN + 1023) / 1024;  // 98

  hipMemsetAsync(zz, 0, zz_bytes, stream);
  hist_kernel<<<(EE + 255) / 256, 256, 0, stream>>>(edst, cnt, EE);
  scan_p1<<<nblk, 256, 0, stream>>>(cnt, bsum, NN);
  scan_p2<<<1, 128, 0, stream>>>(bsum, rowptr, nblk, NN);
  scan_p3<<<nblk, 256, 0, stream>>>(cnt, bsum, rowptr, cursor, NN);
  {
    const int nch = (EE + 4095) / 4096;  // 391
    for (int p = 0; p < 7; ++p)
      fill_bucket<<<nch * 8, 256, 0, stream>>>(esrc, edst, cursor, csr_src, EE, p);
  }
  f2b4_kernel<<<(NN * 128 / 4 + 255) / 256, 256, 0, stream>>>(x, x16, NN * 128 / 4);
  convert_trunk<<<(LL * 16384 + 255) / 256, 256, 0, stream>>>(cW1, cW2, WT1, WT2);
  f2bT_kernel<<<(1024 * 256 + 255) / 256, 256, 0, stream>>>(epW1, W1T, 1024, 256);
  f2bT_kernel<<<(256 * 128 + 255) / 256, 256, 0, stream>>>(epW2, W2T, 256, 128);

  for (int l = 0; l < LL; ++l) {
    const unsigned short* h16 = (l == 0) ? x16 : (emb16 + (size_t)(l - 1) * 128);
    int ld = (l == 0) ? 128 : 512;
    aggregate_bf16<<<(NN + 3) / 4, 256, 0, stream>>>(h16, ld, rowptr, csr_src, ceps + l, g16a, NN);
    trunk_fused<<<(NN + 127) / 128, 256, 0, stream>>>(
        g16a, WT1 + (size_t)l * 16384, cb1 + l * 128,
        WT2 + (size_t)l * 16384, cb2 + l * 128,
        bnsum + l * 128, bnsumsq + l * 128, g16a, NN);
    bn_apply_bf16<<<(NN * 16 + 255) / 256, 256, 0, stream>>>(
        g16a, bnsum + l * 128, bnsumsq + l * 128, cgamma + l * 128, cbeta + l * 128,
        emb16 + (size_t)l * 128, NN);
  }

  bounds_kernel<<<1, 128, 0, stream>>>(batch, gstart, NN);
  pool_bf16<<<dim3(GG, 8), 256, 0, stream>>>(emb16, gstart, gsum);
  nc_fused<<<GG, 256, 0, stream>>>(gsum, gstart, ncW1, ncb1, ncW2, ncb2, ncW3, ncb3,
                                   ncW4, ncb4, (float*)d_out);

  mfma_gemm_gather<<<(NC + 127) / 128, 512, 0, stream>>>(emb16, cand, W1T, epb1, C1, NC);
  mfma_gemm_bt<<<dim3((NC + 127) / 128, 1), 256, 0, stream>>>(C1, 256, W2T, 256, epb2, C2, 128, NC);
  ep_final_bf16<<<(NC + 3) / 4, 256, 0, stream>>>(C2, epW3, epb3, (float*)d_out + GG * CCLS, NC);
}

// Round 7
// 1222.105 us; speedup vs baseline: 2.1149x; 1.0550x over previous
//
#include <hip/hip_runtime.h>
#include <math.h>

#define NN 100000
#define EE 1600000
#define GG 64
#define HH 128
#define LL 4
#define CCLS 16
#define NC 100000
#define LDK 40   // padded LDS row stride (bf16 elems) for 32-wide K tiles
#define LDA2 136 // padded LDS row stride for full-K (128) A tiles

typedef __attribute__((ext_vector_type(8))) short bf16x8;
typedef __attribute__((ext_vector_type(4))) float f32x4;

__device__ __forceinline__ unsigned short f2bf(float x) {
  union { float f; unsigned int u; } v; v.f = x;
  unsigned int r = v.u + 0x7fffu + ((v.u >> 16) & 1u);
  return (unsigned short)(r >> 16);
}
__device__ __forceinline__ float bl(unsigned u) {
  union { unsigned u; float f; } v; v.u = u << 16; return v.f;
}
__device__ __forceinline__ float bh(unsigned u) {
  union { unsigned u; float f; } v; v.u = u & 0xffff0000u; return v.f;
}

// ---------------- CSR build ----------------
__global__ void hist_kernel(const int* __restrict__ dst, int* __restrict__ cnt, int E) {
  int e = blockIdx.x * 256 + threadIdx.x;
  if (e < E) atomicAdd(&cnt[dst[e]], 1);
}

__global__ __launch_bounds__(256) void scan_p1(const int* __restrict__ cnt,
                                               int* __restrict__ bsum, int n) {
  __shared__ int red[256];
  int tid = threadIdx.x;
  int base = blockIdx.x * 1024 + tid * 4;
  int s = 0;
  if (base + 3 < n) {
    int4 v = *(const int4*)(cnt + base);
    s = v.x + v.y + v.z + v.w;
  } else {
    for (int i = 0; i < 4; ++i) if (base + i < n) s += cnt[base + i];
  }
  red[tid] = s;
  __syncthreads();
  for (int st = 128; st >= 1; st >>= 1) {
    if (tid < st) red[tid] += red[tid + st];
    __syncthreads();
  }
  if (tid == 0) bsum[blockIdx.x] = red[0];
}

__global__ void scan_p2(int* __restrict__ bsum, int* __restrict__ rowptr, int nb, int n) {
  __shared__ int buf[128];
  int tid = threadIdx.x;
  int v = (tid < nb) ? bsum[tid] : 0;
  buf[tid] = v;
  __syncthreads();
  for (int off = 1; off < 128; off <<= 1) {
    int t = (tid >= off) ? buf[tid - off] : 0;
    __syncthreads();
    buf[tid] += t;
    __syncthreads();
  }
  if (tid < nb) bsum[tid] = buf[tid] - v;
  if (tid == 127) rowptr[n] = buf[127];
}

__global__ __launch_bounds__(256) void scan_p3(const int* __restrict__ cnt,
                                               const int* __restrict__ bsum,
                                               int* __restrict__ rowptr,
                                               int* __restrict__ cursor, int n) {
  __shared__ int red[256];
  int tid = threadIdx.x;
  int base = blockIdx.x * 1024 + tid * 4;
  int v[4] = {0, 0, 0, 0};
  if (base + 3 < n) {
    int4 t = *(const int4*)(cnt + base);
    v[0] = t.x; v[1] = t.y; v[2] = t.z; v[3] = t.w;
  } else {
    for (int i = 0; i < 4; ++i) if (base + i < n) v[i] = cnt[base + i];
  }
  int s = v[0] + v[1] + v[2] + v[3];
  red[tid] = s;
  __syncthreads();
  for (int off = 1; off < 256; off <<= 1) {
    int t = (tid >= off) ? red[tid - off] : 0;
    __syncthreads();
    red[tid] += t;
    __syncthreads();
  }
  int run = bsum[blockIdx.x] + red[tid] - s;
  int4 o;
  o.x = run; o.y = run + v[0]; o.z = o.y + v[1]; o.w = o.z + v[2];
  if (base + 3 < n) {
    *(int4*)(rowptr + base) = o;
    *(int4*)(cursor + base) = o;
  } else {
    int oo[4] = {o.x, o.y, o.z, o.w};
    for (int i = 0; i < 4; ++i)
      if (base + i < n) { rowptr[base + i] = oo[i]; cursor[base + i] = oo[i]; }
  }
}

// Bucketed fill with XCD-affinity (see R5 notes): kills scatter write amplification.
__global__ __launch_bounds__(256) void fill_bucket(const int* __restrict__ src,
                                                   const int* __restrict__ dst,
                                                   int* __restrict__ cursor,
                                                   int* __restrict__ csr_src,
                                                   int E, int pass) {
  int cls = blockIdx.x & 7;
  int base = (blockIdx.x >> 3) * 4096;
  int want = (pass << 3) | cls;
  for (int i = threadIdx.x; i < 4096; i += 256) {
    int e = base + i;
    if (e >= E) break;
    int d = dst[e];
    if ((d >> 11) == want) {
      int p = atomicAdd(&cursor[d], 1);
      csr_src[p] = src[e];
    }
  }
}

// ---------------- converts ----------------
__global__ void f2b4_kernel(const float* __restrict__ in, unsigned short* __restrict__ out, int n4) {
  int i = blockIdx.x * 256 + threadIdx.x;
  if (i >= n4) return;
  float4 v = ((const float4*)in)[i];
  unsigned short r[4] = {f2bf(v.x), f2bf(v.y), f2bf(v.z), f2bf(v.w)};
  *(uint2*)(out + (size_t)i * 4) = *(uint2*)r;
}

__global__ void convert_trunk(const float* __restrict__ cW1, const float* __restrict__ cW2,
                              unsigned short* __restrict__ WT1, unsigned short* __restrict__ WT2) {
  int idx = blockIdx.x * 256 + threadIdx.x;
  if (idx >= LL * 16384) return;
  int l = idx >> 14, r = idx & 16383, k = r >> 7, n = r & 127;
  WT1[l * 16384 + n * 128 + k] = f2bf(cW1[idx]);
  WT2[l * 16384 + n * 128 + k] = f2bf(cW2[idx]);
}

__global__ void f2bT_kernel(const float* __restrict__ in, unsigned short* __restrict__ out,
                            int K, int Nn) {
  int idx = blockIdx.x * 256 + threadIdx.x;
  if (idx >= K * Nn) return;
  int k = idx / Nn, n = idx - k * Nn;
  out[(size_t)n * K + k] = f2bf(in[idx]);
}

// ---------------- GIN aggregate: 16-lane subgroup per node, uint4 row loads ----------------
// wave = 4 nodes; each neighbor row (256 B) read by 16 lanes in ONE instruction;
// x4 unroll -> 16 rows outstanding per wave (4x the MLP of the 64-lane version).
__global__ void aggregate_bf16(const unsigned short* __restrict__ h16, int ld,
                               const int* __restrict__ rowptr,
                               const int* __restrict__ csr_src,
                               const float* __restrict__ ceps_l,
                               unsigned short* __restrict__ out, int n) {
  int wave = threadIdx.x >> 6;
  int lane = threadIdx.x & 63;
  int sub = lane >> 4;
  int li = lane & 15;
  int node = blockIdx.x * 16 + wave * 4 + sub;
  if (node >= n) return;
  int c8 = li * 8;  // 8 bf16 = 16 B per lane
  float eps1 = 1.0f + *ceps_l;
  float acc[8] = {};
  int b = rowptr[node], e = rowptr[node + 1];
  int j = b;
  for (; j + 4 <= e; j += 4) {
    int s0 = csr_src[j + 0];
    int s1 = csr_src[j + 1];
    int s2 = csr_src[j + 2];
    int s3 = csr_src[j + 3];
    uint4 u0 = *(const uint4*)(h16 + (size_t)s0 * ld + c8);
    uint4 u1 = *(const uint4*)(h16 + (size_t)s1 * ld + c8);
    uint4 u2 = *(const uint4*)(h16 + (size_t)s2 * ld + c8);
    uint4 u3 = *(const uint4*)(h16 + (size_t)s3 * ld + c8);
    acc[0] += bl(u0.x) + bl(u1.x) + bl(u2.x) + bl(u3.x);
    acc[1] += bh(u0.x) + bh(u1.x) + bh(u2.x) + bh(u3.x);
    acc[2] += bl(u0.y) + bl(u1.y) + bl(u2.y) + bl(u3.y);
    acc[3] += bh(u0.y) + bh(u1.y) + bh(u2.y) + bh(u3.y);
    acc[4] += bl(u0.z) + bl(u1.z) + bl(u2.z) + bl(u3.z);
    acc[5] += bh(u0.z) + bh(u1.z) + bh(u2.z) + bh(u3.z);
    acc[6] += bl(u0.w) + bl(u1.w) + bl(u2.w) + bl(u3.w);
    acc[7] += bh(u0.w) + bh(u1.w) + bh(u2.w) + bh(u3.w);
  }
  for (; j < e; ++j) {
    int s = csr_src[j];
    uint4 u = *(const uint4*)(h16 + (size_t)s * ld + c8);
    acc[0] += bl(u.x); acc[1] += bh(u.x);
    acc[2] += bl(u.y); acc[3] += bh(u.y);
    acc[4] += bl(u.z); acc[5] += bh(u.z);
    acc[6] += bl(u.w); acc[7] += bh(u.w);
  }
  uint4 hu = *(const uint4*)(h16 + (size_t)node * ld + c8);
  acc[0] = fmaf(eps1, bl(hu.x), acc[0]); acc[1] = fmaf(eps1, bh(hu.x), acc[1]);
  acc[2] = fmaf(eps1, bl(hu.y), acc[2]); acc[3] = fmaf(eps1, bh(hu.y), acc[3]);
  acc[4] = fmaf(eps1, bl(hu.z), acc[4]); acc[5] = fmaf(eps1, bh(hu.z), acc[5]);
  acc[6] = fmaf(eps1, bl(hu.w), acc[6]); acc[7] = fmaf(eps1, bh(hu.w), acc[7]);
  unsigned short o[8];
#pragma unroll
  for (int i = 0; i < 8; ++i) o[i] = f2bf(acc[i]);
  *(uint4*)(out + (size_t)node * 128 + c8) = *(uint4*)o;
}

// ---------------- fused trunk layer (with B register-prefetch) ----------------
__global__ __launch_bounds__(256) void trunk_fused(
    const unsigned short* __restrict__ A16,
    const unsigned short* __restrict__ W1T, const float* __restrict__ b1,
    const unsigned short* __restrict__ W2T, const float* __restrict__ b2,
    float* __restrict__ bnsum, float* __restrict__ bnsumsq,
    unsigned short* __restrict__ C16, int M) {
  __shared__ unsigned short As[128 * LDA2];
  __shared__ unsigned short Bs[128 * LDK];
  const int tid = threadIdx.x;
  const int bm = blockIdx.x * 128;
  const int lane = tid & 63;
  const int wave = tid >> 6;
  const int wr = (wave >> 1) << 6;
  const int wc = (wave & 1) << 6;
  const int ar = tid >> 1;
  const int ah = (tid & 1) << 4;
  int gra = bm + ar; if (gra >= M) gra = M - 1;
  const unsigned short* Arow = A16 + (size_t)gra * 128;
  const int mrow = lane & 15;
  const int kq = (lane >> 4) << 3;
  f32x4 acc[4][4] = {};

#pragma unroll
  for (int ks = 0; ks < 4; ++ks) {
    const int k0 = ks << 5;
    const uint4* s = (const uint4*)(Arow + k0 + ah);
    *(uint4*)(As + ar * LDA2 + k0 + ah) = s[0];
    *(uint4*)(As + ar * LDA2 + k0 + ah + 8) = s[1];
  }
  // phase 1
  uint4 p0 = *(const uint4*)(W1T + (size_t)ar * 128 + ah);
  uint4 p1 = *(const uint4*)(W1T + (size_t)ar * 128 + ah + 8);
  for (int ks = 0; ks < 4; ++ks) {
    const int k0 = ks << 5;
    *(uint4*)(Bs + ar * LDK + ah) = p0;
    *(uint4*)(Bs + ar * LDK + ah + 8) = p1;
    __syncthreads();
    if (ks < 3) {
      p0 = *(const uint4*)(W1T + (size_t)ar * 128 + k0 + 32 + ah);
      p1 = *(const uint4*)(W1T + (size_t)ar * 128 + k0 + 32 + ah + 8);
    }
    bf16x8 af[4], bfv[4];
#pragma unroll
    for (int t = 0; t < 4; ++t)
      af[t] = *(const bf16x8*)(As + (wr + t * 16 + mrow) * LDA2 + k0 + kq);
#pragma unroll
    for (int t = 0; t < 4; ++t)
      bfv[t] = *(const bf16x8*)(Bs + (wc + t * 16 + mrow) * LDK + kq);
#pragma unroll
    for (int mt = 0; mt < 4; ++mt)
#pragma unroll
      for (int nt = 0; nt < 4; ++nt)
        acc[mt][nt] = __builtin_amdgcn_mfma_f32_16x16x32_bf16(af[mt], bfv[nt], acc[mt][nt], 0, 0, 0);
    __syncthreads();
  }
  // z1 writeback (C-layout -> A-row layout)
  const int crow = (lane >> 4) << 2;
  const int ccol = lane & 15;
#pragma unroll
  for (int nt = 0; nt < 4; ++nt) {
    int c = wc + nt * 16 + ccol;
    float bz = b1[c];
#pragma unroll
    for (int mt = 0; mt < 4; ++mt) {
      int rl = wr + mt * 16 + crow;
#pragma unroll
      for (int i = 0; i < 4; ++i)
        As[(rl + i) * LDA2 + c] = f2bf(fmaxf(acc[mt][nt][i] + bz, 0.f));
    }
  }
#pragma unroll
  for (int mt = 0; mt < 4; ++mt)
#pragma unroll
    for (int nt = 0; nt < 4; ++nt)
      acc[mt][nt] = (f32x4){0.f, 0.f, 0.f, 0.f};
  p0 = *(const uint4*)(W2T + (size_t)ar * 128 + ah);
  p1 = *(const uint4*)(W2T + (size_t)ar * 128 + ah + 8);
  __syncthreads();
  // phase 2
  for (int ks = 0; ks < 4; ++ks) {
    const int k0 = ks << 5;
    *(uint4*)(Bs + ar * LDK + ah) = p0;
    *(uint4*)(Bs + ar * LDK + ah + 8) = p1;
    __syncthreads();
    if (ks < 3) {
      p0 = *(const uint4*)(W2T + (size_t)ar * 128 + k0 + 32 + ah);
      p1 = *(const uint4*)(W2T + (size_t)ar * 128 + k0 + 32 + ah + 8);
    }
    bf16x8 af[4], bfv[4];
#pragma unroll
    for (int t = 0; t < 4; ++t)
      af[t] = *(const bf16x8*)(As + (wr + t * 16 + mrow) * LDA2 + k0 + kq);
#pragma unroll
    for (int t = 0; t < 4; ++t)
      bfv[t] = *(const bf16x8*)(Bs + (wc + t * 16 + mrow) * LDK + kq);
#pragma unroll
    for (int mt = 0; mt < 4; ++mt)
#pragma unroll
      for (int nt = 0; nt < 4; ++nt)
        acc[mt][nt] = __builtin_amdgcn_mfma_f32_16x16x32_bf16(af[mt], bfv[nt], acc[mt][nt], 0, 0, 0);
    __syncthreads();
  }
#pragma unroll
  for (int nt = 0; nt < 4; ++nt) {
    int c = wc + nt * 16 + ccol;
    float bz = b2[c];
    float s = 0.f, q = 0.f;
#pragma unroll
    for (int mt = 0; mt < 4; ++mt) {
      int rbase = bm + wr + mt * 16 + crow;
#pragma unroll
      for (int i = 0; i < 4; ++i) {
        int r = rbase + i;
        if (r < M) {
          float v = fmaxf(acc[mt][nt][i] + bz, 0.f);
          C16[(size_t)r * 128 + c] = f2bf(v);
          s += v; q += v * v;
        }
      }
    }
    s += __shfl_xor(s, 16, 64);
    s += __shfl_xor(s, 32, 64);
    q += __shfl_xor(q, 16, 64);
    q += __shfl_xor(q, 32, 64);
    if (lane < 16) {
      atomicAdd(&bnsum[c], s);
      atomicAdd(&bnsumsq[c], q);
    }
  }
}

// ---------------- generic bf16 MFMA GEMM (ep GEMM2), register-prefetched ----------------
__global__ __launch_bounds__(256) void mfma_gemm_bt(
    const unsigned short* __restrict__ A16, int lda,
    const unsigned short* __restrict__ WT, int K,
    const float* __restrict__ bias,
    unsigned short* __restrict__ C16, int ldc, int M) {
  __shared__ unsigned short As[128 * LDK];
  __shared__ unsigned short Bs[128 * LDK];
  const int tid = threadIdx.x;
  const int bm = blockIdx.x * 128;
  const int bn = blockIdx.y * 128;
  const int lane = tid & 63;
  const int wave = tid >> 6;
  const int wr = (wave >> 1) << 6;
  const int wc = (wave & 1) << 6;
  f32x4 acc[4][4] = {};
  const int ar = tid >> 1;
  const int ah = (tid & 1) << 4;
  int gra = bm + ar; if (gra >= M) gra = M - 1;
  const unsigned short* Arow = A16 + (size_t)gra * lda;
  const unsigned short* Brow = WT + (size_t)(bn + ar) * K;
  const int mrow = lane & 15;
  const int kq = (lane >> 4) << 3;
  const int nks = K >> 5;

  uint4 a0 = *(const uint4*)(Arow + ah);
  uint4 a1 = *(const uint4*)(Arow + ah + 8);
  uint4 b0 = *(const uint4*)(Brow + ah);
  uint4 b1 = *(const uint4*)(Brow + ah + 8);
  for (int ks = 0; ks < nks; ++ks) {
    const int k0 = ks << 5;
    *(uint4*)(As + ar * LDK + ah) = a0;
    *(uint4*)(As + ar * LDK + ah + 8) = a1;
    *(uint4*)(Bs + ar * LDK + ah) = b0;
    *(uint4*)(Bs + ar * LDK + ah + 8) = b1;
    __syncthreads();
    if (ks + 1 < nks) {
      const int k1 = k0 + 32;
      a0 = *(const uint4*)(Arow + k1 + ah);
      a1 = *(const uint4*)(Arow + k1 + ah + 8);
      b0 = *(const uint4*)(Brow + k1 + ah);
      b1 = *(const uint4*)(Brow + k1 + ah + 8);
    }
    bf16x8 af[4], bfv[4];
#pragma unroll
    for (int t = 0; t < 4; ++t)
      af[t] = *(const bf16x8*)(As + (wr + t * 16 + mrow) * LDK + kq);
#pragma unroll
    for (int t = 0; t < 4; ++t)
      bfv[t] = *(const bf16x8*)(Bs + (wc + t * 16 + mrow) * LDK + kq);
#pragma unroll
    for (int mt = 0; mt < 4; ++mt)
#pragma unroll
      for (int nt = 0; nt < 4; ++nt)
        acc[mt][nt] = __builtin_amdgcn_mfma_f32_16x16x32_bf16(af[mt], bfv[nt], acc[mt][nt], 0, 0, 0);
    __syncthreads();
  }
  const int crow = (lane >> 4) << 2;
  const int ccol = lane & 15;
#pragma unroll
  for (int nt = 0; nt < 4; ++nt) {
    int cbase = bn + wc + nt * 16 + ccol;
    float bz = bias[cbase];
#pragma unroll
    for (int mt = 0; mt < 4; ++mt) {
      int rbase = bm + wr + mt * 16 + crow;
#pragma unroll
      for (int i = 0; i < 4; ++i) {
        int r = rbase + i;
        if (r < M) C16[(size_t)r * ldc + cbase] = f2bf(fmaxf(acc[mt][nt][i] + bz, 0.f));
      }
    }
  }
}

// ep GEMM1 with fused candidate gather, block 128x256, 8 waves 2x4, wave 64x64.
// Register-prefetch of step k+1 overlaps random-gather latency with MFMA of step k.
__global__ __launch_bounds__(512) void mfma_gemm_gather(
    const unsigned short* __restrict__ emb16, const int* __restrict__ cand,
    const unsigned short* __restrict__ WT /*[256][1024]*/,
    const float* __restrict__ bias,
    unsigned short* __restrict__ C16 /*[M,256]*/, int M) {
  __shared__ unsigned short As[128 * LDK];
  __shared__ unsigned short Bs[256 * LDK];
  const int tid = threadIdx.x;
  const int bm = blockIdx.x * 128;
  const int lane = tid & 63;
  const int wave = tid >> 6;
  const int wr = (wave >> 2) << 6;
  const int wc = (wave & 3) << 6;
  f32x4 acc[4][4] = {};
  const int ar = tid >> 2;
  const int ah = (tid & 3) << 3;
  int gra = bm + ar; if (gra >= M) gra = M - 1;
  const int node0 = cand[gra];
  const int node1 = cand[NC + gra];
  const int br = tid >> 1;
  const int bh8 = (tid & 1) << 4;
  const unsigned short* Brow = WT + (size_t)br * 1024 + bh8;
  const int mrow = lane & 15;
  const int kq = (lane >> 4) << 3;

  uint4 a_reg = *(const uint4*)(emb16 + (size_t)node0 * 512 + ah);
  uint4 b_reg0 = *(const uint4*)(Brow);
  uint4 b_reg1 = *(const uint4*)(Brow + 8);
  for (int ks = 0; ks < 32; ++ks) {
    *(uint4*)(As + ar * LDK + ah) = a_reg;
    *(uint4*)(Bs + br * LDK + bh8) = b_reg0;
    *(uint4*)(Bs + br * LDK + bh8 + 8) = b_reg1;
    __syncthreads();
    if (ks < 31) {
      const int k1 = (ks + 1) << 5;
      int node = (k1 < 512) ? node0 : node1;
      a_reg = *(const uint4*)(emb16 + (size_t)node * 512 + (k1 & 511) + ah);
      b_reg0 = *(const uint4*)(Brow + k1);
      b_reg1 = *(const uint4*)(Brow + k1 + 8);
    }
    bf16x8 af[4], bfv[4];
#pragma unroll
    for (int t = 0; t < 4; ++t)
      af[t] = *(const bf16x8*)(As + (wr + t * 16 + mrow) * LDK + kq);
#pragma unroll
    for (int t = 0; t < 4; ++t)
      bfv[t] = *(const bf16x8*)(Bs + (wc + t * 16 + mrow) * LDK + kq);
#pragma unroll
    for (int mt = 0; mt < 4; ++mt)
#pragma unroll
      for (int nt = 0; nt < 4; ++nt)
        acc[mt][nt] = __builtin_amdgcn_mfma_f32_16x16x32_bf16(af[mt], bfv[nt], acc[mt][nt], 0, 0, 0);
    __syncthreads();
  }
  const int crow = (lane >> 4) << 2;
  const int ccol = lane & 15;
#pragma unroll
  for (int nt = 0; nt < 4; ++nt) {
    int cbase = wc + nt * 16 + ccol;
    float bz = bias[cbase];
#pragma unroll
    for (int mt = 0; mt < 4; ++mt) {
      int rbase = bm + wr + mt * 16 + crow;
#pragma unroll
      for (int i = 0; i < 4; ++i) {
        int r = rbase + i;
        if (r < M) C16[(size_t)r * 256 + cbase] = f2bf(fmaxf(acc[mt][nt][i] + bz, 0.f));
      }
    }
  }
}

// ---------------- BatchNorm apply ----------------
__global__ void bn_apply_bf16(const unsigned short* __restrict__ z,
                              const float* __restrict__ sum, const float* __restrict__ sumsq,
                              const float* __restrict__ gamma, const float* __restrict__ beta,
                              unsigned short* __restrict__ out, int n) {
  int idx = blockIdx.x * 256 + threadIdx.x;
  if (idx >= n * 16) return;
  int r = idx >> 4, c8 = (idx & 15) << 3;
  uint4 v = *(const uint4*)(z + (size_t)r * 128 + c8);
  float f[8] = {bl(v.x), bh(v.x), bl(v.y), bh(v.y), bl(v.z), bh(v.z), bl(v.w), bh(v.w)};
  const float inv_n = 1.0f / (float)NN;
  unsigned short o[8];
#pragma unroll
  for (int j = 0; j < 8; ++j) {
    int c = c8 + j;
    float mu = sum[c] * inv_n;
    float var = sumsq[c] * inv_n - mu * mu;
    float sc = rsqrtf(var + 1e-5f) * gamma[c];
    o[j] = f2bf((f[j] - mu) * sc + beta[c]);
  }
  *(uint4*)(out + (size_t)r * 512 + c8) = *(uint4*)o;
}

// ---------------- pooling ----------------
__global__ void bounds_kernel(const int* __restrict__ batch, int* __restrict__ gstart, int n) {
  int g = threadIdx.x;
  if (g > GG) return;
  int lo = 0, hi = n;
  while (lo < hi) {
    int mid = (lo + hi) >> 1;
    if (batch[mid] < g) lo = mid + 1; else hi = mid;
  }
  gstart[g] = lo;
}

__global__ __launch_bounds__(256) void pool_bf16(const unsigned short* __restrict__ emb16,
                                                 const int* __restrict__ gstart,
                                                 float* __restrict__ gsum) {
  int g = blockIdx.x;
  int chunk = blockIdx.y;
  int c2 = threadIdx.x * 2;
  int s = gstart[g], e = gstart[g + 1];
  int len = e - s;
  int per = (len + 7) >> 3;
  int r0 = s + chunk * per;
  int r1 = min(r0 + per, e);
  float ax = 0.f, ay = 0.f;
  for (int r = r0; r < r1; ++r) {
    unsigned u = *(const unsigned*)(emb16 + (size_t)r * 512 + c2);
    ax += bl(u); ay += bh(u);
  }
  if (r1 > r0) {
    atomicAdd(&gsum[g * 512 + c2], ax);
    atomicAdd(&gsum[g * 512 + c2 + 1], ay);
  }
}

// ---------------- fused node classifier ----------------
__global__ __launch_bounds__(256) void nc_fused(
    const float* __restrict__ gsum, const int* __restrict__ gstart,
    const float* __restrict__ W1, const float* __restrict__ b1,
    const float* __restrict__ W2, const float* __restrict__ b2,
    const float* __restrict__ W3, const float* __restrict__ b3,
    const float* __restrict__ W4, const float* __restrict__ b4,
    float* __restrict__ out) {
  __shared__ float row[512];
  __shared__ float t1[256];
  __shared__ float t2[128];
  __shared__ float t3s[128];
  __shared__ float lg[16];
  int g = blockIdx.x;
  int tid = threadIdx.x;
  float inv = 1.0f / fmaxf((float)(gstart[g + 1] - gstart[g]), 1.0f);
  row[tid] = gsum[g * 512 + tid] * inv;
  row[tid + 256] = gsum[g * 512 + tid + 256] * inv;
  __syncthreads();
  {
    float acc = b1[tid];
#pragma unroll 8
    for (int k = 0; k < 512; ++k) acc = fmaf(row[k], W1[k * 256 + tid], acc);
    t1[tid] = fmaxf(acc, 0.f);
  }
  __syncthreads();
  if (tid < 128) {
    float acc = b2[tid];
#pragma unroll 8
    for (int k = 0; k < 256; ++k) acc = fmaf(t1[k], W2[k * 128 + tid], acc);
    t2[tid] = fmaxf(acc, 0.f);
  }
  __syncthreads();
  if (tid < 128) {
    float acc = b3[tid];
#pragma unroll 8
    for (int k = 0; k < 128; ++k) acc = fmaf(t2[k], W3[k * 128 + tid], acc);
    t3s[tid] = fmaxf(acc, 0.f);
  }
  __syncthreads();
  if (tid < 16) {
    float acc = b4[tid];
#pragma unroll 8
    for (int k = 0; k < 128; ++k) acc = fmaf(t3s[k], W4[k * 16 + tid], acc);
    lg[tid] = acc;
  }
  __syncthreads();
  if (tid < 16) {
    float v = lg[tid];
    float m = v;
    for (int j = 0; j < 16; ++j) m = fmaxf(m, lg[j]);
    float s = 0.f;
    for (int j = 0; j < 16; ++j) s += expf(lg[j] - m);
    out[g * 16 + tid] = v - m - logf(s);
  }
}

__global__ void ep_final_bf16(const unsigned short* __restrict__ C2, const float* __restrict__ w,
                              const float* __restrict__ b3, float* __restrict__ out, int M) {
  int row = blockIdx.x * 4 + (threadIdx.x >> 6);
  if (row >= M) return;
  int lane = threadIdx.x & 63;
  int c2 = lane * 2;
  unsigned u = *(const unsigned*)(C2 + (size_t)row * 128 + c2);
  float2 wv = *(const float2*)(w + c2);
  float s = bl(u) * wv.x + bh(u) * wv.y;
  for (int off = 32; off >= 1; off >>= 1) s += __shfl_down(s, off, 64);
  if (lane == 0) out[row] = 1.f / (1.f + expf(-(s + b3[0])));
}

// ---------------- launch ----------------
extern "C" void kernel_launch(void* const* d_in, const int* in_sizes, int n_in,
                              void* d_out, int out_size, void* d_ws, size_t ws_size,
                              hipStream_t stream) {
  const float* x = (const float*)d_in[0];
  const int* edge_index = (const int*)d_in[1];
  const int* batch = (const int*)d_in[2];
  const int* cand = (const int*)d_in[3];
  const float* cW1 = (const float*)d_in[4];
  const float* cb1 = (const float*)d_in[5];
  const float* cW2 = (const float*)d_in[6];
  const float* cb2 = (const float*)d_in[7];
  const float* cgamma = (const float*)d_in[8];
  const float* cbeta = (const float*)d_in[9];
  const float* ceps = (const float*)d_in[10];
  const float* ncW1 = (const float*)d_in[11];
  const float* ncb1 = (const float*)d_in[12];
  const float* ncW2 = (const float*)d_in[13];
  const float* ncb2 = (const float*)d_in[14];
  const float* ncW3 = (const float*)d_in[15];
  const float* ncb3 = (const float*)d_in[16];
  const float* ncW4 = (const float*)d_in[17];
  const float* ncb4 = (const float*)d_in[18];
  const float* epW1 = (const float*)d_in[19];
  const float* epb1 = (const float*)d_in[20];
  const float* epW2 = (const float*)d_in[21];
  const float* epb2 = (const float*)d_in[22];
  const float* epW3 = (const float*)d_in[23];
  const float* epb3 = (const float*)d_in[24];

  char* ws = (char*)d_ws;
  size_t off = 0;
  auto alloc = [&](size_t bytes) -> void* {
    off = (off + 255) & ~(size_t)255;
    void* p = ws + off;
    off += bytes;
    return p;
  };
  size_t zz_bytes = (size_t)NN * 4 + 512 * 4 + 512 * 4 + (size_t)GG * 512 * 4;
  char* zz = (char*)alloc(zz_bytes);
  int* cnt = (int*)zz;
  float* bnsum = (float*)(zz + (size_t)NN * 4);
  float* bnsumsq = bnsum + 512;
  float* gsum = bnsumsq + 512;
  int* rowptr = (int*)alloc((size_t)(NN + 1) * 4);
  int* cursor = (int*)alloc((size_t)NN * 4);
  int* csr_src = (int*)alloc((size_t)EE * 4);
  int* bsum = (int*)alloc(128 * 4);
  unsigned short* x16 = (unsigned short*)alloc((size_t)NN * 128 * 2);
  unsigned short* g16a = (unsigned short*)alloc((size_t)NN * 128 * 2);
  unsigned short* emb16 = (unsigned short*)alloc((size_t)NN * 512 * 2);
  unsigned short* C1 = (unsigned short*)alloc((size_t)NC * 256 * 2);
  unsigned short* C2 = (unsigned short*)alloc((size_t)NC * 128 * 2);
  unsigned short* WT1 = (unsigned short*)alloc((size_t)LL * 16384 * 2);
  unsigned short* WT2 = (unsigned short*)alloc((size_t)LL * 16384 * 2);
  unsigned short* W1T = (unsigned short*)alloc((size_t)1024 * 256 * 2);
  unsigned short* W2T = (unsigned short*)alloc((size_t)256 * 128 * 2);
  int* gstart = (int*)alloc(65 * 4);

  const int* esrc = edge_index;
  const int* edst = edge_index + EE;
  const int nblk = (NN + 1023) / 1024;  // 98

  hipMemsetAsync(zz, 0, zz_bytes, stream);
  hist_kernel<<<(EE + 255) / 256, 256, 0, stream>>>(edst, cnt, EE);
  scan_p1<<<nblk, 256, 0, stream>>>(cnt, bsum, NN);
  scan_p2<<<1, 128, 0, stream>>>(bsum, rowptr, nblk, NN);
  scan_p3<<<nblk, 256, 0, stream>>>(cnt, bsum, rowptr, cursor, NN);
  {
    const int nch = (EE + 4095) / 4096;  // 391
    for (int p = 0; p < 7; ++p)
      fill_bucket<<<nch * 8, 256, 0, stream>>>(esrc, edst, cursor, csr_src, EE, p);
  }
  f2b4_kernel<<<(NN * 128 / 4 + 255) / 256, 256, 0, stream>>>(x, x16, NN * 128 / 4);
  convert_trunk<<<(LL * 16384 + 255) / 256, 256, 0, stream>>>(cW1, cW2, WT1, WT2);
  f2bT_kernel<<<(1024 * 256 + 255) / 256, 256, 0, stream>>>(epW1, W1T, 1024, 256);
  f2bT_kernel<<<(256 * 128 + 255) / 256, 256, 0, stream>>>(epW2, W2T, 256, 128);

  for (int l = 0; l < LL; ++l) {
    const unsigned short* h16 = (l == 0) ? x16 : (emb16 + (size_t)(l - 1) * 128);
    int ld = (l == 0) ? 128 : 512;
    aggregate_bf16<<<(NN + 15) / 16, 256, 0, stream>>>(h16, ld, rowptr, csr_src, ceps + l, g16a, NN);
    trunk_fused<<<(NN + 127) / 128, 256, 0, stream>>>(
        g16a, WT1 + (size_t)l * 16384, cb1 + l * 128,
        WT2 + (size_t)l * 16384, cb2 + l * 128,
        bnsum + l * 128, bnsumsq + l * 128, g16a, NN);
    bn_apply_bf16<<<(NN * 16 + 255) / 256, 256, 0, stream>>>(
        g16a, bnsum + l * 128, bnsumsq + l * 128, cgamma + l * 128, cbeta + l * 128,
        emb16 + (size_t)l * 128, NN);
  }

  bounds_kernel<<<1, 128, 0, stream>>>(batch, gstart, NN);
  pool_bf16<<<dim3(GG, 8), 256, 0, stream>>>(emb16, gstart, gsum);
  nc_fused<<<GG, 256, 0, stream>>>(gsum, gstart, ncW1, ncb1, ncW2, ncb2, ncW3, ncb3,
                                   ncW4, ncb4, (float*)d_out);

  mfma_gemm_gather<<<(NC + 127) / 128, 512, 0, stream>>>(emb16, cand, W1T, epb1, C1, NC);
  mfma_gemm_bt<<<dim3((NC + 127) / 128, 1), 256, 0, stream>>>(C1, 256, W2T, 256, epb2, C2, 128, NC);
  ep_final_bf16<<<(NC + 3) / 4, 256, 0, stream>>>(C2, epW3, epb3, (float*)d_out + GG * CCLS, NC);
}